// Round 3
// baseline (1104.292 us; speedup 1.0000x reference)
//
#include <hip/hip_runtime.h>
#include <cstdint>
#include <cstddef>

#define NN   50000
#define NE   500000
#define DIN  64
#define EDIM 32
#define NH   4
#define NC   64
#define HC   256   // NH*NC
#define NGG  64
#define ND   64
#define LN_EPS 1e-5f
#define EESLOTS (NE + NN)   // edges + self-loops, CSR-slot order
#define XLR  512            // row stride of fused xl|xr buffer

typedef __attribute__((ext_vector_type(8))) short bf16x8;
typedef __attribute__((ext_vector_type(4))) float f32x4;
typedef __attribute__((ext_vector_type(4))) unsigned short u16x4;

__device__ __forceinline__ unsigned short f2bf(float x) {
    unsigned u = __float_as_uint(x);
    unsigned r = (u + 0x7FFFu + ((u >> 16) & 1u)) >> 16;
    return (unsigned short)r;
}
__device__ __forceinline__ float bf2f(unsigned short h) {
    return __uint_as_float(((unsigned)h) << 16);
}

// ---------------------------------------------------------------------------
// CSR build: degree count -> single-block scan -> fill
// ---------------------------------------------------------------------------
__global__ void count_deg(const int* __restrict__ dst, int* __restrict__ deg) {
    int e = blockIdx.x * blockDim.x + threadIdx.x;
    if (e < NE) atomicAdd(&deg[dst[e]], 1);
}

__global__ void scan_deg(int* __restrict__ cursor, int* __restrict__ row_ptr) {
    __shared__ int sums[1024];
    const int T = 1024;
    const int chunk = (NN + T - 1) / T;  // 49
    int t = threadIdx.x;
    int lo = t * chunk, hi = min(lo + chunk, NN);
    int s = 0;
    for (int i = lo; i < hi; i++) s += cursor[i];
    sums[t] = s;
    __syncthreads();
    for (int off = 1; off < T; off <<= 1) {
        int v = (t >= off) ? sums[t - off] : 0;
        __syncthreads();
        sums[t] += v;
        __syncthreads();
    }
    int base = (t == 0) ? 0 : sums[t - 1];
    for (int i = lo; i < hi; i++) {
        int d = cursor[i];
        row_ptr[i] = base;
        cursor[i] = base;
        base += d;
    }
    if (t == 0) row_ptr[NN] = NE;
}

__global__ void fill_csr(const int* __restrict__ src, const int* __restrict__ dst,
                         int* __restrict__ cursor, int* __restrict__ csr_src,
                         int* __restrict__ csr_dst, int* __restrict__ csr_eid) {
    int e = blockIdx.x * blockDim.x + threadIdx.x;
    if (e < NE) {
        int d = dst[e];
        int pos = atomicAdd(&cursor[d], 1);
        csr_src[pos] = src[e];
        csr_dst[pos] = d;
        csr_eid[pos] = e;
    }
}

__global__ void loop_attr_kernel(const float* __restrict__ ef, const int* __restrict__ row_ptr,
                                 const int* __restrict__ csr_eid, float* __restrict__ loop_attr) {
    int idx = blockIdx.x * blockDim.x + threadIdx.x;
    if (idx >= NN * EDIM) return;
    int n = idx >> 5, c = idx & 31;
    int s = row_ptr[n], e = row_ptr[n + 1];
    float acc = 0.f;
    for (int j = s; j < e; j++) acc += ef[(size_t)csr_eid[j] * EDIM + c];
    int d = e - s;
    loop_attr[(size_t)n * EDIM + c] = acc / (float)max(d, 1);
}

// ---------------------------------------------------------------------------
// Weight pre-passes
// ---------------------------------------------------------------------------
// W[K][N] fp32 -> transposed bf16 hi/lo [N][K] (for MFMA GEMM)
__global__ void conv_wt(const float* __restrict__ W, unsigned short* __restrict__ hi,
                        unsigned short* __restrict__ lo, int K, int Nn) {
    int idx = blockIdx.x * blockDim.x + threadIdx.x;
    if (idx >= K * Nn) return;
    int k = idx / Nn, n = idx - k * Nn;
    float x = W[idx];
    unsigned short h = f2bf(x);
    unsigned short l = f2bf(x - bf2f(h));
    hi[(size_t)n * K + k] = h;
    lo[(size_t)n * K + k] = l;
}

// We[EDIM][HC] fp32 -> PERMUTED transposed bf16 hi/lo [HC][EDIM].
// Row r of Weth holds We column ((r&15)<<4)|(r>>4), so that the MFMA output
// channel at (tile ct, col m) is m*16+ct -> each lane owns 16 CONSECUTIVE
// channels in the score epilogue (float4 gathers instead of strided dwords).
__global__ void conv_wet(const float* __restrict__ We, unsigned short* __restrict__ hi,
                         unsigned short* __restrict__ lo) {
    int idx = blockIdx.x * blockDim.x + threadIdx.x;
    if (idx >= EDIM * HC) return;
    int k = idx / HC, c = idx - k * HC;
    float x = We[idx];
    unsigned short h = f2bf(x);
    unsigned short l = f2bf(x - bf2f(h));
    int r = ((c & 15) << 4) | (c >> 4);   // inverse of c = (r&15)*16 + (r>>4)
    hi[(size_t)r * EDIM + k] = h;
    lo[(size_t)r * EDIM + k] = l;
}

__global__ void concat_bias(const float* __restrict__ a, const float* __restrict__ b,
                            float* __restrict__ o) {
    int i = threadIdx.x;
    o[i] = a[i];
    o[i + HC] = b[i];
}

#define LDT 40

// ---------------------------------------------------------------------------
// Wide fused GEMM: C[M,512] = A[M,K] @ [Wl|Wr] + [bl|br].  Tile 64x128,
// 256 threads, 8 16x16 col-tiles per wave row-group. 3-term split-bf16.
// Output row stride XLR=512 (xl = cols 0..255, xr = cols 256..511).
// ---------------------------------------------------------------------------
__global__ __launch_bounds__(256, 2)
void gemm_wide(const float* __restrict__ A, const unsigned short* __restrict__ Bth,
               const unsigned short* __restrict__ Btl, const float* __restrict__ bias,
               float* __restrict__ C, int M, int K) {
    __shared__ unsigned short Ah[64][LDT], Al[64][LDT];
    __shared__ unsigned short Bh[128][LDT], Bl[128][LDT];
    int tid = threadIdx.x;
    int lane = tid & 63, w = tid >> 6;
    int m = lane & 15, q = lane >> 4;
    int rowBase = blockIdx.y * 64, colBase = blockIdx.x * 128;
    f32x4 acc[8];
    #pragma unroll
    for (int ct = 0; ct < 8; ct++) acc[ct] = (f32x4){0.f, 0.f, 0.f, 0.f};

    for (int kk = 0; kk < K; kk += 32) {
        // ---- stage A: 64 rows x 32 k fp32 -> hi/lo bf16 (2 float4 / thread)
        #pragma unroll
        for (int u = 0; u < 2; u++) {
            int f = tid + 256 * u;
            int r = f >> 3;
            int k4 = (f & 7) * 4;
            int row = rowBase + r;
            float4 v = make_float4(0.f, 0.f, 0.f, 0.f);
            if (row < M) v = *(const float4*)(A + (size_t)row * K + kk + k4);
            unsigned short h0 = f2bf(v.x), h1 = f2bf(v.y), h2 = f2bf(v.z), h3 = f2bf(v.w);
            unsigned short l0 = f2bf(v.x - bf2f(h0)), l1 = f2bf(v.y - bf2f(h1));
            unsigned short l2 = f2bf(v.z - bf2f(h2)), l3 = f2bf(v.w - bf2f(h3));
            *(u16x4*)&Ah[r][k4] = (u16x4){h0, h1, h2, h3};
            *(u16x4*)&Al[r][k4] = (u16x4){l0, l1, l2, l3};
        }
        // ---- stage B: 128 rows x 32 k bf16 hi/lo (2 chunks / thread)
        #pragma unroll
        for (int u = 0; u < 2; u++) {
            int f = tid + 256 * u;
            int n = f >> 2;
            int ch = f & 3;
            size_t goff = (size_t)(colBase + n) * K + kk + ch * 8;
            *(bf16x8*)&Bh[n][ch * 8] = *(const bf16x8*)(Bth + goff);
            *(bf16x8*)&Bl[n][ch * 8] = *(const bf16x8*)(Btl + goff);
        }
        __syncthreads();
        bf16x8 a_h = *(const bf16x8*)&Ah[w * 16 + m][q * 8];
        bf16x8 a_l = *(const bf16x8*)&Al[w * 16 + m][q * 8];
        #pragma unroll
        for (int ct = 0; ct < 8; ct++) {
            bf16x8 b_h = *(const bf16x8*)&Bh[ct * 16 + m][q * 8];
            bf16x8 b_l = *(const bf16x8*)&Bl[ct * 16 + m][q * 8];
            acc[ct] = __builtin_amdgcn_mfma_f32_16x16x32_bf16(a_h, b_h, acc[ct], 0, 0, 0);
            acc[ct] = __builtin_amdgcn_mfma_f32_16x16x32_bf16(a_l, b_h, acc[ct], 0, 0, 0);
            acc[ct] = __builtin_amdgcn_mfma_f32_16x16x32_bf16(a_h, b_l, acc[ct], 0, 0, 0);
        }
        __syncthreads();
    }
    #pragma unroll
    for (int ct = 0; ct < 8; ct++) {
        int col = colBase + ct * 16 + m;
        float bb = bias[col];
        #pragma unroll
        for (int r = 0; r < 4; r++) {
            int row = rowBase + w * 16 + q * 4 + r;
            if (row < M) C[(size_t)row * XLR + col] = acc[ct][r] + bb;
        }
    }
}

// ---------------------------------------------------------------------------
// MFMA split-bf16 GEMM (64x64) with fused LayerNorm epilogue (Nn==64).
// Used for the local head only.
// ---------------------------------------------------------------------------
__global__ __launch_bounds__(256, 2)
void gemm_head(const float* __restrict__ A, const unsigned short* __restrict__ Bth,
               const unsigned short* __restrict__ Btl, const float* __restrict__ bias,
               float* __restrict__ C, int M, int K,
               const float* __restrict__ ln_g, const float* __restrict__ ln_b) {
    __shared__ unsigned short Ah[64][LDT], Al[64][LDT];
    __shared__ unsigned short Bh[64][LDT], Bl[64][LDT];
    int tid = threadIdx.x;
    int lane = tid & 63, w = tid >> 6;
    int m = lane & 15, q = lane >> 4;
    int rowBase = blockIdx.y * 64;
    f32x4 acc[4];
    #pragma unroll
    for (int ct = 0; ct < 4; ct++) acc[ct] = (f32x4){0.f, 0.f, 0.f, 0.f};

    for (int kk = 0; kk < K; kk += 32) {
        #pragma unroll
        for (int u = 0; u < 2; u++) {
            int f = tid + 256 * u;
            int r = f >> 3;
            int k4 = (f & 7) * 4;
            int row = rowBase + r;
            float4 v = make_float4(0.f, 0.f, 0.f, 0.f);
            if (row < M) v = *(const float4*)(A + (size_t)row * K + kk + k4);
            unsigned short h0 = f2bf(v.x), h1 = f2bf(v.y), h2 = f2bf(v.z), h3 = f2bf(v.w);
            unsigned short l0 = f2bf(v.x - bf2f(h0)), l1 = f2bf(v.y - bf2f(h1));
            unsigned short l2 = f2bf(v.z - bf2f(h2)), l3 = f2bf(v.w - bf2f(h3));
            *(u16x4*)&Ah[r][k4] = (u16x4){h0, h1, h2, h3};
            *(u16x4*)&Al[r][k4] = (u16x4){l0, l1, l2, l3};
        }
        {
            int n = tid >> 2;
            int ch = tid & 3;
            size_t goff = (size_t)n * K + kk + ch * 8;
            *(bf16x8*)&Bh[n][ch * 8] = *(const bf16x8*)(Bth + goff);
            *(bf16x8*)&Bl[n][ch * 8] = *(const bf16x8*)(Btl + goff);
        }
        __syncthreads();
        bf16x8 a_h = *(const bf16x8*)&Ah[w * 16 + m][q * 8];
        bf16x8 a_l = *(const bf16x8*)&Al[w * 16 + m][q * 8];
        #pragma unroll
        for (int ct = 0; ct < 4; ct++) {
            bf16x8 b_h = *(const bf16x8*)&Bh[ct * 16 + m][q * 8];
            bf16x8 b_l = *(const bf16x8*)&Bl[ct * 16 + m][q * 8];
            acc[ct] = __builtin_amdgcn_mfma_f32_16x16x32_bf16(a_h, b_h, acc[ct], 0, 0, 0);
            acc[ct] = __builtin_amdgcn_mfma_f32_16x16x32_bf16(a_l, b_h, acc[ct], 0, 0, 0);
            acc[ct] = __builtin_amdgcn_mfma_f32_16x16x32_bf16(a_h, b_l, acc[ct], 0, 0, 0);
        }
        __syncthreads();
    }
    // LN epilogue: row held by 16 lanes (m) x 4 cols (ct)
    #pragma unroll
    for (int r = 0; r < 4; r++) {
        float v[4];
        float sum = 0.f;
        #pragma unroll
        for (int ct = 0; ct < 4; ct++) {
            v[ct] = acc[ct][r] + bias[ct * 16 + m];
            sum += v[ct];
        }
        sum += __shfl_xor(sum, 1); sum += __shfl_xor(sum, 2);
        sum += __shfl_xor(sum, 4); sum += __shfl_xor(sum, 8);
        float mu = sum * (1.f / 64.f);
        float sq = 0.f;
        #pragma unroll
        for (int ct = 0; ct < 4; ct++) {
            float d = v[ct] - mu;
            sq += d * d;
        }
        sq += __shfl_xor(sq, 1); sq += __shfl_xor(sq, 2);
        sq += __shfl_xor(sq, 4); sq += __shfl_xor(sq, 8);
        float inv = rsqrtf(sq * (1.f / 64.f) + LN_EPS);
        int row = rowBase + w * 16 + q * 4 + r;
        if (row < M) {
            #pragma unroll
            for (int ct = 0; ct < 4; ct++) {
                int col = ct * 16 + m;
                C[(size_t)row * 64 + col] = (v[ct] - mu) * inv * ln_g[col] + ln_b[col];
            }
        }
    }
}

// ---------------------------------------------------------------------------
// score_kernel (persistent): per 128-slot group, ee = ea @ We via split-bf16
// MFMA, fused GATv2 score epilogue -> alpha[slot][h]. We^T staged ONCE per
// block; blocks loop over slot groups (grid-stride).
// 512 threads (8 waves), 128-slot groups: LDS 61 KB -> 2 blocks/CU =
// 16 waves/CU (50% static occupancy vs 37.5% at 256-thread/64-slot).
// With the permuted Weth, MFMA output channel at (tile ct, col m) = m*16+ct:
// lane m owns channels [m*16 .. m*16+15] -> xl/xr gathered as 4 float4 each,
// head index = m>>2, reduction = 2 shfls.
// ---------------------------------------------------------------------------
__global__ __launch_bounds__(512, 4)
void score_kernel(const float* __restrict__ ef, const float* __restrict__ loop_attr,
                  const int* __restrict__ csr_eid, const int* __restrict__ csr_src,
                  const int* __restrict__ csr_dst,
                  const float* __restrict__ xlr,
                  const unsigned short* __restrict__ Weth,
                  const unsigned short* __restrict__ Wetl,
                  const float* __restrict__ att, float* __restrict__ alpha) {
    __shared__ unsigned short Ah[128][LDT], Al[128][LDT];
    __shared__ unsigned short Bh[256][LDT], Bl[256][LDT];
    __shared__ int s_src[128], s_dst[128];
    int tid = threadIdx.x;
    int lane = tid & 63, w = tid >> 6;
    int m = lane & 15, q = lane >> 4;

    // stage B (We^T permuted, [256][32] hi/lo) ONCE: 512 thr x 2 bf16x8 each
    {
        int rr = tid >> 1, hf = (tid & 1) * 16;
        *(bf16x8*)&Bh[rr][hf]     = *(const bf16x8*)(Weth + (size_t)rr * EDIM + hf);
        *(bf16x8*)&Bh[rr][hf + 8] = *(const bf16x8*)(Weth + (size_t)rr * EDIM + hf + 8);
        *(bf16x8*)&Bl[rr][hf]     = *(const bf16x8*)(Wetl + (size_t)rr * EDIM + hf);
        *(bf16x8*)&Bl[rr][hf + 8] = *(const bf16x8*)(Wetl + (size_t)rr * EDIM + hf + 8);
    }
    // attv[ct] = att coefficient of channel m*16+ct (consecutive -> float4 x4)
    float attv[16];
    #pragma unroll
    for (int u = 0; u < 4; u++) {
        float4 a4 = *(const float4*)(att + m * 16 + u * 4);
        attv[u * 4 + 0] = a4.x; attv[u * 4 + 1] = a4.y;
        attv[u * 4 + 2] = a4.z; attv[u * 4 + 3] = a4.w;
    }

    int groups = (EESLOTS + 127) >> 7;
    for (int g = blockIdx.x; g < groups; g += gridDim.x) {
        int base = g << 7;
        __syncthreads();   // protect Ah/Al + s_src reads of previous group
        // stage A: 128 slots x 32 k (gathered), split hi/lo; record src/dst
        {
            int r = tid >> 2, ch = tid & 3;
            int j = base + r;
            if (j >= EESLOTS) j = EESLOTS - 1;
            const float* srcp;
            int ss, dd;
            if (j < NE) {
                srcp = ef + (size_t)csr_eid[j] * EDIM;
                ss = csr_src[j]; dd = csr_dst[j];
            } else {
                int n = j - NE;
                srcp = loop_attr + (size_t)n * EDIM;
                ss = n; dd = n;
            }
            if (ch == 0) { s_src[r] = ss; s_dst[r] = dd; }
            float4 v0 = *(const float4*)(srcp + ch * 8);
            float4 v1 = *(const float4*)(srcp + ch * 8 + 4);
            float vv[8] = {v0.x, v0.y, v0.z, v0.w, v1.x, v1.y, v1.z, v1.w};
            unsigned short hh[8], ll[8];
            #pragma unroll
            for (int i = 0; i < 8; i++) {
                hh[i] = f2bf(vv[i]);
                ll[i] = f2bf(vv[i] - bf2f(hh[i]));
            }
            *(u16x4*)&Ah[r][ch * 8]     = (u16x4){hh[0], hh[1], hh[2], hh[3]};
            *(u16x4*)&Ah[r][ch * 8 + 4] = (u16x4){hh[4], hh[5], hh[6], hh[7]};
            *(u16x4*)&Al[r][ch * 8]     = (u16x4){ll[0], ll[1], ll[2], ll[3]};
            *(u16x4*)&Al[r][ch * 8 + 4] = (u16x4){ll[4], ll[5], ll[6], ll[7]};
        }
        __syncthreads();

        bf16x8 a_h = *(const bf16x8*)&Ah[w * 16 + m][q * 8];
        bf16x8 a_l = *(const bf16x8*)&Al[w * 16 + m][q * 8];
        f32x4 acc[16];
        #pragma unroll
        for (int ct = 0; ct < 16; ct++) {
            bf16x8 b_h = *(const bf16x8*)&Bh[ct * 16 + m][q * 8];
            bf16x8 b_l = *(const bf16x8*)&Bl[ct * 16 + m][q * 8];
            f32x4 c = (f32x4){0.f, 0.f, 0.f, 0.f};
            c = __builtin_amdgcn_mfma_f32_16x16x32_bf16(a_h, b_h, c, 0, 0, 0);
            c = __builtin_amdgcn_mfma_f32_16x16x32_bf16(a_l, b_h, c, 0, 0, 0);
            c = __builtin_amdgcn_mfma_f32_16x16x32_bf16(a_h, b_l, c, 0, 0, 0);
            acc[ct] = c;
        }

        // epilogue: per-slot score. Lane m owns channels [m*16 .. m*16+15].
        #pragma unroll
        for (int r = 0; r < 4; r++) {
            int sl = w * 16 + q * 4 + r;
            int slot = base + sl;
            int ss = s_src[sl], dd = s_dst[sl];
            const float* xlp = xlr + (size_t)ss * XLR + m * 16;         // xl part
            const float* xrp = xlr + (size_t)dd * XLR + HC + m * 16;    // xr part
            float4 xl0 = *(const float4*)(xlp + 0);
            float4 xl1 = *(const float4*)(xlp + 4);
            float4 xl2 = *(const float4*)(xlp + 8);
            float4 xl3 = *(const float4*)(xlp + 12);
            float4 xr0 = *(const float4*)(xrp + 0);
            float4 xr1 = *(const float4*)(xrp + 4);
            float4 xr2 = *(const float4*)(xrp + 8);
            float4 xr3 = *(const float4*)(xrp + 12);
            float xl[16] = {xl0.x, xl0.y, xl0.z, xl0.w, xl1.x, xl1.y, xl1.z, xl1.w,
                            xl2.x, xl2.y, xl2.z, xl2.w, xl3.x, xl3.y, xl3.z, xl3.w};
            float xr[16] = {xr0.x, xr0.y, xr0.z, xr0.w, xr1.x, xr1.y, xr1.z, xr1.w,
                            xr2.x, xr2.y, xr2.z, xr2.w, xr3.x, xr3.y, xr3.z, xr3.w};
            float s = 0.f;
            #pragma unroll
            for (int ct = 0; ct < 16; ct++) {
                float z = xl[ct] + xr[ct] + acc[ct][r];
                float lz = fmaxf(z, 0.f) + 0.2f * fminf(z, 0.f);
                s += lz * attv[ct];
            }
            // head h = m>>2: reduce over the 4 lanes m in [4h..4h+3]
            s += __shfl_xor(s, 1);
            s += __shfl_xor(s, 2);
            if ((m & 3) == 0 && slot < EESLOTS) {
                alpha[(size_t)slot * 4 + (m >> 2)] = s;
            }
        }
    }
}

// ---------------------------------------------------------------------------
// Lean aggregation: softmax over precomputed alpha (shift = alpha_self),
// weighted gather of xl (cols 0..255 of xlr). One wave per node, ILP x4.
// ---------------------------------------------------------------------------
__global__ __launch_bounds__(256)
void gat_aggr(const float* __restrict__ xlr, const float* __restrict__ alpha,
              const int* __restrict__ row_ptr, const int* __restrict__ csr_src,
              const float* __restrict__ bias, float* __restrict__ out, int do_relu) {
    int lane = threadIdx.x & 63;
    int wv = threadIdx.x >> 6;
    int n = blockIdx.x * 4 + wv;
    if (n >= NN) return;
    int h = lane >> 4;
    float4 bb = *(const float4*)(bias + 4 * lane);
    int s0 = row_ptr[n], e0 = row_ptr[n + 1];
    float aself = alpha[(size_t)(NE + n) * 4 + h];
    float denom = 1.f;
    float4 acc = *(const float4*)(xlr + (size_t)n * XLR + 4 * lane);

    for (int j0 = s0; j0 < e0; j0 += 64) {
        int cnt = min(64, e0 - j0);
        int sidx = (j0 + lane < e0) ? csr_src[j0 + lane] : 0;
        int t = 0;
        for (; t + 3 < cnt; t += 4) {
            int sa = __shfl(sidx, t);
            int sb = __shfl(sidx, t + 1);
            int sc = __shfl(sidx, t + 2);
            int sd = __shfl(sidx, t + 3);
            float a0 = __expf(alpha[(size_t)(j0 + t) * 4 + h] - aself);
            float a1 = __expf(alpha[(size_t)(j0 + t + 1) * 4 + h] - aself);
            float a2 = __expf(alpha[(size_t)(j0 + t + 2) * 4 + h] - aself);
            float a3 = __expf(alpha[(size_t)(j0 + t + 3) * 4 + h] - aself);
            float4 x0 = *(const float4*)(xlr + (size_t)sa * XLR + 4 * lane);
            float4 x1 = *(const float4*)(xlr + (size_t)sb * XLR + 4 * lane);
            float4 x2 = *(const float4*)(xlr + (size_t)sc * XLR + 4 * lane);
            float4 x3 = *(const float4*)(xlr + (size_t)sd * XLR + 4 * lane);
            denom += a0 + a1 + a2 + a3;
            acc.x += a0 * x0.x + a1 * x1.x + a2 * x2.x + a3 * x3.x;
            acc.y += a0 * x0.y + a1 * x1.y + a2 * x2.y + a3 * x3.y;
            acc.z += a0 * x0.z + a1 * x1.z + a2 * x2.z + a3 * x3.z;
            acc.w += a0 * x0.w + a1 * x1.w + a2 * x2.w + a3 * x3.w;
        }
        for (; t < cnt; t++) {
            int sa = __shfl(sidx, t);
            float a0 = __expf(alpha[(size_t)(j0 + t) * 4 + h] - aself);
            float4 x0 = *(const float4*)(xlr + (size_t)sa * XLR + 4 * lane);
            denom += a0;
            acc.x += a0 * x0.x; acc.y += a0 * x0.y;
            acc.z += a0 * x0.z; acc.w += a0 * x0.w;
        }
    }

    float inv = 1.f / denom;
    float4 r = make_float4(acc.x * inv + bb.x, acc.y * inv + bb.y,
                           acc.z * inv + bb.z, acc.w * inv + bb.w);
    if (do_relu) {
        r.x = fmaxf(r.x, 0.f); r.y = fmaxf(r.y, 0.f);
        r.z = fmaxf(r.z, 0.f); r.w = fmaxf(r.w, 0.f);
    }
    *(float4*)(out + (size_t)n * HC + 4 * lane) = r;
}

// ---------------------------------------------------------------------------
// Graph mean pre-reduction exploiting sorted batch
// ---------------------------------------------------------------------------
__global__ void graph_sum(const float* __restrict__ x, const int* __restrict__ batch,
                          float* __restrict__ gsum, float* __restrict__ gcnt) {
    int c = threadIdx.x;
    int r0 = blockIdx.x * 256;
    int r1 = min(r0 + 256, NN);
    float acc = 0.f;
    int gcur = batch[r0];
    for (int n = r0; n < r1; n++) {
        int g = batch[n];
        if (g != gcur) {
            atomicAdd(&gsum[(size_t)gcur * HC + c], acc);
            acc = 0.f; gcur = g;
        }
        acc += x[(size_t)n * HC + c];
    }
    atomicAdd(&gsum[(size_t)gcur * HC + c], acc);
    if (c == 0) {
        int cnt = 0; gcur = batch[r0];
        for (int n = r0; n < r1; n++) {
            int g = batch[n];
            if (g != gcur) {
                atomicAdd(&gcnt[gcur], (float)cnt);
                cnt = 0; gcur = g;
            }
            cnt++;
        }
        atomicAdd(&gcnt[gcur], (float)cnt);
    }
}

__global__ void glob_kernel(const float* __restrict__ gsum, const float* __restrict__ gcnt,
                            const float* __restrict__ W, const float* __restrict__ bias,
                            const float* __restrict__ g, const float* __restrict__ b,
                            float* __restrict__ out) {
    int gi = blockIdx.x;
    int lane = threadIdx.x;
    float inv = 1.f / fmaxf(gcnt[gi], 1.f);
    float acc = 0.f;
    for (int k = 0; k < HC; k++)
        acc += (gsum[(size_t)gi * HC + k] * inv) * W[(size_t)k * ND + lane];
    acc += bias[lane];
    float s = acc;
    #pragma unroll
    for (int o = 32; o >= 1; o >>= 1) s += __shfl_xor(s, o);
    float mu = s * (1.f / 64.f);
    float dv = acc - mu;
    float q = dv * dv;
    #pragma unroll
    for (int o = 32; o >= 1; o >>= 1) q += __shfl_xor(q, o);
    float var = q * (1.f / 64.f);
    out[(size_t)gi * ND + lane] = dv * rsqrtf(var + LN_EPS) * g[lane] + b[lane];
}

// ---------------------------------------------------------------------------
extern "C" void kernel_launch(void* const* d_in, const int* in_sizes, int n_in,
                              void* d_out, int out_size, void* d_ws, size_t ws_size,
                              hipStream_t stream) {
    (void)in_sizes; (void)n_in; (void)out_size; (void)ws_size;
    const float* node_feature = (const float*)d_in[0];
    const int*   edge_index   = (const int*)d_in[1];
    const float* edge_feature = (const float*)d_in[2];
    const int*   batch        = (const int*)d_in[3];
    const float* Wl0   = (const float*)d_in[4];
    const float* bl0   = (const float*)d_in[5];
    const float* Wr0   = (const float*)d_in[6];
    const float* br0   = (const float*)d_in[7];
    const float* We0   = (const float*)d_in[8];
    const float* att0  = (const float*)d_in[9];
    const float* bias0 = (const float*)d_in[10];
    const float* Wl1   = (const float*)d_in[11];
    const float* bl1   = (const float*)d_in[12];
    const float* Wr1   = (const float*)d_in[13];
    const float* br1   = (const float*)d_in[14];
    const float* We1   = (const float*)d_in[15];
    const float* att1  = (const float*)d_in[16];
    const float* bias1 = (const float*)d_in[17];
    const float* node_W  = (const float*)d_in[18];
    const float* node_b  = (const float*)d_in[19];
    const float* graph_W = (const float*)d_in[20];
    const float* graph_b = (const float*)d_in[21];
    const float* nn_g = (const float*)d_in[22];
    const float* nn_b = (const float*)d_in[23];
    const float* gn_g = (const float*)d_in[24];
    const float* gn_b = (const float*)d_in[25];

    const int* src = edge_index;
    const int* dst = edge_index + NE;

    char* p = (char*)d_ws;
    auto carve = [&](size_t bytes) {
        char* r = p;
        p += (bytes + 255) & ~(size_t)255;
        return r;
    };
    int*   row_ptr   = (int*)carve((NN + 1) * sizeof(int));
    int*   cursor    = (int*)carve(NN * sizeof(int));
    int*   csr_src   = (int*)carve((size_t)NE * sizeof(int));
    int*   csr_dst   = (int*)carve((size_t)NE * sizeof(int));
    int*   csr_eid   = (int*)carve((size_t)NE * sizeof(int));
    float* loop_attr = (float*)carve((size_t)NN * EDIM * sizeof(float));
    float* xlr       = (float*)carve((size_t)NN * XLR * sizeof(float));   // xl|xr fused
    float* xb        = (float*)carve((size_t)NN * HC * sizeof(float));
    float* alpha     = (float*)carve((size_t)EESLOTS * NH * sizeof(float));
    float* gsum      = (float*)carve((size_t)(NGG * HC + NGG) * sizeof(float));
    float* gcnt      = gsum + (size_t)NGG * HC;
    // concat bf16 transposed weights [512][K] hi/lo
    unsigned short* wlr0h = (unsigned short*)carve((size_t)XLR * DIN * 2 * 2);
    unsigned short* wlr0l = wlr0h + (size_t)XLR * DIN;
    unsigned short* wlr1h = (unsigned short*)carve((size_t)XLR * HC * 2 * 2);
    unsigned short* wlr1l = wlr1h + (size_t)XLR * HC;
    unsigned short* nwh   = (unsigned short*)carve((size_t)HC * ND * 2 * 2);
    unsigned short* nwl   = nwh + (size_t)HC * ND;
    unsigned short* we0h  = (unsigned short*)carve((size_t)EDIM * HC * 2 * 2);
    unsigned short* we0l  = we0h + (size_t)EDIM * HC;
    unsigned short* we1h  = (unsigned short*)carve((size_t)EDIM * HC * 2 * 2);
    unsigned short* we1l  = we1h + (size_t)EDIM * HC;
    float* b0cat = (float*)carve(XLR * sizeof(float));
    float* b1cat = (float*)carve(XLR * sizeof(float));

    hipMemsetAsync(cursor, 0, NN * sizeof(int), stream);
    hipMemsetAsync(gsum, 0, (NGG * HC + NGG) * sizeof(float), stream);

    // CSR + loop_attr + weight conversion (layer-independent)
    count_deg<<<(NE + 255) / 256, 256, 0, stream>>>(dst, cursor);
    scan_deg<<<1, 1024, 0, stream>>>(cursor, row_ptr);
    fill_csr<<<(NE + 255) / 256, 256, 0, stream>>>(src, dst, cursor, csr_src, csr_dst, csr_eid);
    loop_attr_kernel<<<(NN * EDIM + 255) / 256, 256, 0, stream>>>(edge_feature, row_ptr, csr_eid, loop_attr);
    conv_wt<<<(DIN * HC + 255) / 256, 256, 0, stream>>>(Wl0, wlr0h, wlr0l, DIN, HC);
    conv_wt<<<(DIN * HC + 255) / 256, 256, 0, stream>>>(Wr0, wlr0h + (size_t)HC * DIN, wlr0l + (size_t)HC * DIN, DIN, HC);
    conv_wt<<<(HC * HC + 255) / 256, 256, 0, stream>>>(Wl1, wlr1h, wlr1l, HC, HC);
    conv_wt<<<(HC * HC + 255) / 256, 256, 0, stream>>>(Wr1, wlr1h + (size_t)HC * HC, wlr1l + (size_t)HC * HC, HC, HC);
    conv_wt<<<(HC * ND + 255) / 256, 256, 0, stream>>>(node_W, nwh, nwl, HC, ND);
    conv_wet<<<(EDIM * HC + 255) / 256, 256, 0, stream>>>(We0, we0h, we0l);
    conv_wet<<<(EDIM * HC + 255) / 256, 256, 0, stream>>>(We1, we1h, we1l);
    concat_bias<<<1, 256, 0, stream>>>(bl0, br0, b0cat);
    concat_bias<<<1, 256, 0, stream>>>(bl1, br1, b1cat);

    dim3 gw(4, (NN + 63) / 64);
    // Layer 0
    gemm_wide<<<gw, 256, 0, stream>>>(node_feature, wlr0h, wlr0l, b0cat, xlr, NN, DIN);
    score_kernel<<<2048, 512, 0, stream>>>(edge_feature, loop_attr, csr_eid, csr_src, csr_dst,
                                           xlr, we0h, we0l, att0, alpha);
    gat_aggr<<<(NN + 3) / 4, 256, 0, stream>>>(xlr, alpha, row_ptr, csr_src, bias0, xb, 1);
    // Layer 1
    gemm_wide<<<gw, 256, 0, stream>>>(xb, wlr1h, wlr1l, b1cat, xlr, NN, HC);
    score_kernel<<<2048, 512, 0, stream>>>(edge_feature, loop_attr, csr_eid, csr_src, csr_dst,
                                           xlr, we1h, we1l, att1, alpha);
    gat_aggr<<<(NN + 3) / 4, 256, 0, stream>>>(xlr, alpha, row_ptr, csr_src, bias1, xb, 0);

    // Heads
    float* out_local = (float*)d_out;
    float* out_glob  = out_local + (size_t)NN * ND;
    dim3 gh(1, (NN + 63) / 64);
    gemm_head<<<gh, 256, 0, stream>>>(xb, nwh, nwl, node_b, out_local, NN, HC, nn_g, nn_b);
    graph_sum<<<(NN + 255) / 256, 256, 0, stream>>>(xb, batch, gsum, gcnt);
    glob_kernel<<<NGG, 64, 0, stream>>>(gsum, gcnt, graph_W, graph_b, gn_g, gn_b, out_glob);
}

// Round 4
// 1034.629 us; speedup vs baseline: 1.0673x; 1.0673x over previous
//
#include <hip/hip_runtime.h>
#include <cstdint>
#include <cstddef>

#define NN   50000
#define NE   500000
#define DIN  64
#define EDIM 32
#define NH   4
#define NC   64
#define HC   256   // NH*NC
#define NGG  64
#define ND   64
#define LN_EPS 1e-5f
#define EESLOTS (NE + NN)   // edges + self-loops, CSR-slot order
#define XLR  512            // row stride of fused xl|xr buffer

typedef __attribute__((ext_vector_type(8))) short bf16x8;
typedef __attribute__((ext_vector_type(4))) float f32x4;
typedef __attribute__((ext_vector_type(4))) unsigned short u16x4;

__device__ __forceinline__ unsigned short f2bf(float x) {
    unsigned u = __float_as_uint(x);
    unsigned r = (u + 0x7FFFu + ((u >> 16) & 1u)) >> 16;
    return (unsigned short)r;
}
__device__ __forceinline__ float bf2f(unsigned short h) {
    return __uint_as_float(((unsigned)h) << 16);
}

// ---------------------------------------------------------------------------
// CSR build: degree count -> single-block scan -> fill
// ---------------------------------------------------------------------------
__global__ void count_deg(const int* __restrict__ dst, int* __restrict__ deg) {
    int e = blockIdx.x * blockDim.x + threadIdx.x;
    if (e < NE) atomicAdd(&deg[dst[e]], 1);
}

__global__ void scan_deg(int* __restrict__ cursor, int* __restrict__ row_ptr) {
    __shared__ int sums[1024];
    const int T = 1024;
    const int chunk = (NN + T - 1) / T;  // 49
    int t = threadIdx.x;
    int lo = t * chunk, hi = min(lo + chunk, NN);
    int s = 0;
    for (int i = lo; i < hi; i++) s += cursor[i];
    sums[t] = s;
    __syncthreads();
    for (int off = 1; off < T; off <<= 1) {
        int v = (t >= off) ? sums[t - off] : 0;
        __syncthreads();
        sums[t] += v;
        __syncthreads();
    }
    int base = (t == 0) ? 0 : sums[t - 1];
    for (int i = lo; i < hi; i++) {
        int d = cursor[i];
        row_ptr[i] = base;
        cursor[i] = base;
        base += d;
    }
    if (t == 0) row_ptr[NN] = NE;
}

__global__ void fill_csr(const int* __restrict__ src, const int* __restrict__ dst,
                         int* __restrict__ cursor, int* __restrict__ csr_src,
                         int* __restrict__ csr_dst, int* __restrict__ csr_eid) {
    int e = blockIdx.x * blockDim.x + threadIdx.x;
    if (e < NE) {
        int d = dst[e];
        int pos = atomicAdd(&cursor[d], 1);
        csr_src[pos] = src[e];
        csr_dst[pos] = d;
        csr_eid[pos] = e;
    }
}

__global__ void loop_attr_kernel(const float* __restrict__ ef, const int* __restrict__ row_ptr,
                                 const int* __restrict__ csr_eid, float* __restrict__ loop_attr) {
    int idx = blockIdx.x * blockDim.x + threadIdx.x;
    if (idx >= NN * EDIM) return;
    int n = idx >> 5, c = idx & 31;
    int s = row_ptr[n], e = row_ptr[n + 1];
    float acc = 0.f;
    for (int j = s; j < e; j++) acc += ef[(size_t)csr_eid[j] * EDIM + c];
    int d = e - s;
    loop_attr[(size_t)n * EDIM + c] = acc / (float)max(d, 1);
}

// ---------------------------------------------------------------------------
// Weight pre-passes
// ---------------------------------------------------------------------------
// W[K][N] fp32 -> transposed bf16 hi/lo [N][K] (for MFMA GEMM)
__global__ void conv_wt(const float* __restrict__ W, unsigned short* __restrict__ hi,
                        unsigned short* __restrict__ lo, int K, int Nn) {
    int idx = blockIdx.x * blockDim.x + threadIdx.x;
    if (idx >= K * Nn) return;
    int k = idx / Nn, n = idx - k * Nn;
    float x = W[idx];
    unsigned short h = f2bf(x);
    unsigned short l = f2bf(x - bf2f(h));
    hi[(size_t)n * K + k] = h;
    lo[(size_t)n * K + k] = l;
}

// We[EDIM][HC] fp32 -> PERMUTED transposed bf16 hi/lo [HC][EDIM].
// Row r of Weth holds We column ((r&15)<<4)|(r>>4), so that the MFMA output
// channel at (tile ct, col m) is m*16+ct -> each lane owns 16 CONSECUTIVE
// channels in the score epilogue (float4 gathers instead of strided dwords).
__global__ void conv_wet(const float* __restrict__ We, unsigned short* __restrict__ hi,
                         unsigned short* __restrict__ lo) {
    int idx = blockIdx.x * blockDim.x + threadIdx.x;
    if (idx >= EDIM * HC) return;
    int k = idx / HC, c = idx - k * HC;
    float x = We[idx];
    unsigned short h = f2bf(x);
    unsigned short l = f2bf(x - bf2f(h));
    int r = ((c & 15) << 4) | (c >> 4);   // inverse of c = (r&15)*16 + (r>>4)
    hi[(size_t)r * EDIM + k] = h;
    lo[(size_t)r * EDIM + k] = l;
}

__global__ void concat_bias(const float* __restrict__ a, const float* __restrict__ b,
                            float* __restrict__ o) {
    int i = threadIdx.x;
    o[i] = a[i];
    o[i + HC] = b[i];
}

#define LDT 40

// ---------------------------------------------------------------------------
// Wide fused GEMM: C[M,512] = A[M,K] @ [Wl|Wr] + [bl|br].  Tile 64x128,
// 256 threads, 8 16x16 col-tiles per wave row-group. 3-term split-bf16.
// Output row stride XLR=512 (xl = cols 0..255, xr = cols 256..511).
// ---------------------------------------------------------------------------
__global__ __launch_bounds__(256, 2)
void gemm_wide(const float* __restrict__ A, const unsigned short* __restrict__ Bth,
               const unsigned short* __restrict__ Btl, const float* __restrict__ bias,
               float* __restrict__ C, int M, int K) {
    __shared__ unsigned short Ah[64][LDT], Al[64][LDT];
    __shared__ unsigned short Bh[128][LDT], Bl[128][LDT];
    int tid = threadIdx.x;
    int lane = tid & 63, w = tid >> 6;
    int m = lane & 15, q = lane >> 4;
    int rowBase = blockIdx.y * 64, colBase = blockIdx.x * 128;
    f32x4 acc[8];
    #pragma unroll
    for (int ct = 0; ct < 8; ct++) acc[ct] = (f32x4){0.f, 0.f, 0.f, 0.f};

    for (int kk = 0; kk < K; kk += 32) {
        // ---- stage A: 64 rows x 32 k fp32 -> hi/lo bf16 (2 float4 / thread)
        #pragma unroll
        for (int u = 0; u < 2; u++) {
            int f = tid + 256 * u;
            int r = f >> 3;
            int k4 = (f & 7) * 4;
            int row = rowBase + r;
            float4 v = make_float4(0.f, 0.f, 0.f, 0.f);
            if (row < M) v = *(const float4*)(A + (size_t)row * K + kk + k4);
            unsigned short h0 = f2bf(v.x), h1 = f2bf(v.y), h2 = f2bf(v.z), h3 = f2bf(v.w);
            unsigned short l0 = f2bf(v.x - bf2f(h0)), l1 = f2bf(v.y - bf2f(h1));
            unsigned short l2 = f2bf(v.z - bf2f(h2)), l3 = f2bf(v.w - bf2f(h3));
            *(u16x4*)&Ah[r][k4] = (u16x4){h0, h1, h2, h3};
            *(u16x4*)&Al[r][k4] = (u16x4){l0, l1, l2, l3};
        }
        // ---- stage B: 128 rows x 32 k bf16 hi/lo (2 chunks / thread)
        #pragma unroll
        for (int u = 0; u < 2; u++) {
            int f = tid + 256 * u;
            int n = f >> 2;
            int ch = f & 3;
            size_t goff = (size_t)(colBase + n) * K + kk + ch * 8;
            *(bf16x8*)&Bh[n][ch * 8] = *(const bf16x8*)(Bth + goff);
            *(bf16x8*)&Bl[n][ch * 8] = *(const bf16x8*)(Btl + goff);
        }
        __syncthreads();
        bf16x8 a_h = *(const bf16x8*)&Ah[w * 16 + m][q * 8];
        bf16x8 a_l = *(const bf16x8*)&Al[w * 16 + m][q * 8];
        #pragma unroll
        for (int ct = 0; ct < 8; ct++) {
            bf16x8 b_h = *(const bf16x8*)&Bh[ct * 16 + m][q * 8];
            bf16x8 b_l = *(const bf16x8*)&Bl[ct * 16 + m][q * 8];
            acc[ct] = __builtin_amdgcn_mfma_f32_16x16x32_bf16(a_h, b_h, acc[ct], 0, 0, 0);
            acc[ct] = __builtin_amdgcn_mfma_f32_16x16x32_bf16(a_l, b_h, acc[ct], 0, 0, 0);
            acc[ct] = __builtin_amdgcn_mfma_f32_16x16x32_bf16(a_h, b_l, acc[ct], 0, 0, 0);
        }
        __syncthreads();
    }
    #pragma unroll
    for (int ct = 0; ct < 8; ct++) {
        int col = colBase + ct * 16 + m;
        float bb = bias[col];
        #pragma unroll
        for (int r = 0; r < 4; r++) {
            int row = rowBase + w * 16 + q * 4 + r;
            if (row < M) C[(size_t)row * XLR + col] = acc[ct][r] + bb;
        }
    }
}

// ---------------------------------------------------------------------------
// MFMA split-bf16 GEMM (64x64) with fused LayerNorm epilogue (Nn==64).
// Used for the local head only.
// ---------------------------------------------------------------------------
__global__ __launch_bounds__(256, 2)
void gemm_head(const float* __restrict__ A, const unsigned short* __restrict__ Bth,
               const unsigned short* __restrict__ Btl, const float* __restrict__ bias,
               float* __restrict__ C, int M, int K,
               const float* __restrict__ ln_g, const float* __restrict__ ln_b) {
    __shared__ unsigned short Ah[64][LDT], Al[64][LDT];
    __shared__ unsigned short Bh[64][LDT], Bl[64][LDT];
    int tid = threadIdx.x;
    int lane = tid & 63, w = tid >> 6;
    int m = lane & 15, q = lane >> 4;
    int rowBase = blockIdx.y * 64;
    f32x4 acc[4];
    #pragma unroll
    for (int ct = 0; ct < 4; ct++) acc[ct] = (f32x4){0.f, 0.f, 0.f, 0.f};

    for (int kk = 0; kk < K; kk += 32) {
        #pragma unroll
        for (int u = 0; u < 2; u++) {
            int f = tid + 256 * u;
            int r = f >> 3;
            int k4 = (f & 7) * 4;
            int row = rowBase + r;
            float4 v = make_float4(0.f, 0.f, 0.f, 0.f);
            if (row < M) v = *(const float4*)(A + (size_t)row * K + kk + k4);
            unsigned short h0 = f2bf(v.x), h1 = f2bf(v.y), h2 = f2bf(v.z), h3 = f2bf(v.w);
            unsigned short l0 = f2bf(v.x - bf2f(h0)), l1 = f2bf(v.y - bf2f(h1));
            unsigned short l2 = f2bf(v.z - bf2f(h2)), l3 = f2bf(v.w - bf2f(h3));
            *(u16x4*)&Ah[r][k4] = (u16x4){h0, h1, h2, h3};
            *(u16x4*)&Al[r][k4] = (u16x4){l0, l1, l2, l3};
        }
        {
            int n = tid >> 2;
            int ch = tid & 3;
            size_t goff = (size_t)n * K + kk + ch * 8;
            *(bf16x8*)&Bh[n][ch * 8] = *(const bf16x8*)(Bth + goff);
            *(bf16x8*)&Bl[n][ch * 8] = *(const bf16x8*)(Btl + goff);
        }
        __syncthreads();
        bf16x8 a_h = *(const bf16x8*)&Ah[w * 16 + m][q * 8];
        bf16x8 a_l = *(const bf16x8*)&Al[w * 16 + m][q * 8];
        #pragma unroll
        for (int ct = 0; ct < 4; ct++) {
            bf16x8 b_h = *(const bf16x8*)&Bh[ct * 16 + m][q * 8];
            bf16x8 b_l = *(const bf16x8*)&Bl[ct * 16 + m][q * 8];
            acc[ct] = __builtin_amdgcn_mfma_f32_16x16x32_bf16(a_h, b_h, acc[ct], 0, 0, 0);
            acc[ct] = __builtin_amdgcn_mfma_f32_16x16x32_bf16(a_l, b_h, acc[ct], 0, 0, 0);
            acc[ct] = __builtin_amdgcn_mfma_f32_16x16x32_bf16(a_h, b_l, acc[ct], 0, 0, 0);
        }
        __syncthreads();
    }
    // LN epilogue: row held by 16 lanes (m) x 4 cols (ct)
    #pragma unroll
    for (int r = 0; r < 4; r++) {
        float v[4];
        float sum = 0.f;
        #pragma unroll
        for (int ct = 0; ct < 4; ct++) {
            v[ct] = acc[ct][r] + bias[ct * 16 + m];
            sum += v[ct];
        }
        sum += __shfl_xor(sum, 1); sum += __shfl_xor(sum, 2);
        sum += __shfl_xor(sum, 4); sum += __shfl_xor(sum, 8);
        float mu = sum * (1.f / 64.f);
        float sq = 0.f;
        #pragma unroll
        for (int ct = 0; ct < 4; ct++) {
            float d = v[ct] - mu;
            sq += d * d;
        }
        sq += __shfl_xor(sq, 1); sq += __shfl_xor(sq, 2);
        sq += __shfl_xor(sq, 4); sq += __shfl_xor(sq, 8);
        float inv = rsqrtf(sq * (1.f / 64.f) + LN_EPS);
        int row = rowBase + w * 16 + q * 4 + r;
        if (row < M) {
            #pragma unroll
            for (int ct = 0; ct < 4; ct++) {
                int col = ct * 16 + m;
                C[(size_t)row * 64 + col] = (v[ct] - mu) * inv * ln_g[col] + ln_b[col];
            }
        }
    }
}

// ---------------------------------------------------------------------------
// score_kernel (persistent): per 64-slot group, ee = ea @ We via split-bf16
// MFMA, fused GATv2 score epilogue -> alpha[slot][h]. We^T staged ONCE per
// block. XCD-CHUNKED group assignment: blocks dispatch round-robin over the
// 8 XCDs, so rank = (b&7)*256 + (b>>3) makes same-XCD blocks cover a
// CONTIGUOUS span of slot groups -> dst-run (xr row) reuse and src overlap
// hit the same 4 MB XCD-L2 instead of re-fetching from L3.
// ---------------------------------------------------------------------------
__global__ __launch_bounds__(256, 2)
void score_kernel(const float* __restrict__ ef, const float* __restrict__ loop_attr,
                  const int* __restrict__ csr_eid, const int* __restrict__ csr_src,
                  const int* __restrict__ csr_dst,
                  const float* __restrict__ xlr,
                  const unsigned short* __restrict__ Weth,
                  const unsigned short* __restrict__ Wetl,
                  const float* __restrict__ att, float* __restrict__ alpha) {
    __shared__ unsigned short Ah[64][LDT], Al[64][LDT];
    __shared__ unsigned short Bh[256][LDT], Bl[256][LDT];
    __shared__ int s_src[64], s_dst[64];
    int tid = threadIdx.x;
    int lane = tid & 63, w = tid >> 6;
    int m = lane & 15, q = lane >> 4;

    // stage B (We^T permuted, [256][32] hi/lo) ONCE
    #pragma unroll
    for (int u = 0; u < 4; u++) {
        *(bf16x8*)&Bh[tid][u * 8] = *(const bf16x8*)(Weth + (size_t)tid * EDIM + u * 8);
        *(bf16x8*)&Bl[tid][u * 8] = *(const bf16x8*)(Wetl + (size_t)tid * EDIM + u * 8);
    }
    // attv[ct] = att coefficient of channel m*16+ct (consecutive -> float4 x4)
    float attv[16];
    #pragma unroll
    for (int u = 0; u < 4; u++) {
        float4 a4 = *(const float4*)(att + m * 16 + u * 4);
        attv[u * 4 + 0] = a4.x; attv[u * 4 + 1] = a4.y;
        attv[u * 4 + 2] = a4.z; attv[u * 4 + 3] = a4.w;
    }

    // XCD-chunked contiguous span (grid is exactly 2048 = 8 XCD * 256)
    int groups = (EESLOTS + 63) >> 6;
    int rank = ((blockIdx.x & 7) << 8) | (blockIdx.x >> 3);
    int g0 = (int)(((long)rank * groups) >> 11);
    int g1 = (int)(((long)(rank + 1) * groups) >> 11);
    for (int g = g0; g < g1; g++) {
        int base = g << 6;
        __syncthreads();   // protect Ah/Al + s_src reads of previous group
        // stage A: 64 slots x 32 k (gathered), split hi/lo; record src/dst
        {
            int r = tid >> 2, ch = tid & 3;
            int j = base + r;
            if (j >= EESLOTS) j = EESLOTS - 1;
            const float* srcp;
            int ss, dd;
            if (j < NE) {
                srcp = ef + (size_t)csr_eid[j] * EDIM;
                ss = csr_src[j]; dd = csr_dst[j];
            } else {
                int n = j - NE;
                srcp = loop_attr + (size_t)n * EDIM;
                ss = n; dd = n;
            }
            if (ch == 0) { s_src[r] = ss; s_dst[r] = dd; }
            float4 v0 = *(const float4*)(srcp + ch * 8);
            float4 v1 = *(const float4*)(srcp + ch * 8 + 4);
            float vv[8] = {v0.x, v0.y, v0.z, v0.w, v1.x, v1.y, v1.z, v1.w};
            unsigned short hh[8], ll[8];
            #pragma unroll
            for (int i = 0; i < 8; i++) {
                hh[i] = f2bf(vv[i]);
                ll[i] = f2bf(vv[i] - bf2f(hh[i]));
            }
            *(u16x4*)&Ah[r][ch * 8]     = (u16x4){hh[0], hh[1], hh[2], hh[3]};
            *(u16x4*)&Ah[r][ch * 8 + 4] = (u16x4){hh[4], hh[5], hh[6], hh[7]};
            *(u16x4*)&Al[r][ch * 8]     = (u16x4){ll[0], ll[1], ll[2], ll[3]};
            *(u16x4*)&Al[r][ch * 8 + 4] = (u16x4){ll[4], ll[5], ll[6], ll[7]};
        }
        __syncthreads();

        bf16x8 a_h = *(const bf16x8*)&Ah[w * 16 + m][q * 8];
        bf16x8 a_l = *(const bf16x8*)&Al[w * 16 + m][q * 8];
        f32x4 acc[16];
        #pragma unroll
        for (int ct = 0; ct < 16; ct++) {
            bf16x8 b_h = *(const bf16x8*)&Bh[ct * 16 + m][q * 8];
            bf16x8 b_l = *(const bf16x8*)&Bl[ct * 16 + m][q * 8];
            f32x4 c = (f32x4){0.f, 0.f, 0.f, 0.f};
            c = __builtin_amdgcn_mfma_f32_16x16x32_bf16(a_h, b_h, c, 0, 0, 0);
            c = __builtin_amdgcn_mfma_f32_16x16x32_bf16(a_l, b_h, c, 0, 0, 0);
            c = __builtin_amdgcn_mfma_f32_16x16x32_bf16(a_h, b_l, c, 0, 0, 0);
            acc[ct] = c;
        }

        // epilogue: per-slot score. Lane m owns channels [m*16 .. m*16+15].
        #pragma unroll
        for (int r = 0; r < 4; r++) {
            int sl = w * 16 + q * 4 + r;
            int slot = base + sl;
            int ss = s_src[sl], dd = s_dst[sl];
            const float* xlp = xlr + (size_t)ss * XLR + m * 16;         // xl part
            const float* xrp = xlr + (size_t)dd * XLR + HC + m * 16;    // xr part
            float4 xl0 = *(const float4*)(xlp + 0);
            float4 xl1 = *(const float4*)(xlp + 4);
            float4 xl2 = *(const float4*)(xlp + 8);
            float4 xl3 = *(const float4*)(xlp + 12);
            float4 xr0 = *(const float4*)(xrp + 0);
            float4 xr1 = *(const float4*)(xrp + 4);
            float4 xr2 = *(const float4*)(xrp + 8);
            float4 xr3 = *(const float4*)(xrp + 12);
            float xl[16] = {xl0.x, xl0.y, xl0.z, xl0.w, xl1.x, xl1.y, xl1.z, xl1.w,
                            xl2.x, xl2.y, xl2.z, xl2.w, xl3.x, xl3.y, xl3.z, xl3.w};
            float xr[16] = {xr0.x, xr0.y, xr0.z, xr0.w, xr1.x, xr1.y, xr1.z, xr1.w,
                            xr2.x, xr2.y, xr2.z, xr2.w, xr3.x, xr3.y, xr3.z, xr3.w};
            float s = 0.f;
            #pragma unroll
            for (int ct = 0; ct < 16; ct++) {
                float z = xl[ct] + xr[ct] + acc[ct][r];
                float lz = fmaxf(z, 0.f) + 0.2f * fminf(z, 0.f);
                s += lz * attv[ct];
            }
            // head h = m>>2: reduce over the 4 lanes m in [4h..4h+3]
            s += __shfl_xor(s, 1);
            s += __shfl_xor(s, 2);
            if ((m & 3) == 0 && slot < EESLOTS) {
                alpha[(size_t)slot * 4 + (m >> 2)] = s;
            }
        }
    }
}

// ---------------------------------------------------------------------------
// Lean aggregation: softmax over precomputed alpha (shift = alpha_self),
// weighted gather of xl (cols 0..255 of xlr). One wave per node, ILP x4.
// XCD-chunked node assignment (bijective, 12500 blocks): same-XCD blocks
// cover contiguous node (=dst/alpha) ranges.
// ---------------------------------------------------------------------------
__global__ __launch_bounds__(256)
void gat_aggr(const float* __restrict__ xlr, const float* __restrict__ alpha,
              const int* __restrict__ row_ptr, const int* __restrict__ csr_src,
              const float* __restrict__ bias, float* __restrict__ out, int do_relu) {
    int lane = threadIdx.x & 63;
    int wv = threadIdx.x >> 6;
    // bijective XCD chunking: nwg = 12500, q = 1562, rem = 4
    int xcd = blockIdx.x & 7;
    int i = blockIdx.x >> 3;
    int rank = (xcd < 4 ? xcd * 1563 : 4 * 1563 + (xcd - 4) * 1562) + i;
    int n = rank * 4 + wv;
    if (n >= NN) return;
    int h = lane >> 4;
    float4 bb = *(const float4*)(bias + 4 * lane);
    int s0 = row_ptr[n], e0 = row_ptr[n + 1];
    float aself = alpha[(size_t)(NE + n) * 4 + h];
    float denom = 1.f;
    float4 acc = *(const float4*)(xlr + (size_t)n * XLR + 4 * lane);

    for (int j0 = s0; j0 < e0; j0 += 64) {
        int cnt = min(64, e0 - j0);
        int sidx = (j0 + lane < e0) ? csr_src[j0 + lane] : 0;
        int t = 0;
        for (; t + 3 < cnt; t += 4) {
            int sa = __shfl(sidx, t);
            int sb = __shfl(sidx, t + 1);
            int sc = __shfl(sidx, t + 2);
            int sd = __shfl(sidx, t + 3);
            float a0 = __expf(alpha[(size_t)(j0 + t) * 4 + h] - aself);
            float a1 = __expf(alpha[(size_t)(j0 + t + 1) * 4 + h] - aself);
            float a2 = __expf(alpha[(size_t)(j0 + t + 2) * 4 + h] - aself);
            float a3 = __expf(alpha[(size_t)(j0 + t + 3) * 4 + h] - aself);
            float4 x0 = *(const float4*)(xlr + (size_t)sa * XLR + 4 * lane);
            float4 x1 = *(const float4*)(xlr + (size_t)sb * XLR + 4 * lane);
            float4 x2 = *(const float4*)(xlr + (size_t)sc * XLR + 4 * lane);
            float4 x3 = *(const float4*)(xlr + (size_t)sd * XLR + 4 * lane);
            denom += a0 + a1 + a2 + a3;
            acc.x += a0 * x0.x + a1 * x1.x + a2 * x2.x + a3 * x3.x;
            acc.y += a0 * x0.y + a1 * x1.y + a2 * x2.y + a3 * x3.y;
            acc.z += a0 * x0.z + a1 * x1.z + a2 * x2.z + a3 * x3.z;
            acc.w += a0 * x0.w + a1 * x1.w + a2 * x2.w + a3 * x3.w;
        }
        for (; t < cnt; t++) {
            int sa = __shfl(sidx, t);
            float a0 = __expf(alpha[(size_t)(j0 + t) * 4 + h] - aself);
            float4 x0 = *(const float4*)(xlr + (size_t)sa * XLR + 4 * lane);
            denom += a0;
            acc.x += a0 * x0.x; acc.y += a0 * x0.y;
            acc.z += a0 * x0.z; acc.w += a0 * x0.w;
        }
    }

    float inv = 1.f / denom;
    float4 r = make_float4(acc.x * inv + bb.x, acc.y * inv + bb.y,
                           acc.z * inv + bb.z, acc.w * inv + bb.w);
    if (do_relu) {
        r.x = fmaxf(r.x, 0.f); r.y = fmaxf(r.y, 0.f);
        r.z = fmaxf(r.z, 0.f); r.w = fmaxf(r.w, 0.f);
    }
    *(float4*)(out + (size_t)n * HC + 4 * lane) = r;
}

// ---------------------------------------------------------------------------
// Graph mean pre-reduction exploiting sorted batch
// ---------------------------------------------------------------------------
__global__ void graph_sum(const float* __restrict__ x, const int* __restrict__ batch,
                          float* __restrict__ gsum, float* __restrict__ gcnt) {
    int c = threadIdx.x;
    int r0 = blockIdx.x * 256;
    int r1 = min(r0 + 256, NN);
    float acc = 0.f;
    int gcur = batch[r0];
    for (int n = r0; n < r1; n++) {
        int g = batch[n];
        if (g != gcur) {
            atomicAdd(&gsum[(size_t)gcur * HC + c], acc);
            acc = 0.f; gcur = g;
        }
        acc += x[(size_t)n * HC + c];
    }
    atomicAdd(&gsum[(size_t)gcur * HC + c], acc);
    if (c == 0) {
        int cnt = 0; gcur = batch[r0];
        for (int n = r0; n < r1; n++) {
            int g = batch[n];
            if (g != gcur) {
                atomicAdd(&gcnt[gcur], (float)cnt);
                cnt = 0; gcur = g;
            }
            cnt++;
        }
        atomicAdd(&gcnt[gcur], (float)cnt);
    }
}

__global__ void glob_kernel(const float* __restrict__ gsum, const float* __restrict__ gcnt,
                            const float* __restrict__ W, const float* __restrict__ bias,
                            const float* __restrict__ g, const float* __restrict__ b,
                            float* __restrict__ out) {
    int gi = blockIdx.x;
    int lane = threadIdx.x;
    float inv = 1.f / fmaxf(gcnt[gi], 1.f);
    float acc = 0.f;
    for (int k = 0; k < HC; k++)
        acc += (gsum[(size_t)gi * HC + k] * inv) * W[(size_t)k * ND + lane];
    acc += bias[lane];
    float s = acc;
    #pragma unroll
    for (int o = 32; o >= 1; o >>= 1) s += __shfl_xor(s, o);
    float mu = s * (1.f / 64.f);
    float dv = acc - mu;
    float q = dv * dv;
    #pragma unroll
    for (int o = 32; o >= 1; o >>= 1) q += __shfl_xor(q, o);
    float var = q * (1.f / 64.f);
    out[(size_t)gi * ND + lane] = dv * rsqrtf(var + LN_EPS) * g[lane] + b[lane];
}

// ---------------------------------------------------------------------------
extern "C" void kernel_launch(void* const* d_in, const int* in_sizes, int n_in,
                              void* d_out, int out_size, void* d_ws, size_t ws_size,
                              hipStream_t stream) {
    (void)in_sizes; (void)n_in; (void)out_size; (void)ws_size;
    const float* node_feature = (const float*)d_in[0];
    const int*   edge_index   = (const int*)d_in[1];
    const float* edge_feature = (const float*)d_in[2];
    const int*   batch        = (const int*)d_in[3];
    const float* Wl0   = (const float*)d_in[4];
    const float* bl0   = (const float*)d_in[5];
    const float* Wr0   = (const float*)d_in[6];
    const float* br0   = (const float*)d_in[7];
    const float* We0   = (const float*)d_in[8];
    const float* att0  = (const float*)d_in[9];
    const float* bias0 = (const float*)d_in[10];
    const float* Wl1   = (const float*)d_in[11];
    const float* bl1   = (const float*)d_in[12];
    const float* Wr1   = (const float*)d_in[13];
    const float* br1   = (const float*)d_in[14];
    const float* We1   = (const float*)d_in[15];
    const float* att1  = (const float*)d_in[16];
    const float* bias1 = (const float*)d_in[17];
    const float* node_W  = (const float*)d_in[18];
    const float* node_b  = (const float*)d_in[19];
    const float* graph_W = (const float*)d_in[20];
    const float* graph_b = (const float*)d_in[21];
    const float* nn_g = (const float*)d_in[22];
    const float* nn_b = (const float*)d_in[23];
    const float* gn_g = (const float*)d_in[24];
    const float* gn_b = (const float*)d_in[25];

    const int* src = edge_index;
    const int* dst = edge_index + NE;

    char* p = (char*)d_ws;
    auto carve = [&](size_t bytes) {
        char* r = p;
        p += (bytes + 255) & ~(size_t)255;
        return r;
    };
    int*   row_ptr   = (int*)carve((NN + 1) * sizeof(int));
    int*   cursor    = (int*)carve(NN * sizeof(int));
    int*   csr_src   = (int*)carve((size_t)NE * sizeof(int));
    int*   csr_dst   = (int*)carve((size_t)NE * sizeof(int));
    int*   csr_eid   = (int*)carve((size_t)NE * sizeof(int));
    float* loop_attr = (float*)carve((size_t)NN * EDIM * sizeof(float));
    float* xlr       = (float*)carve((size_t)NN * XLR * sizeof(float));   // xl|xr fused
    float* xb        = (float*)carve((size_t)NN * HC * sizeof(float));
    float* alpha     = (float*)carve((size_t)EESLOTS * NH * sizeof(float));
    float* gsum      = (float*)carve((size_t)(NGG * HC + NGG) * sizeof(float));
    float* gcnt      = gsum + (size_t)NGG * HC;
    // concat bf16 transposed weights [512][K] hi/lo
    unsigned short* wlr0h = (unsigned short*)carve((size_t)XLR * DIN * 2 * 2);
    unsigned short* wlr0l = wlr0h + (size_t)XLR * DIN;
    unsigned short* wlr1h = (unsigned short*)carve((size_t)XLR * HC * 2 * 2);
    unsigned short* wlr1l = wlr1h + (size_t)XLR * HC;
    unsigned short* nwh   = (unsigned short*)carve((size_t)HC * ND * 2 * 2);
    unsigned short* nwl   = nwh + (size_t)HC * ND;
    unsigned short* we0h  = (unsigned short*)carve((size_t)EDIM * HC * 2 * 2);
    unsigned short* we0l  = we0h + (size_t)EDIM * HC;
    unsigned short* we1h  = (unsigned short*)carve((size_t)EDIM * HC * 2 * 2);
    unsigned short* we1l  = we1h + (size_t)EDIM * HC;
    float* b0cat = (float*)carve(XLR * sizeof(float));
    float* b1cat = (float*)carve(XLR * sizeof(float));

    hipMemsetAsync(cursor, 0, NN * sizeof(int), stream);
    hipMemsetAsync(gsum, 0, (NGG * HC + NGG) * sizeof(float), stream);

    // CSR + loop_attr + weight conversion (layer-independent)
    count_deg<<<(NE + 255) / 256, 256, 0, stream>>>(dst, cursor);
    scan_deg<<<1, 1024, 0, stream>>>(cursor, row_ptr);
    fill_csr<<<(NE + 255) / 256, 256, 0, stream>>>(src, dst, cursor, csr_src, csr_dst, csr_eid);
    loop_attr_kernel<<<(NN * EDIM + 255) / 256, 256, 0, stream>>>(edge_feature, row_ptr, csr_eid, loop_attr);
    conv_wt<<<(DIN * HC + 255) / 256, 256, 0, stream>>>(Wl0, wlr0h, wlr0l, DIN, HC);
    conv_wt<<<(DIN * HC + 255) / 256, 256, 0, stream>>>(Wr0, wlr0h + (size_t)HC * DIN, wlr0l + (size_t)HC * DIN, DIN, HC);
    conv_wt<<<(HC * HC + 255) / 256, 256, 0, stream>>>(Wl1, wlr1h, wlr1l, HC, HC);
    conv_wt<<<(HC * HC + 255) / 256, 256, 0, stream>>>(Wr1, wlr1h + (size_t)HC * HC, wlr1l + (size_t)HC * HC, HC, HC);
    conv_wt<<<(HC * ND + 255) / 256, 256, 0, stream>>>(node_W, nwh, nwl, HC, ND);
    conv_wet<<<(EDIM * HC + 255) / 256, 256, 0, stream>>>(We0, we0h, we0l);
    conv_wet<<<(EDIM * HC + 255) / 256, 256, 0, stream>>>(We1, we1h, we1l);
    concat_bias<<<1, 256, 0, stream>>>(bl0, br0, b0cat);
    concat_bias<<<1, 256, 0, stream>>>(bl1, br1, b1cat);

    dim3 gw(4, (NN + 63) / 64);
    // Layer 0
    gemm_wide<<<gw, 256, 0, stream>>>(node_feature, wlr0h, wlr0l, b0cat, xlr, NN, DIN);
    score_kernel<<<2048, 256, 0, stream>>>(edge_feature, loop_attr, csr_eid, csr_src, csr_dst,
                                           xlr, we0h, we0l, att0, alpha);
    gat_aggr<<<(NN + 3) / 4, 256, 0, stream>>>(xlr, alpha, row_ptr, csr_src, bias0, xb, 1);
    // Layer 1
    gemm_wide<<<gw, 256, 0, stream>>>(xb, wlr1h, wlr1l, b1cat, xlr, NN, HC);
    score_kernel<<<2048, 256, 0, stream>>>(edge_feature, loop_attr, csr_eid, csr_src, csr_dst,
                                           xlr, we1h, we1l, att1, alpha);
    gat_aggr<<<(NN + 3) / 4, 256, 0, stream>>>(xlr, alpha, row_ptr, csr_src, bias1, xb, 0);

    // Heads
    float* out_local = (float*)d_out;
    float* out_glob  = out_local + (size_t)NN * ND;
    dim3 gh(1, (NN + 63) / 64);
    gemm_head<<<gh, 256, 0, stream>>>(xb, nwh, nwl, node_b, out_local, NN, HC, nn_g, nn_b);
    graph_sum<<<(NN + 255) / 256, 256, 0, stream>>>(xb, batch, gsum, gcnt);
    glob_kernel<<<NGG, 64, 0, stream>>>(gsum, gcnt, graph_W, graph_b, gn_g, gn_b, out_glob);
}

// Round 5
// 997.751 us; speedup vs baseline: 1.1068x; 1.0370x over previous
//
#include <hip/hip_runtime.h>
#include <cstdint>
#include <cstddef>

#define NN   50000
#define NE   500000
#define DIN  64
#define EDIM 32
#define NH   4
#define NC   64
#define HC   256   // NH*NC
#define NGG  64
#define ND   64
#define LN_EPS 1e-5f
#define EESLOTS (NE + NN)   // edges + self-loops, CSR-slot order
#define XLR  512            // row stride of fused xl|xr buffer

typedef __attribute__((ext_vector_type(8))) short bf16x8;
typedef __attribute__((ext_vector_type(4))) float f32x4;
typedef __attribute__((ext_vector_type(4))) unsigned short u16x4;

__device__ __forceinline__ unsigned short f2bf(float x) {
    unsigned u = __float_as_uint(x);
    unsigned r = (u + 0x7FFFu + ((u >> 16) & 1u)) >> 16;
    return (unsigned short)r;
}
__device__ __forceinline__ float bf2f(unsigned short h) {
    return __uint_as_float(((unsigned)h) << 16);
}

// ---------------------------------------------------------------------------
// CSR build: degree count -> single-block scan -> fill
// ---------------------------------------------------------------------------
__global__ void count_deg(const int* __restrict__ dst, int* __restrict__ deg) {
    int e = blockIdx.x * blockDim.x + threadIdx.x;
    if (e < NE) atomicAdd(&deg[dst[e]], 1);
}

__global__ void scan_deg(int* __restrict__ cursor, int* __restrict__ row_ptr) {
    __shared__ int sums[1024];
    const int T = 1024;
    const int chunk = (NN + T - 1) / T;  // 49
    int t = threadIdx.x;
    int lo = t * chunk, hi = min(lo + chunk, NN);
    int s = 0;
    for (int i = lo; i < hi; i++) s += cursor[i];
    sums[t] = s;
    __syncthreads();
    for (int off = 1; off < T; off <<= 1) {
        int v = (t >= off) ? sums[t - off] : 0;
        __syncthreads();
        sums[t] += v;
        __syncthreads();
    }
    int base = (t == 0) ? 0 : sums[t - 1];
    for (int i = lo; i < hi; i++) {
        int d = cursor[i];
        row_ptr[i] = base;
        cursor[i] = base;
        base += d;
    }
    if (t == 0) row_ptr[NN] = NE;
}

__global__ void fill_csr(const int* __restrict__ src, const int* __restrict__ dst,
                         int* __restrict__ cursor, int* __restrict__ csr_src,
                         int* __restrict__ csr_dst, int* __restrict__ csr_eid) {
    int e = blockIdx.x * blockDim.x + threadIdx.x;
    if (e < NE) {
        int d = dst[e];
        int pos = atomicAdd(&cursor[d], 1);
        csr_src[pos] = src[e];
        csr_dst[pos] = d;
        csr_eid[pos] = e;
    }
}

// ---------------------------------------------------------------------------
// perm_ef: materialize ef in CSR-slot order as pre-split bf16 hi/lo, and
// build full src/dst arrays (edge slots).  One-time gather; score then
// streams efp sequentially (twice) with zero conversion VALU.
// ---------------------------------------------------------------------------
__global__ void perm_ef(const float* __restrict__ ef, const int* __restrict__ csr_eid,
                        const int* __restrict__ csr_src, const int* __restrict__ csr_dst,
                        unsigned short* __restrict__ efp_h, unsigned short* __restrict__ efp_l,
                        int* __restrict__ srcf, int* __restrict__ dstf) {
    int idx = blockIdx.x * blockDim.x + threadIdx.x;
    if (idx >= NE * 4) return;
    int j = idx >> 2, ch = idx & 3;
    int eid = csr_eid[j];
    const float* sp = ef + (size_t)eid * EDIM + ch * 8;
    float4 v0 = *(const float4*)sp;
    float4 v1 = *(const float4*)(sp + 4);
    float vv[8] = {v0.x, v0.y, v0.z, v0.w, v1.x, v1.y, v1.z, v1.w};
    unsigned short hh[8], ll[8];
    #pragma unroll
    for (int i = 0; i < 8; i++) {
        hh[i] = f2bf(vv[i]);
        ll[i] = f2bf(vv[i] - bf2f(hh[i]));
    }
    size_t o = (size_t)j * EDIM + ch * 8;
    *(u16x4*)&efp_h[o]     = (u16x4){hh[0], hh[1], hh[2], hh[3]};
    *(u16x4*)&efp_h[o + 4] = (u16x4){hh[4], hh[5], hh[6], hh[7]};
    *(u16x4*)&efp_l[o]     = (u16x4){ll[0], ll[1], ll[2], ll[3]};
    *(u16x4*)&efp_l[o + 4] = (u16x4){ll[4], ll[5], ll[6], ll[7]};
    if (ch == 0) { srcf[j] = csr_src[j]; dstf[j] = csr_dst[j]; }
}

// ---------------------------------------------------------------------------
// self_slots: per-node mean of incident edge attrs (sequential scan of efp),
// written as bf16 hi/lo into the self-loop slots NE..NE+NN of efp.
// ---------------------------------------------------------------------------
__global__ void self_slots(const int* __restrict__ row_ptr,
                           unsigned short* __restrict__ efp_h, unsigned short* __restrict__ efp_l,
                           int* __restrict__ srcf, int* __restrict__ dstf) {
    int idx = blockIdx.x * blockDim.x + threadIdx.x;
    if (idx >= NN * EDIM) return;
    int n = idx >> 5, c = idx & 31;
    int s = row_ptr[n], e = row_ptr[n + 1];
    float acc = 0.f;
    for (int j = s; j < e; j++)
        acc += bf2f(efp_h[(size_t)j * EDIM + c]) + bf2f(efp_l[(size_t)j * EDIM + c]);
    float m = acc / (float)max(e - s, 1);
    unsigned short h = f2bf(m);
    unsigned short l = f2bf(m - bf2f(h));
    size_t o = (size_t)(NE + n) * EDIM + c;
    efp_h[o] = h;
    efp_l[o] = l;
    if (c == 0) { srcf[NE + n] = n; dstf[NE + n] = n; }
}

// ---------------------------------------------------------------------------
// Weight pre-passes
// ---------------------------------------------------------------------------
// W[K][N] fp32 -> transposed bf16 hi/lo [N][K] (for MFMA GEMM)
__global__ void conv_wt(const float* __restrict__ W, unsigned short* __restrict__ hi,
                        unsigned short* __restrict__ lo, int K, int Nn) {
    int idx = blockIdx.x * blockDim.x + threadIdx.x;
    if (idx >= K * Nn) return;
    int k = idx / Nn, n = idx - k * Nn;
    float x = W[idx];
    unsigned short h = f2bf(x);
    unsigned short l = f2bf(x - bf2f(h));
    hi[(size_t)n * K + k] = h;
    lo[(size_t)n * K + k] = l;
}

// We[EDIM][HC] fp32 -> PERMUTED transposed bf16 hi/lo [HC][EDIM].
// Row r of Weth holds We column ((r&15)<<4)|(r>>4), so that the MFMA output
// channel at (tile ct, col m) is m*16+ct -> each lane owns 16 CONSECUTIVE
// channels in the score epilogue (float4 gathers instead of strided dwords).
__global__ void conv_wet(const float* __restrict__ We, unsigned short* __restrict__ hi,
                         unsigned short* __restrict__ lo) {
    int idx = blockIdx.x * blockDim.x + threadIdx.x;
    if (idx >= EDIM * HC) return;
    int k = idx / HC, c = idx - k * HC;
    float x = We[idx];
    unsigned short h = f2bf(x);
    unsigned short l = f2bf(x - bf2f(h));
    int r = ((c & 15) << 4) | (c >> 4);   // inverse of c = (r&15)*16 + (r>>4)
    hi[(size_t)r * EDIM + k] = h;
    lo[(size_t)r * EDIM + k] = l;
}

__global__ void concat_bias(const float* __restrict__ a, const float* __restrict__ b,
                            float* __restrict__ o) {
    int i = threadIdx.x;
    o[i] = a[i];
    o[i + HC] = b[i];
}

#define LDT 40

// ---------------------------------------------------------------------------
// Wide fused GEMM: C[M,512] = A[M,K] @ [Wl|Wr] + [bl|br].  Tile 64x128,
// 256 threads, 8 16x16 col-tiles per wave row-group. 3-term split-bf16.
// Output row stride XLR=512 (xl = cols 0..255, xr = cols 256..511).
// ---------------------------------------------------------------------------
__global__ __launch_bounds__(256, 2)
void gemm_wide(const float* __restrict__ A, const unsigned short* __restrict__ Bth,
               const unsigned short* __restrict__ Btl, const float* __restrict__ bias,
               float* __restrict__ C, int M, int K) {
    __shared__ unsigned short Ah[64][LDT], Al[64][LDT];
    __shared__ unsigned short Bh[128][LDT], Bl[128][LDT];
    int tid = threadIdx.x;
    int lane = tid & 63, w = tid >> 6;
    int m = lane & 15, q = lane >> 4;
    int rowBase = blockIdx.y * 64, colBase = blockIdx.x * 128;
    f32x4 acc[8];
    #pragma unroll
    for (int ct = 0; ct < 8; ct++) acc[ct] = (f32x4){0.f, 0.f, 0.f, 0.f};

    for (int kk = 0; kk < K; kk += 32) {
        // ---- stage A: 64 rows x 32 k fp32 -> hi/lo bf16 (2 float4 / thread)
        #pragma unroll
        for (int u = 0; u < 2; u++) {
            int f = tid + 256 * u;
            int r = f >> 3;
            int k4 = (f & 7) * 4;
            int row = rowBase + r;
            float4 v = make_float4(0.f, 0.f, 0.f, 0.f);
            if (row < M) v = *(const float4*)(A + (size_t)row * K + kk + k4);
            unsigned short h0 = f2bf(v.x), h1 = f2bf(v.y), h2 = f2bf(v.z), h3 = f2bf(v.w);
            unsigned short l0 = f2bf(v.x - bf2f(h0)), l1 = f2bf(v.y - bf2f(h1));
            unsigned short l2 = f2bf(v.z - bf2f(h2)), l3 = f2bf(v.w - bf2f(h3));
            *(u16x4*)&Ah[r][k4] = (u16x4){h0, h1, h2, h3};
            *(u16x4*)&Al[r][k4] = (u16x4){l0, l1, l2, l3};
        }
        // ---- stage B: 128 rows x 32 k bf16 hi/lo (2 chunks / thread)
        #pragma unroll
        for (int u = 0; u < 2; u++) {
            int f = tid + 256 * u;
            int n = f >> 2;
            int ch = f & 3;
            size_t goff = (size_t)(colBase + n) * K + kk + ch * 8;
            *(bf16x8*)&Bh[n][ch * 8] = *(const bf16x8*)(Bth + goff);
            *(bf16x8*)&Bl[n][ch * 8] = *(const bf16x8*)(Btl + goff);
        }
        __syncthreads();
        bf16x8 a_h = *(const bf16x8*)&Ah[w * 16 + m][q * 8];
        bf16x8 a_l = *(const bf16x8*)&Al[w * 16 + m][q * 8];
        #pragma unroll
        for (int ct = 0; ct < 8; ct++) {
            bf16x8 b_h = *(const bf16x8*)&Bh[ct * 16 + m][q * 8];
            bf16x8 b_l = *(const bf16x8*)&Bl[ct * 16 + m][q * 8];
            acc[ct] = __builtin_amdgcn_mfma_f32_16x16x32_bf16(a_h, b_h, acc[ct], 0, 0, 0);
            acc[ct] = __builtin_amdgcn_mfma_f32_16x16x32_bf16(a_l, b_h, acc[ct], 0, 0, 0);
            acc[ct] = __builtin_amdgcn_mfma_f32_16x16x32_bf16(a_h, b_l, acc[ct], 0, 0, 0);
        }
        __syncthreads();
    }
    #pragma unroll
    for (int ct = 0; ct < 8; ct++) {
        int col = colBase + ct * 16 + m;
        float bb = bias[col];
        #pragma unroll
        for (int r = 0; r < 4; r++) {
            int row = rowBase + w * 16 + q * 4 + r;
            if (row < M) C[(size_t)row * XLR + col] = acc[ct][r] + bb;
        }
    }
}

// ---------------------------------------------------------------------------
// MFMA split-bf16 GEMM (64x64) with fused LayerNorm epilogue (Nn==64).
// Used for the local head only.
// ---------------------------------------------------------------------------
__global__ __launch_bounds__(256, 2)
void gemm_head(const float* __restrict__ A, const unsigned short* __restrict__ Bth,
               const unsigned short* __restrict__ Btl, const float* __restrict__ bias,
               float* __restrict__ C, int M, int K,
               const float* __restrict__ ln_g, const float* __restrict__ ln_b) {
    __shared__ unsigned short Ah[64][LDT], Al[64][LDT];
    __shared__ unsigned short Bh[64][LDT], Bl[64][LDT];
    int tid = threadIdx.x;
    int lane = tid & 63, w = tid >> 6;
    int m = lane & 15, q = lane >> 4;
    int rowBase = blockIdx.y * 64;
    f32x4 acc[4];
    #pragma unroll
    for (int ct = 0; ct < 4; ct++) acc[ct] = (f32x4){0.f, 0.f, 0.f, 0.f};

    for (int kk = 0; kk < K; kk += 32) {
        #pragma unroll
        for (int u = 0; u < 2; u++) {
            int f = tid + 256 * u;
            int r = f >> 3;
            int k4 = (f & 7) * 4;
            int row = rowBase + r;
            float4 v = make_float4(0.f, 0.f, 0.f, 0.f);
            if (row < M) v = *(const float4*)(A + (size_t)row * K + kk + k4);
            unsigned short h0 = f2bf(v.x), h1 = f2bf(v.y), h2 = f2bf(v.z), h3 = f2bf(v.w);
            unsigned short l0 = f2bf(v.x - bf2f(h0)), l1 = f2bf(v.y - bf2f(h1));
            unsigned short l2 = f2bf(v.z - bf2f(h2)), l3 = f2bf(v.w - bf2f(h3));
            *(u16x4*)&Ah[r][k4] = (u16x4){h0, h1, h2, h3};
            *(u16x4*)&Al[r][k4] = (u16x4){l0, l1, l2, l3};
        }
        {
            int n = tid >> 2;
            int ch = tid & 3;
            size_t goff = (size_t)n * K + kk + ch * 8;
            *(bf16x8*)&Bh[n][ch * 8] = *(const bf16x8*)(Bth + goff);
            *(bf16x8*)&Bl[n][ch * 8] = *(const bf16x8*)(Btl + goff);
        }
        __syncthreads();
        bf16x8 a_h = *(const bf16x8*)&Ah[w * 16 + m][q * 8];
        bf16x8 a_l = *(const bf16x8*)&Al[w * 16 + m][q * 8];
        #pragma unroll
        for (int ct = 0; ct < 4; ct++) {
            bf16x8 b_h = *(const bf16x8*)&Bh[ct * 16 + m][q * 8];
            bf16x8 b_l = *(const bf16x8*)&Bl[ct * 16 + m][q * 8];
            acc[ct] = __builtin_amdgcn_mfma_f32_16x16x32_bf16(a_h, b_h, acc[ct], 0, 0, 0);
            acc[ct] = __builtin_amdgcn_mfma_f32_16x16x32_bf16(a_l, b_h, acc[ct], 0, 0, 0);
            acc[ct] = __builtin_amdgcn_mfma_f32_16x16x32_bf16(a_h, b_l, acc[ct], 0, 0, 0);
        }
        __syncthreads();
    }
    // LN epilogue: row held by 16 lanes (m) x 4 cols (ct)
    #pragma unroll
    for (int r = 0; r < 4; r++) {
        float v[4];
        float sum = 0.f;
        #pragma unroll
        for (int ct = 0; ct < 4; ct++) {
            v[ct] = acc[ct][r] + bias[ct * 16 + m];
            sum += v[ct];
        }
        sum += __shfl_xor(sum, 1); sum += __shfl_xor(sum, 2);
        sum += __shfl_xor(sum, 4); sum += __shfl_xor(sum, 8);
        float mu = sum * (1.f / 64.f);
        float sq = 0.f;
        #pragma unroll
        for (int ct = 0; ct < 4; ct++) {
            float d = v[ct] - mu;
            sq += d * d;
        }
        sq += __shfl_xor(sq, 1); sq += __shfl_xor(sq, 2);
        sq += __shfl_xor(sq, 4); sq += __shfl_xor(sq, 8);
        float inv = rsqrtf(sq * (1.f / 64.f) + LN_EPS);
        int row = rowBase + w * 16 + q * 4 + r;
        if (row < M) {
            #pragma unroll
            for (int ct = 0; ct < 4; ct++) {
                int col = ct * 16 + m;
                C[(size_t)row * 64 + col] = (v[ct] - mu) * inv * ln_g[col] + ln_b[col];
            }
        }
    }
}

// ---------------------------------------------------------------------------
// score_kernel (persistent): per 64-slot group, ee = ea @ We via split-bf16
// MFMA, fused GATv2 score epilogue -> alpha[slot][h]. We^T staged ONCE per
// block; blocks loop over slot groups (grid-stride).  Stage A is now a
// branch-free SEQUENTIAL bf16x8 stream from the pre-permuted efp buffer
// (no gather, no f2bf conversion VALU).
// ---------------------------------------------------------------------------
__global__ __launch_bounds__(256, 2)
void score_kernel(const unsigned short* __restrict__ efp_h,
                  const unsigned short* __restrict__ efp_l,
                  const int* __restrict__ srcf, const int* __restrict__ dstf,
                  const float* __restrict__ xlr,
                  const unsigned short* __restrict__ Weth,
                  const unsigned short* __restrict__ Wetl,
                  const float* __restrict__ att, float* __restrict__ alpha) {
    __shared__ unsigned short Ah[64][LDT], Al[64][LDT];
    __shared__ unsigned short Bh[256][LDT], Bl[256][LDT];
    __shared__ int s_src[64], s_dst[64];
    int tid = threadIdx.x;
    int lane = tid & 63, w = tid >> 6;
    int m = lane & 15, q = lane >> 4;

    // stage B (We^T permuted, [256][32] hi/lo) ONCE
    #pragma unroll
    for (int u = 0; u < 4; u++) {
        *(bf16x8*)&Bh[tid][u * 8] = *(const bf16x8*)(Weth + (size_t)tid * EDIM + u * 8);
        *(bf16x8*)&Bl[tid][u * 8] = *(const bf16x8*)(Wetl + (size_t)tid * EDIM + u * 8);
    }
    // attv[ct] = att coefficient of channel m*16+ct (consecutive -> float4 x4)
    float attv[16];
    #pragma unroll
    for (int u = 0; u < 4; u++) {
        float4 a4 = *(const float4*)(att + m * 16 + u * 4);
        attv[u * 4 + 0] = a4.x; attv[u * 4 + 1] = a4.y;
        attv[u * 4 + 2] = a4.z; attv[u * 4 + 3] = a4.w;
    }

    int groups = (EESLOTS + 63) >> 6;
    for (int g = blockIdx.x; g < groups; g += gridDim.x) {
        int base = g << 6;
        __syncthreads();   // protect Ah/Al + s_src reads of previous group
        // stage A: 64 slots x 32 k, sequential bf16 hi/lo stream from efp
        {
            int r = tid >> 2, ch = tid & 3;
            int j = base + r;
            if (j >= EESLOTS) j = EESLOTS - 1;
            size_t o = (size_t)j * EDIM + ch * 8;
            *(bf16x8*)&Ah[r][ch * 8] = *(const bf16x8*)(efp_h + o);
            *(bf16x8*)&Al[r][ch * 8] = *(const bf16x8*)(efp_l + o);
            if (ch == 0) { s_src[r] = srcf[j]; s_dst[r] = dstf[j]; }
        }
        __syncthreads();

        bf16x8 a_h = *(const bf16x8*)&Ah[w * 16 + m][q * 8];
        bf16x8 a_l = *(const bf16x8*)&Al[w * 16 + m][q * 8];
        f32x4 acc[16];
        #pragma unroll
        for (int ct = 0; ct < 16; ct++) {
            bf16x8 b_h = *(const bf16x8*)&Bh[ct * 16 + m][q * 8];
            bf16x8 b_l = *(const bf16x8*)&Bl[ct * 16 + m][q * 8];
            f32x4 c = (f32x4){0.f, 0.f, 0.f, 0.f};
            c = __builtin_amdgcn_mfma_f32_16x16x32_bf16(a_h, b_h, c, 0, 0, 0);
            c = __builtin_amdgcn_mfma_f32_16x16x32_bf16(a_l, b_h, c, 0, 0, 0);
            c = __builtin_amdgcn_mfma_f32_16x16x32_bf16(a_h, b_l, c, 0, 0, 0);
            acc[ct] = c;
        }

        // epilogue: per-slot score. Lane m owns channels [m*16 .. m*16+15].
        #pragma unroll
        for (int r = 0; r < 4; r++) {
            int sl = w * 16 + q * 4 + r;
            int slot = base + sl;
            int ss = s_src[sl], dd = s_dst[sl];
            const float* xlp = xlr + (size_t)ss * XLR + m * 16;         // xl part
            const float* xrp = xlr + (size_t)dd * XLR + HC + m * 16;    // xr part
            float4 xl0 = *(const float4*)(xlp + 0);
            float4 xl1 = *(const float4*)(xlp + 4);
            float4 xl2 = *(const float4*)(xlp + 8);
            float4 xl3 = *(const float4*)(xlp + 12);
            float4 xr0 = *(const float4*)(xrp + 0);
            float4 xr1 = *(const float4*)(xrp + 4);
            float4 xr2 = *(const float4*)(xrp + 8);
            float4 xr3 = *(const float4*)(xrp + 12);
            float xl[16] = {xl0.x, xl0.y, xl0.z, xl0.w, xl1.x, xl1.y, xl1.z, xl1.w,
                            xl2.x, xl2.y, xl2.z, xl2.w, xl3.x, xl3.y, xl3.z, xl3.w};
            float xr[16] = {xr0.x, xr0.y, xr0.z, xr0.w, xr1.x, xr1.y, xr1.z, xr1.w,
                            xr2.x, xr2.y, xr2.z, xr2.w, xr3.x, xr3.y, xr3.z, xr3.w};
            float s = 0.f;
            #pragma unroll
            for (int ct = 0; ct < 16; ct++) {
                float z = xl[ct] + xr[ct] + acc[ct][r];
                float lz = fmaxf(z, 0.f) + 0.2f * fminf(z, 0.f);
                s += lz * attv[ct];
            }
            // head h = m>>2: reduce over the 4 lanes m in [4h..4h+3]
            s += __shfl_xor(s, 1);
            s += __shfl_xor(s, 2);
            if ((m & 3) == 0 && slot < EESLOTS) {
                alpha[(size_t)slot * 4 + (m >> 2)] = s;
            }
        }
    }
}

// ---------------------------------------------------------------------------
// Lean aggregation: softmax over precomputed alpha (shift = alpha_self),
// weighted gather of xl (cols 0..255 of xlr). One wave per node, ILP x4.
// ---------------------------------------------------------------------------
__global__ __launch_bounds__(256)
void gat_aggr(const float* __restrict__ xlr, const float* __restrict__ alpha,
              const int* __restrict__ row_ptr, const int* __restrict__ csr_src,
              const float* __restrict__ bias, float* __restrict__ out, int do_relu) {
    int lane = threadIdx.x & 63;
    int wv = threadIdx.x >> 6;
    int n = blockIdx.x * 4 + wv;
    if (n >= NN) return;
    int h = lane >> 4;
    float4 bb = *(const float4*)(bias + 4 * lane);
    int s0 = row_ptr[n], e0 = row_ptr[n + 1];
    float aself = alpha[(size_t)(NE + n) * 4 + h];
    float denom = 1.f;
    float4 acc = *(const float4*)(xlr + (size_t)n * XLR + 4 * lane);

    for (int j0 = s0; j0 < e0; j0 += 64) {
        int cnt = min(64, e0 - j0);
        int sidx = (j0 + lane < e0) ? csr_src[j0 + lane] : 0;
        int t = 0;
        for (; t + 3 < cnt; t += 4) {
            int sa = __shfl(sidx, t);
            int sb = __shfl(sidx, t + 1);
            int sc = __shfl(sidx, t + 2);
            int sd = __shfl(sidx, t + 3);
            float a0 = __expf(alpha[(size_t)(j0 + t) * 4 + h] - aself);
            float a1 = __expf(alpha[(size_t)(j0 + t + 1) * 4 + h] - aself);
            float a2 = __expf(alpha[(size_t)(j0 + t + 2) * 4 + h] - aself);
            float a3 = __expf(alpha[(size_t)(j0 + t + 3) * 4 + h] - aself);
            float4 x0 = *(const float4*)(xlr + (size_t)sa * XLR + 4 * lane);
            float4 x1 = *(const float4*)(xlr + (size_t)sb * XLR + 4 * lane);
            float4 x2 = *(const float4*)(xlr + (size_t)sc * XLR + 4 * lane);
            float4 x3 = *(const float4*)(xlr + (size_t)sd * XLR + 4 * lane);
            denom += a0 + a1 + a2 + a3;
            acc.x += a0 * x0.x + a1 * x1.x + a2 * x2.x + a3 * x3.x;
            acc.y += a0 * x0.y + a1 * x1.y + a2 * x2.y + a3 * x3.y;
            acc.z += a0 * x0.z + a1 * x1.z + a2 * x2.z + a3 * x3.z;
            acc.w += a0 * x0.w + a1 * x1.w + a2 * x2.w + a3 * x3.w;
        }
        for (; t < cnt; t++) {
            int sa = __shfl(sidx, t);
            float a0 = __expf(alpha[(size_t)(j0 + t) * 4 + h] - aself);
            float4 x0 = *(const float4*)(xlr + (size_t)sa * XLR + 4 * lane);
            denom += a0;
            acc.x += a0 * x0.x; acc.y += a0 * x0.y;
            acc.z += a0 * x0.z; acc.w += a0 * x0.w;
        }
    }

    float inv = 1.f / denom;
    float4 r = make_float4(acc.x * inv + bb.x, acc.y * inv + bb.y,
                           acc.z * inv + bb.z, acc.w * inv + bb.w);
    if (do_relu) {
        r.x = fmaxf(r.x, 0.f); r.y = fmaxf(r.y, 0.f);
        r.z = fmaxf(r.z, 0.f); r.w = fmaxf(r.w, 0.f);
    }
    *(float4*)(out + (size_t)n * HC + 4 * lane) = r;
}

// ---------------------------------------------------------------------------
// Graph mean pre-reduction exploiting sorted batch
// ---------------------------------------------------------------------------
__global__ void graph_sum(const float* __restrict__ x, const int* __restrict__ batch,
                          float* __restrict__ gsum, float* __restrict__ gcnt) {
    int c = threadIdx.x;
    int r0 = blockIdx.x * 256;
    int r1 = min(r0 + 256, NN);
    float acc = 0.f;
    int gcur = batch[r0];
    for (int n = r0; n < r1; n++) {
        int g = batch[n];
        if (g != gcur) {
            atomicAdd(&gsum[(size_t)gcur * HC + c], acc);
            acc = 0.f; gcur = g;
        }
        acc += x[(size_t)n * HC + c];
    }
    atomicAdd(&gsum[(size_t)gcur * HC + c], acc);
    if (c == 0) {
        int cnt = 0; gcur = batch[r0];
        for (int n = r0; n < r1; n++) {
            int g = batch[n];
            if (g != gcur) {
                atomicAdd(&gcnt[gcur], (float)cnt);
                cnt = 0; gcur = g;
            }
            cnt++;
        }
        atomicAdd(&gcnt[gcur], (float)cnt);
    }
}

__global__ void glob_kernel(const float* __restrict__ gsum, const float* __restrict__ gcnt,
                            const float* __restrict__ W, const float* __restrict__ bias,
                            const float* __restrict__ g, const float* __restrict__ b,
                            float* __restrict__ out) {
    int gi = blockIdx.x;
    int lane = threadIdx.x;
    float inv = 1.f / fmaxf(gcnt[gi], 1.f);
    float acc = 0.f;
    for (int k = 0; k < HC; k++)
        acc += (gsum[(size_t)gi * HC + k] * inv) * W[(size_t)k * ND + lane];
    acc += bias[lane];
    float s = acc;
    #pragma unroll
    for (int o = 32; o >= 1; o >>= 1) s += __shfl_xor(s, o);
    float mu = s * (1.f / 64.f);
    float dv = acc - mu;
    float q = dv * dv;
    #pragma unroll
    for (int o = 32; o >= 1; o >>= 1) q += __shfl_xor(q, o);
    float var = q * (1.f / 64.f);
    out[(size_t)gi * ND + lane] = dv * rsqrtf(var + LN_EPS) * g[lane] + b[lane];
}

// ---------------------------------------------------------------------------
extern "C" void kernel_launch(void* const* d_in, const int* in_sizes, int n_in,
                              void* d_out, int out_size, void* d_ws, size_t ws_size,
                              hipStream_t stream) {
    (void)in_sizes; (void)n_in; (void)out_size; (void)ws_size;
    const float* node_feature = (const float*)d_in[0];
    const int*   edge_index   = (const int*)d_in[1];
    const float* edge_feature = (const float*)d_in[2];
    const int*   batch        = (const int*)d_in[3];
    const float* Wl0   = (const float*)d_in[4];
    const float* bl0   = (const float*)d_in[5];
    const float* Wr0   = (const float*)d_in[6];
    const float* br0   = (const float*)d_in[7];
    const float* We0   = (const float*)d_in[8];
    const float* att0  = (const float*)d_in[9];
    const float* bias0 = (const float*)d_in[10];
    const float* Wl1   = (const float*)d_in[11];
    const float* bl1   = (const float*)d_in[12];
    const float* Wr1   = (const float*)d_in[13];
    const float* br1   = (const float*)d_in[14];
    const float* We1   = (const float*)d_in[15];
    const float* att1  = (const float*)d_in[16];
    const float* bias1 = (const float*)d_in[17];
    const float* node_W  = (const float*)d_in[18];
    const float* node_b  = (const float*)d_in[19];
    const float* graph_W = (const float*)d_in[20];
    const float* graph_b = (const float*)d_in[21];
    const float* nn_g = (const float*)d_in[22];
    const float* nn_b = (const float*)d_in[23];
    const float* gn_g = (const float*)d_in[24];
    const float* gn_b = (const float*)d_in[25];

    const int* src = edge_index;
    const int* dst = edge_index + NE;

    char* p = (char*)d_ws;
    auto carve = [&](size_t bytes) {
        char* r = p;
        p += (bytes + 255) & ~(size_t)255;
        return r;
    };
    int*   row_ptr   = (int*)carve((NN + 1) * sizeof(int));
    int*   cursor    = (int*)carve(NN * sizeof(int));
    int*   csr_src   = (int*)carve((size_t)NE * sizeof(int));
    int*   csr_dst   = (int*)carve((size_t)NE * sizeof(int));
    int*   csr_eid   = (int*)carve((size_t)NE * sizeof(int));
    int*   srcf      = (int*)carve((size_t)EESLOTS * sizeof(int));
    int*   dstf      = (int*)carve((size_t)EESLOTS * sizeof(int));
    unsigned short* efp_h = (unsigned short*)carve((size_t)EESLOTS * EDIM * sizeof(unsigned short));
    unsigned short* efp_l = (unsigned short*)carve((size_t)EESLOTS * EDIM * sizeof(unsigned short));
    float* xlr       = (float*)carve((size_t)NN * XLR * sizeof(float));   // xl|xr fused
    float* xb        = (float*)carve((size_t)NN * HC * sizeof(float));
    float* alpha     = (float*)carve((size_t)EESLOTS * NH * sizeof(float));
    float* gsum      = (float*)carve((size_t)(NGG * HC + NGG) * sizeof(float));
    float* gcnt      = gsum + (size_t)NGG * HC;
    // concat bf16 transposed weights [512][K] hi/lo
    unsigned short* wlr0h = (unsigned short*)carve((size_t)XLR * DIN * 2 * 2);
    unsigned short* wlr0l = wlr0h + (size_t)XLR * DIN;
    unsigned short* wlr1h = (unsigned short*)carve((size_t)XLR * HC * 2 * 2);
    unsigned short* wlr1l = wlr1h + (size_t)XLR * HC;
    unsigned short* nwh   = (unsigned short*)carve((size_t)HC * ND * 2 * 2);
    unsigned short* nwl   = nwh + (size_t)HC * ND;
    unsigned short* we0h  = (unsigned short*)carve((size_t)EDIM * HC * 2 * 2);
    unsigned short* we0l  = we0h + (size_t)EDIM * HC;
    unsigned short* we1h  = (unsigned short*)carve((size_t)EDIM * HC * 2 * 2);
    unsigned short* we1l  = we1h + (size_t)EDIM * HC;
    float* b0cat = (float*)carve(XLR * sizeof(float));
    float* b1cat = (float*)carve(XLR * sizeof(float));

    hipMemsetAsync(cursor, 0, NN * sizeof(int), stream);
    hipMemsetAsync(gsum, 0, (NGG * HC + NGG) * sizeof(float), stream);

    // CSR + efp pre-permutation + weight conversion (layer-independent)
    count_deg<<<(NE + 255) / 256, 256, 0, stream>>>(dst, cursor);
    scan_deg<<<1, 1024, 0, stream>>>(cursor, row_ptr);
    fill_csr<<<(NE + 255) / 256, 256, 0, stream>>>(src, dst, cursor, csr_src, csr_dst, csr_eid);
    perm_ef<<<(NE * 4 + 255) / 256, 256, 0, stream>>>(edge_feature, csr_eid, csr_src, csr_dst,
                                                      efp_h, efp_l, srcf, dstf);
    self_slots<<<(NN * EDIM + 255) / 256, 256, 0, stream>>>(row_ptr, efp_h, efp_l, srcf, dstf);
    conv_wt<<<(DIN * HC + 255) / 256, 256, 0, stream>>>(Wl0, wlr0h, wlr0l, DIN, HC);
    conv_wt<<<(DIN * HC + 255) / 256, 256, 0, stream>>>(Wr0, wlr0h + (size_t)HC * DIN, wlr0l + (size_t)HC * DIN, DIN, HC);
    conv_wt<<<(HC * HC + 255) / 256, 256, 0, stream>>>(Wl1, wlr1h, wlr1l, HC, HC);
    conv_wt<<<(HC * HC + 255) / 256, 256, 0, stream>>>(Wr1, wlr1h + (size_t)HC * HC, wlr1l + (size_t)HC * HC, HC, HC);
    conv_wt<<<(HC * ND + 255) / 256, 256, 0, stream>>>(node_W, nwh, nwl, HC, ND);
    conv_wet<<<(EDIM * HC + 255) / 256, 256, 0, stream>>>(We0, we0h, we0l);
    conv_wet<<<(EDIM * HC + 255) / 256, 256, 0, stream>>>(We1, we1h, we1l);
    concat_bias<<<1, 256, 0, stream>>>(bl0, br0, b0cat);
    concat_bias<<<1, 256, 0, stream>>>(bl1, br1, b1cat);

    dim3 gw(4, (NN + 63) / 64);
    // Layer 0
    gemm_wide<<<gw, 256, 0, stream>>>(node_feature, wlr0h, wlr0l, b0cat, xlr, NN, DIN);
    score_kernel<<<2048, 256, 0, stream>>>(efp_h, efp_l, srcf, dstf,
                                           xlr, we0h, we0l, att0, alpha);
    gat_aggr<<<(NN + 3) / 4, 256, 0, stream>>>(xlr, alpha, row_ptr, csr_src, bias0, xb, 1);
    // Layer 1
    gemm_wide<<<gw, 256, 0, stream>>>(xb, wlr1h, wlr1l, b1cat, xlr, NN, HC);
    score_kernel<<<2048, 256, 0, stream>>>(efp_h, efp_l, srcf, dstf,
                                           xlr, we1h, we1l, att1, alpha);
    gat_aggr<<<(NN + 3) / 4, 256, 0, stream>>>(xlr, alpha, row_ptr, csr_src, bias1, xb, 0);

    // Heads
    float* out_local = (float*)d_out;
    float* out_glob  = out_local + (size_t)NN * ND;
    dim3 gh(1, (NN + 63) / 64);
    gemm_head<<<gh, 256, 0, stream>>>(xb, nwh, nwl, node_b, out_local, NN, HC, nn_g, nn_b);
    graph_sum<<<(NN + 255) / 256, 256, 0, stream>>>(xb, batch, gsum, gcnt);
    glob_kernel<<<NGG, 64, 0, stream>>>(gsum, gcnt, graph_W, graph_b, gn_g, gn_b, out_glob);
}

// Round 6
// 846.099 us; speedup vs baseline: 1.3052x; 1.1792x over previous
//
#include <hip/hip_runtime.h>
#include <cstdint>
#include <cstddef>

#define NN   50000
#define NE   500000
#define DIN  64
#define EDIM 32
#define NH   4
#define NC   64
#define HC   256   // NH*NC
#define NGG  64
#define ND   64
#define LN_EPS 1e-5f
#define EESLOTS (NE + NN)   // edges + self-loops, CSR-slot order
#define XLR  512            // row stride of fused xl|xr buffer (fp16)

typedef __attribute__((ext_vector_type(8))) short bf16x8;
typedef __attribute__((ext_vector_type(4))) float f32x4;
typedef __attribute__((ext_vector_type(4))) unsigned short u16x4;
typedef _Float16 f16;
typedef __attribute__((ext_vector_type(4))) _Float16 f16x4;
typedef __attribute__((ext_vector_type(8))) _Float16 f16x8;

__device__ __forceinline__ unsigned short f2bf(float x) {
    unsigned u = __float_as_uint(x);
    unsigned r = (u + 0x7FFFu + ((u >> 16) & 1u)) >> 16;
    return (unsigned short)r;
}
__device__ __forceinline__ float bf2f(unsigned short h) {
    return __uint_as_float(((unsigned)h) << 16);
}

// ---------------------------------------------------------------------------
// CSR build: degree count -> single-block scan -> fill
// ---------------------------------------------------------------------------
__global__ void count_deg(const int* __restrict__ dst, int* __restrict__ deg) {
    int e = blockIdx.x * blockDim.x + threadIdx.x;
    if (e < NE) atomicAdd(&deg[dst[e]], 1);
}

__global__ void scan_deg(int* __restrict__ cursor, int* __restrict__ row_ptr) {
    __shared__ int sums[1024];
    const int T = 1024;
    const int chunk = (NN + T - 1) / T;  // 49
    int t = threadIdx.x;
    int lo = t * chunk, hi = min(lo + chunk, NN);
    int s = 0;
    for (int i = lo; i < hi; i++) s += cursor[i];
    sums[t] = s;
    __syncthreads();
    for (int off = 1; off < T; off <<= 1) {
        int v = (t >= off) ? sums[t - off] : 0;
        __syncthreads();
        sums[t] += v;
        __syncthreads();
    }
    int base = (t == 0) ? 0 : sums[t - 1];
    for (int i = lo; i < hi; i++) {
        int d = cursor[i];
        row_ptr[i] = base;
        cursor[i] = base;
        base += d;
    }
    if (t == 0) row_ptr[NN] = NE;
}

__global__ void fill_csr(const int* __restrict__ src, const int* __restrict__ dst,
                         int* __restrict__ cursor, int* __restrict__ csr_src,
                         int* __restrict__ csr_dst, int* __restrict__ csr_eid) {
    int e = blockIdx.x * blockDim.x + threadIdx.x;
    if (e < NE) {
        int d = dst[e];
        int pos = atomicAdd(&cursor[d], 1);
        csr_src[pos] = src[e];
        csr_dst[pos] = d;
        csr_eid[pos] = e;
    }
}

// ---------------------------------------------------------------------------
// perm_ef: materialize ef in CSR-slot order as pre-split bf16 hi/lo, and
// build full src/dst arrays (edge slots).
// ---------------------------------------------------------------------------
__global__ void perm_ef(const float* __restrict__ ef, const int* __restrict__ csr_eid,
                        const int* __restrict__ csr_src, const int* __restrict__ csr_dst,
                        unsigned short* __restrict__ efp_h, unsigned short* __restrict__ efp_l,
                        int* __restrict__ srcf, int* __restrict__ dstf) {
    int idx = blockIdx.x * blockDim.x + threadIdx.x;
    if (idx >= NE * 4) return;
    int j = idx >> 2, ch = idx & 3;
    int eid = csr_eid[j];
    const float* sp = ef + (size_t)eid * EDIM + ch * 8;
    float4 v0 = *(const float4*)sp;
    float4 v1 = *(const float4*)(sp + 4);
    float vv[8] = {v0.x, v0.y, v0.z, v0.w, v1.x, v1.y, v1.z, v1.w};
    unsigned short hh[8], ll[8];
    #pragma unroll
    for (int i = 0; i < 8; i++) {
        hh[i] = f2bf(vv[i]);
        ll[i] = f2bf(vv[i] - bf2f(hh[i]));
    }
    size_t o = (size_t)j * EDIM + ch * 8;
    *(u16x4*)&efp_h[o]     = (u16x4){hh[0], hh[1], hh[2], hh[3]};
    *(u16x4*)&efp_h[o + 4] = (u16x4){hh[4], hh[5], hh[6], hh[7]};
    *(u16x4*)&efp_l[o]     = (u16x4){ll[0], ll[1], ll[2], ll[3]};
    *(u16x4*)&efp_l[o + 4] = (u16x4){ll[4], ll[5], ll[6], ll[7]};
    if (ch == 0) { srcf[j] = csr_src[j]; dstf[j] = csr_dst[j]; }
}

// ---------------------------------------------------------------------------
// self_slots: per-node mean of incident edge attrs (sequential scan of efp),
// written as bf16 hi/lo into the self-loop slots NE..NE+NN of efp.
// ---------------------------------------------------------------------------
__global__ void self_slots(const int* __restrict__ row_ptr,
                           unsigned short* __restrict__ efp_h, unsigned short* __restrict__ efp_l,
                           int* __restrict__ srcf, int* __restrict__ dstf) {
    int idx = blockIdx.x * blockDim.x + threadIdx.x;
    if (idx >= NN * EDIM) return;
    int n = idx >> 5, c = idx & 31;
    int s = row_ptr[n], e = row_ptr[n + 1];
    float acc = 0.f;
    for (int j = s; j < e; j++)
        acc += bf2f(efp_h[(size_t)j * EDIM + c]) + bf2f(efp_l[(size_t)j * EDIM + c]);
    float m = acc / (float)max(e - s, 1);
    unsigned short h = f2bf(m);
    unsigned short l = f2bf(m - bf2f(h));
    size_t o = (size_t)(NE + n) * EDIM + c;
    efp_h[o] = h;
    efp_l[o] = l;
    if (c == 0) { srcf[NE + n] = n; dstf[NE + n] = n; }
}

// ---------------------------------------------------------------------------
// Weight pre-passes
// ---------------------------------------------------------------------------
// W[K][N] fp32 -> transposed bf16 hi/lo [N][K] (for MFMA GEMM)
__global__ void conv_wt(const float* __restrict__ W, unsigned short* __restrict__ hi,
                        unsigned short* __restrict__ lo, int K, int Nn) {
    int idx = blockIdx.x * blockDim.x + threadIdx.x;
    if (idx >= K * Nn) return;
    int k = idx / Nn, n = idx - k * Nn;
    float x = W[idx];
    unsigned short h = f2bf(x);
    unsigned short l = f2bf(x - bf2f(h));
    hi[(size_t)n * K + k] = h;
    lo[(size_t)n * K + k] = l;
}

// We[EDIM][HC] fp32 -> PERMUTED transposed bf16 hi/lo [HC][EDIM].
// Row r of Weth holds We column ((r&15)<<4)|(r>>4): MFMA output channel at
// (tile ct, col m) is m*16+ct -> lane owns 16 consecutive channels.
__global__ void conv_wet(const float* __restrict__ We, unsigned short* __restrict__ hi,
                         unsigned short* __restrict__ lo) {
    int idx = blockIdx.x * blockDim.x + threadIdx.x;
    if (idx >= EDIM * HC) return;
    int k = idx / HC, c = idx - k * HC;
    float x = We[idx];
    unsigned short h = f2bf(x);
    unsigned short l = f2bf(x - bf2f(h));
    int r = ((c & 15) << 4) | (c >> 4);   // inverse of c = (r&15)*16 + (r>>4)
    hi[(size_t)r * EDIM + k] = h;
    lo[(size_t)r * EDIM + k] = l;
}

__global__ void concat_bias(const float* __restrict__ a, const float* __restrict__ b,
                            float* __restrict__ o) {
    int i = threadIdx.x;
    o[i] = a[i];
    o[i + HC] = b[i];
}

#define LDT 40

// ---------------------------------------------------------------------------
// Wide fused GEMM: C[M,512] = A[M,K] @ [Wl|Wr] + [bl|br].  Tile 64x128,
// 256 threads, 8 16x16 col-tiles per wave row-group. 3-term split-bf16.
// Output: FP16 xlr buffer, row stride XLR=512 (xl = 0..255, xr = 256..511).
// fp16 storage halves the score/aggr gather traffic (the measured 3.2 TB/s
// L2-fill bottleneck); fp16 is only consumed by softmax scores & weighted
// averaging, which tolerate 2^-11 rounding.
// ---------------------------------------------------------------------------
__global__ __launch_bounds__(256, 2)
void gemm_wide(const float* __restrict__ A, const unsigned short* __restrict__ Bth,
               const unsigned short* __restrict__ Btl, const float* __restrict__ bias,
               f16* __restrict__ C, int M, int K) {
    __shared__ unsigned short Ah[64][LDT], Al[64][LDT];
    __shared__ unsigned short Bh[128][LDT], Bl[128][LDT];
    int tid = threadIdx.x;
    int lane = tid & 63, w = tid >> 6;
    int m = lane & 15, q = lane >> 4;
    int rowBase = blockIdx.y * 64, colBase = blockIdx.x * 128;
    f32x4 acc[8];
    #pragma unroll
    for (int ct = 0; ct < 8; ct++) acc[ct] = (f32x4){0.f, 0.f, 0.f, 0.f};

    for (int kk = 0; kk < K; kk += 32) {
        // ---- stage A: 64 rows x 32 k fp32 -> hi/lo bf16 (2 float4 / thread)
        #pragma unroll
        for (int u = 0; u < 2; u++) {
            int f = tid + 256 * u;
            int r = f >> 3;
            int k4 = (f & 7) * 4;
            int row = rowBase + r;
            float4 v = make_float4(0.f, 0.f, 0.f, 0.f);
            if (row < M) v = *(const float4*)(A + (size_t)row * K + kk + k4);
            unsigned short h0 = f2bf(v.x), h1 = f2bf(v.y), h2 = f2bf(v.z), h3 = f2bf(v.w);
            unsigned short l0 = f2bf(v.x - bf2f(h0)), l1 = f2bf(v.y - bf2f(h1));
            unsigned short l2 = f2bf(v.z - bf2f(h2)), l3 = f2bf(v.w - bf2f(h3));
            *(u16x4*)&Ah[r][k4] = (u16x4){h0, h1, h2, h3};
            *(u16x4*)&Al[r][k4] = (u16x4){l0, l1, l2, l3};
        }
        // ---- stage B: 128 rows x 32 k bf16 hi/lo (2 chunks / thread)
        #pragma unroll
        for (int u = 0; u < 2; u++) {
            int f = tid + 256 * u;
            int n = f >> 2;
            int ch = f & 3;
            size_t goff = (size_t)(colBase + n) * K + kk + ch * 8;
            *(bf16x8*)&Bh[n][ch * 8] = *(const bf16x8*)(Bth + goff);
            *(bf16x8*)&Bl[n][ch * 8] = *(const bf16x8*)(Btl + goff);
        }
        __syncthreads();
        bf16x8 a_h = *(const bf16x8*)&Ah[w * 16 + m][q * 8];
        bf16x8 a_l = *(const bf16x8*)&Al[w * 16 + m][q * 8];
        #pragma unroll
        for (int ct = 0; ct < 8; ct++) {
            bf16x8 b_h = *(const bf16x8*)&Bh[ct * 16 + m][q * 8];
            bf16x8 b_l = *(const bf16x8*)&Bl[ct * 16 + m][q * 8];
            acc[ct] = __builtin_amdgcn_mfma_f32_16x16x32_bf16(a_h, b_h, acc[ct], 0, 0, 0);
            acc[ct] = __builtin_amdgcn_mfma_f32_16x16x32_bf16(a_l, b_h, acc[ct], 0, 0, 0);
            acc[ct] = __builtin_amdgcn_mfma_f32_16x16x32_bf16(a_h, b_l, acc[ct], 0, 0, 0);
        }
        __syncthreads();
    }
    #pragma unroll
    for (int ct = 0; ct < 8; ct++) {
        int col = colBase + ct * 16 + m;
        float bb = bias[col];
        #pragma unroll
        for (int r = 0; r < 4; r++) {
            int row = rowBase + w * 16 + q * 4 + r;
            if (row < M) C[(size_t)row * XLR + col] = (f16)(acc[ct][r] + bb);
        }
    }
}

// ---------------------------------------------------------------------------
// MFMA split-bf16 GEMM (64x64) with fused LayerNorm epilogue (Nn==64).
// Used for the local head only (fp32 in/out, unchanged).
// ---------------------------------------------------------------------------
__global__ __launch_bounds__(256, 2)
void gemm_head(const float* __restrict__ A, const unsigned short* __restrict__ Bth,
               const unsigned short* __restrict__ Btl, const float* __restrict__ bias,
               float* __restrict__ C, int M, int K,
               const float* __restrict__ ln_g, const float* __restrict__ ln_b) {
    __shared__ unsigned short Ah[64][LDT], Al[64][LDT];
    __shared__ unsigned short Bh[64][LDT], Bl[64][LDT];
    int tid = threadIdx.x;
    int lane = tid & 63, w = tid >> 6;
    int m = lane & 15, q = lane >> 4;
    int rowBase = blockIdx.y * 64;
    f32x4 acc[4];
    #pragma unroll
    for (int ct = 0; ct < 4; ct++) acc[ct] = (f32x4){0.f, 0.f, 0.f, 0.f};

    for (int kk = 0; kk < K; kk += 32) {
        #pragma unroll
        for (int u = 0; u < 2; u++) {
            int f = tid + 256 * u;
            int r = f >> 3;
            int k4 = (f & 7) * 4;
            int row = rowBase + r;
            float4 v = make_float4(0.f, 0.f, 0.f, 0.f);
            if (row < M) v = *(const float4*)(A + (size_t)row * K + kk + k4);
            unsigned short h0 = f2bf(v.x), h1 = f2bf(v.y), h2 = f2bf(v.z), h3 = f2bf(v.w);
            unsigned short l0 = f2bf(v.x - bf2f(h0)), l1 = f2bf(v.y - bf2f(h1));
            unsigned short l2 = f2bf(v.z - bf2f(h2)), l3 = f2bf(v.w - bf2f(h3));
            *(u16x4*)&Ah[r][k4] = (u16x4){h0, h1, h2, h3};
            *(u16x4*)&Al[r][k4] = (u16x4){l0, l1, l2, l3};
        }
        {
            int n = tid >> 2;
            int ch = tid & 3;
            size_t goff = (size_t)n * K + kk + ch * 8;
            *(bf16x8*)&Bh[n][ch * 8] = *(const bf16x8*)(Bth + goff);
            *(bf16x8*)&Bl[n][ch * 8] = *(const bf16x8*)(Btl + goff);
        }
        __syncthreads();
        bf16x8 a_h = *(const bf16x8*)&Ah[w * 16 + m][q * 8];
        bf16x8 a_l = *(const bf16x8*)&Al[w * 16 + m][q * 8];
        #pragma unroll
        for (int ct = 0; ct < 4; ct++) {
            bf16x8 b_h = *(const bf16x8*)&Bh[ct * 16 + m][q * 8];
            bf16x8 b_l = *(const bf16x8*)&Bl[ct * 16 + m][q * 8];
            acc[ct] = __builtin_amdgcn_mfma_f32_16x16x32_bf16(a_h, b_h, acc[ct], 0, 0, 0);
            acc[ct] = __builtin_amdgcn_mfma_f32_16x16x32_bf16(a_l, b_h, acc[ct], 0, 0, 0);
            acc[ct] = __builtin_amdgcn_mfma_f32_16x16x32_bf16(a_h, b_l, acc[ct], 0, 0, 0);
        }
        __syncthreads();
    }
    // LN epilogue: row held by 16 lanes (m) x 4 cols (ct)
    #pragma unroll
    for (int r = 0; r < 4; r++) {
        float v[4];
        float sum = 0.f;
        #pragma unroll
        for (int ct = 0; ct < 4; ct++) {
            v[ct] = acc[ct][r] + bias[ct * 16 + m];
            sum += v[ct];
        }
        sum += __shfl_xor(sum, 1); sum += __shfl_xor(sum, 2);
        sum += __shfl_xor(sum, 4); sum += __shfl_xor(sum, 8);
        float mu = sum * (1.f / 64.f);
        float sq = 0.f;
        #pragma unroll
        for (int ct = 0; ct < 4; ct++) {
            float d = v[ct] - mu;
            sq += d * d;
        }
        sq += __shfl_xor(sq, 1); sq += __shfl_xor(sq, 2);
        sq += __shfl_xor(sq, 4); sq += __shfl_xor(sq, 8);
        float inv = rsqrtf(sq * (1.f / 64.f) + LN_EPS);
        int row = rowBase + w * 16 + q * 4 + r;
        if (row < M) {
            #pragma unroll
            for (int ct = 0; ct < 4; ct++) {
                int col = ct * 16 + m;
                C[(size_t)row * 64 + col] = (v[ct] - mu) * inv * ln_g[col] + ln_b[col];
            }
        }
    }
}

// ---------------------------------------------------------------------------
// score_kernel (persistent): per 64-slot group, ee = ea @ We via split-bf16
// MFMA, fused GATv2 score epilogue -> alpha[slot][h]. Stage A streams the
// pre-permuted efp buffer; xl/xr gathered from the FP16 xlr buffer
// (half the bytes of fp32 -> half the L2-fill traffic that bounds this
// kernel). Lane m owns channels [m*16 .. m*16+15].
// ---------------------------------------------------------------------------
__global__ __launch_bounds__(256, 2)
void score_kernel(const unsigned short* __restrict__ efp_h,
                  const unsigned short* __restrict__ efp_l,
                  const int* __restrict__ srcf, const int* __restrict__ dstf,
                  const f16* __restrict__ xlr,
                  const unsigned short* __restrict__ Weth,
                  const unsigned short* __restrict__ Wetl,
                  const float* __restrict__ att, float* __restrict__ alpha) {
    __shared__ unsigned short Ah[64][LDT], Al[64][LDT];
    __shared__ unsigned short Bh[256][LDT], Bl[256][LDT];
    __shared__ int s_src[64], s_dst[64];
    int tid = threadIdx.x;
    int lane = tid & 63, w = tid >> 6;
    int m = lane & 15, q = lane >> 4;

    // stage B (We^T permuted, [256][32] hi/lo) ONCE
    #pragma unroll
    for (int u = 0; u < 4; u++) {
        *(bf16x8*)&Bh[tid][u * 8] = *(const bf16x8*)(Weth + (size_t)tid * EDIM + u * 8);
        *(bf16x8*)&Bl[tid][u * 8] = *(const bf16x8*)(Wetl + (size_t)tid * EDIM + u * 8);
    }
    // attv[ct] = att coefficient of channel m*16+ct
    float attv[16];
    #pragma unroll
    for (int u = 0; u < 4; u++) {
        float4 a4 = *(const float4*)(att + m * 16 + u * 4);
        attv[u * 4 + 0] = a4.x; attv[u * 4 + 1] = a4.y;
        attv[u * 4 + 2] = a4.z; attv[u * 4 + 3] = a4.w;
    }

    int groups = (EESLOTS + 63) >> 6;
    for (int g = blockIdx.x; g < groups; g += gridDim.x) {
        int base = g << 6;
        __syncthreads();   // protect Ah/Al + s_src reads of previous group
        // stage A: 64 slots x 32 k, sequential bf16 hi/lo stream from efp
        {
            int r = tid >> 2, ch = tid & 3;
            int j = base + r;
            if (j >= EESLOTS) j = EESLOTS - 1;
            size_t o = (size_t)j * EDIM + ch * 8;
            *(bf16x8*)&Ah[r][ch * 8] = *(const bf16x8*)(efp_h + o);
            *(bf16x8*)&Al[r][ch * 8] = *(const bf16x8*)(efp_l + o);
            if (ch == 0) { s_src[r] = srcf[j]; s_dst[r] = dstf[j]; }
        }
        __syncthreads();

        bf16x8 a_h = *(const bf16x8*)&Ah[w * 16 + m][q * 8];
        bf16x8 a_l = *(const bf16x8*)&Al[w * 16 + m][q * 8];
        f32x4 acc[16];
        #pragma unroll
        for (int ct = 0; ct < 16; ct++) {
            bf16x8 b_h = *(const bf16x8*)&Bh[ct * 16 + m][q * 8];
            bf16x8 b_l = *(const bf16x8*)&Bl[ct * 16 + m][q * 8];
            f32x4 c = (f32x4){0.f, 0.f, 0.f, 0.f};
            c = __builtin_amdgcn_mfma_f32_16x16x32_bf16(a_h, b_h, c, 0, 0, 0);
            c = __builtin_amdgcn_mfma_f32_16x16x32_bf16(a_l, b_h, c, 0, 0, 0);
            c = __builtin_amdgcn_mfma_f32_16x16x32_bf16(a_h, b_l, c, 0, 0, 0);
            acc[ct] = c;
        }

        // epilogue: per-slot score (fp16 gathers, 32 B per side per lane)
        #pragma unroll
        for (int r = 0; r < 4; r++) {
            int sl = w * 16 + q * 4 + r;
            int slot = base + sl;
            int ss = s_src[sl], dd = s_dst[sl];
            const f16* xlp = xlr + (size_t)ss * XLR + m * 16;         // xl part
            const f16* xrp = xlr + (size_t)dd * XLR + HC + m * 16;    // xr part
            f16x8 xa0 = *(const f16x8*)(xlp);
            f16x8 xa1 = *(const f16x8*)(xlp + 8);
            f16x8 xb0 = *(const f16x8*)(xrp);
            f16x8 xb1 = *(const f16x8*)(xrp + 8);
            float s = 0.f;
            #pragma unroll
            for (int i = 0; i < 8; i++) {
                float z0 = (float)xa0[i] + (float)xb0[i] + acc[i][r];
                float lz0 = fmaxf(z0, 0.f) + 0.2f * fminf(z0, 0.f);
                s += lz0 * attv[i];
                float z1 = (float)xa1[i] + (float)xb1[i] + acc[8 + i][r];
                float lz1 = fmaxf(z1, 0.f) + 0.2f * fminf(z1, 0.f);
                s += lz1 * attv[8 + i];
            }
            // head h = m>>2: reduce over the 4 lanes m in [4h..4h+3]
            s += __shfl_xor(s, 1);
            s += __shfl_xor(s, 2);
            if ((m & 3) == 0 && slot < EESLOTS) {
                alpha[(size_t)slot * 4 + (m >> 2)] = s;
            }
        }
    }
}

// ---------------------------------------------------------------------------
// Lean aggregation: softmax over precomputed alpha (shift = alpha_self),
// weighted gather of fp16 xl (cols 0..255 of xlr). One wave per node, ILP x4.
// fp32 accumulation; fp32 output xb.
// ---------------------------------------------------------------------------
__global__ __launch_bounds__(256)
void gat_aggr(const f16* __restrict__ xlr, const float* __restrict__ alpha,
              const int* __restrict__ row_ptr, const int* __restrict__ csr_src,
              const float* __restrict__ bias, float* __restrict__ out, int do_relu) {
    int lane = threadIdx.x & 63;
    int wv = threadIdx.x >> 6;
    int n = blockIdx.x * 4 + wv;
    if (n >= NN) return;
    int h = lane >> 4;
    float4 bb = *(const float4*)(bias + 4 * lane);
    int s0 = row_ptr[n], e0 = row_ptr[n + 1];
    float aself = alpha[(size_t)(NE + n) * 4 + h];
    float denom = 1.f;
    f16x4 xs = *(const f16x4*)(xlr + (size_t)n * XLR + 4 * lane);
    float4 acc = make_float4((float)xs[0], (float)xs[1], (float)xs[2], (float)xs[3]);

    for (int j0 = s0; j0 < e0; j0 += 64) {
        int cnt = min(64, e0 - j0);
        int sidx = (j0 + lane < e0) ? csr_src[j0 + lane] : 0;
        int t = 0;
        for (; t + 3 < cnt; t += 4) {
            int sa = __shfl(sidx, t);
            int sb = __shfl(sidx, t + 1);
            int sc = __shfl(sidx, t + 2);
            int sd = __shfl(sidx, t + 3);
            float a0 = __expf(alpha[(size_t)(j0 + t) * 4 + h] - aself);
            float a1 = __expf(alpha[(size_t)(j0 + t + 1) * 4 + h] - aself);
            float a2 = __expf(alpha[(size_t)(j0 + t + 2) * 4 + h] - aself);
            float a3 = __expf(alpha[(size_t)(j0 + t + 3) * 4 + h] - aself);
            f16x4 x0 = *(const f16x4*)(xlr + (size_t)sa * XLR + 4 * lane);
            f16x4 x1 = *(const f16x4*)(xlr + (size_t)sb * XLR + 4 * lane);
            f16x4 x2 = *(const f16x4*)(xlr + (size_t)sc * XLR + 4 * lane);
            f16x4 x3 = *(const f16x4*)(xlr + (size_t)sd * XLR + 4 * lane);
            denom += a0 + a1 + a2 + a3;
            acc.x += a0 * (float)x0[0] + a1 * (float)x1[0] + a2 * (float)x2[0] + a3 * (float)x3[0];
            acc.y += a0 * (float)x0[1] + a1 * (float)x1[1] + a2 * (float)x2[1] + a3 * (float)x3[1];
            acc.z += a0 * (float)x0[2] + a1 * (float)x1[2] + a2 * (float)x2[2] + a3 * (float)x3[2];
            acc.w += a0 * (float)x0[3] + a1 * (float)x1[3] + a2 * (float)x2[3] + a3 * (float)x3[3];
        }
        for (; t < cnt; t++) {
            int sa = __shfl(sidx, t);
            float a0 = __expf(alpha[(size_t)(j0 + t) * 4 + h] - aself);
            f16x4 x0 = *(const f16x4*)(xlr + (size_t)sa * XLR + 4 * lane);
            denom += a0;
            acc.x += a0 * (float)x0[0]; acc.y += a0 * (float)x0[1];
            acc.z += a0 * (float)x0[2]; acc.w += a0 * (float)x0[3];
        }
    }

    float inv = 1.f / denom;
    float4 r = make_float4(acc.x * inv + bb.x, acc.y * inv + bb.y,
                           acc.z * inv + bb.z, acc.w * inv + bb.w);
    if (do_relu) {
        r.x = fmaxf(r.x, 0.f); r.y = fmaxf(r.y, 0.f);
        r.z = fmaxf(r.z, 0.f); r.w = fmaxf(r.w, 0.f);
    }
    *(float4*)(out + (size_t)n * HC + 4 * lane) = r;
}

// ---------------------------------------------------------------------------
// Graph mean pre-reduction exploiting sorted batch
// ---------------------------------------------------------------------------
__global__ void graph_sum(const float* __restrict__ x, const int* __restrict__ batch,
                          float* __restrict__ gsum, float* __restrict__ gcnt) {
    int c = threadIdx.x;
    int r0 = blockIdx.x * 256;
    int r1 = min(r0 + 256, NN);
    float acc = 0.f;
    int gcur = batch[r0];
    for (int n = r0; n < r1; n++) {
        int g = batch[n];
        if (g != gcur) {
            atomicAdd(&gsum[(size_t)gcur * HC + c], acc);
            acc = 0.f; gcur = g;
        }
        acc += x[(size_t)n * HC + c];
    }
    atomicAdd(&gsum[(size_t)gcur * HC + c], acc);
    if (c == 0) {
        int cnt = 0; gcur = batch[r0];
        for (int n = r0; n < r1; n++) {
            int g = batch[n];
            if (g != gcur) {
                atomicAdd(&gcnt[gcur], (float)cnt);
                cnt = 0; gcur = g;
            }
            cnt++;
        }
        atomicAdd(&gcnt[gcur], (float)cnt);
    }
}

__global__ void glob_kernel(const float* __restrict__ gsum, const float* __restrict__ gcnt,
                            const float* __restrict__ W, const float* __restrict__ bias,
                            const float* __restrict__ g, const float* __restrict__ b,
                            float* __restrict__ out) {
    int gi = blockIdx.x;
    int lane = threadIdx.x;
    float inv = 1.f / fmaxf(gcnt[gi], 1.f);
    float acc = 0.f;
    for (int k = 0; k < HC; k++)
        acc += (gsum[(size_t)gi * HC + k] * inv) * W[(size_t)k * ND + lane];
    acc += bias[lane];
    float s = acc;
    #pragma unroll
    for (int o = 32; o >= 1; o >>= 1) s += __shfl_xor(s, o);
    float mu = s * (1.f / 64.f);
    float dv = acc - mu;
    float q = dv * dv;
    #pragma unroll
    for (int o = 32; o >= 1; o >>= 1) q += __shfl_xor(q, o);
    float var = q * (1.f / 64.f);
    out[(size_t)gi * ND + lane] = dv * rsqrtf(var + LN_EPS) * g[lane] + b[lane];
}

// ---------------------------------------------------------------------------
extern "C" void kernel_launch(void* const* d_in, const int* in_sizes, int n_in,
                              void* d_out, int out_size, void* d_ws, size_t ws_size,
                              hipStream_t stream) {
    (void)in_sizes; (void)n_in; (void)out_size; (void)ws_size;
    const float* node_feature = (const float*)d_in[0];
    const int*   edge_index   = (const int*)d_in[1];
    const float* edge_feature = (const float*)d_in[2];
    const int*   batch        = (const int*)d_in[3];
    const float* Wl0   = (const float*)d_in[4];
    const float* bl0   = (const float*)d_in[5];
    const float* Wr0   = (const float*)d_in[6];
    const float* br0   = (const float*)d_in[7];
    const float* We0   = (const float*)d_in[8];
    const float* att0  = (const float*)d_in[9];
    const float* bias0 = (const float*)d_in[10];
    const float* Wl1   = (const float*)d_in[11];
    const float* bl1   = (const float*)d_in[12];
    const float* Wr1   = (const float*)d_in[13];
    const float* br1   = (const float*)d_in[14];
    const float* We1   = (const float*)d_in[15];
    const float* att1  = (const float*)d_in[16];
    const float* bias1 = (const float*)d_in[17];
    const float* node_W  = (const float*)d_in[18];
    const float* node_b  = (const float*)d_in[19];
    const float* graph_W = (const float*)d_in[20];
    const float* graph_b = (const float*)d_in[21];
    const float* nn_g = (const float*)d_in[22];
    const float* nn_b = (const float*)d_in[23];
    const float* gn_g = (const float*)d_in[24];
    const float* gn_b = (const float*)d_in[25];

    const int* src = edge_index;
    const int* dst = edge_index + NE;

    char* p = (char*)d_ws;
    auto carve = [&](size_t bytes) {
        char* r = p;
        p += (bytes + 255) & ~(size_t)255;
        return r;
    };
    int*   row_ptr   = (int*)carve((NN + 1) * sizeof(int));
    int*   cursor    = (int*)carve(NN * sizeof(int));
    int*   csr_src   = (int*)carve((size_t)NE * sizeof(int));
    int*   csr_dst   = (int*)carve((size_t)NE * sizeof(int));
    int*   csr_eid   = (int*)carve((size_t)NE * sizeof(int));
    int*   srcf      = (int*)carve((size_t)EESLOTS * sizeof(int));
    int*   dstf      = (int*)carve((size_t)EESLOTS * sizeof(int));
    unsigned short* efp_h = (unsigned short*)carve((size_t)EESLOTS * EDIM * sizeof(unsigned short));
    unsigned short* efp_l = (unsigned short*)carve((size_t)EESLOTS * EDIM * sizeof(unsigned short));
    f16*   xlr       = (f16*)carve((size_t)NN * XLR * sizeof(f16));   // fp16 xl|xr fused
    float* xb        = (float*)carve((size_t)NN * HC * sizeof(float));
    float* alpha     = (float*)carve((size_t)EESLOTS * NH * sizeof(float));
    float* gsum      = (float*)carve((size_t)(NGG * HC + NGG) * sizeof(float));
    float* gcnt      = gsum + (size_t)NGG * HC;
    // concat bf16 transposed weights [512][K] hi/lo
    unsigned short* wlr0h = (unsigned short*)carve((size_t)XLR * DIN * 2 * 2);
    unsigned short* wlr0l = wlr0h + (size_t)XLR * DIN;
    unsigned short* wlr1h = (unsigned short*)carve((size_t)XLR * HC * 2 * 2);
    unsigned short* wlr1l = wlr1h + (size_t)XLR * HC;
    unsigned short* nwh   = (unsigned short*)carve((size_t)HC * ND * 2 * 2);
    unsigned short* nwl   = nwh + (size_t)HC * ND;
    unsigned short* we0h  = (unsigned short*)carve((size_t)EDIM * HC * 2 * 2);
    unsigned short* we0l  = we0h + (size_t)EDIM * HC;
    unsigned short* we1h  = (unsigned short*)carve((size_t)EDIM * HC * 2 * 2);
    unsigned short* we1l  = we1h + (size_t)EDIM * HC;
    float* b0cat = (float*)carve(XLR * sizeof(float));
    float* b1cat = (float*)carve(XLR * sizeof(float));

    hipMemsetAsync(cursor, 0, NN * sizeof(int), stream);
    hipMemsetAsync(gsum, 0, (NGG * HC + NGG) * sizeof(float), stream);

    // CSR + efp pre-permutation + weight conversion (layer-independent)
    count_deg<<<(NE + 255) / 256, 256, 0, stream>>>(dst, cursor);
    scan_deg<<<1, 1024, 0, stream>>>(cursor, row_ptr);
    fill_csr<<<(NE + 255) / 256, 256, 0, stream>>>(src, dst, cursor, csr_src, csr_dst, csr_eid);
    perm_ef<<<(NE * 4 + 255) / 256, 256, 0, stream>>>(edge_feature, csr_eid, csr_src, csr_dst,
                                                      efp_h, efp_l, srcf, dstf);
    self_slots<<<(NN * EDIM + 255) / 256, 256, 0, stream>>>(row_ptr, efp_h, efp_l, srcf, dstf);
    conv_wt<<<(DIN * HC + 255) / 256, 256, 0, stream>>>(Wl0, wlr0h, wlr0l, DIN, HC);
    conv_wt<<<(DIN * HC + 255) / 256, 256, 0, stream>>>(Wr0, wlr0h + (size_t)HC * DIN, wlr0l + (size_t)HC * DIN, DIN, HC);
    conv_wt<<<(HC * HC + 255) / 256, 256, 0, stream>>>(Wl1, wlr1h, wlr1l, HC, HC);
    conv_wt<<<(HC * HC + 255) / 256, 256, 0, stream>>>(Wr1, wlr1h + (size_t)HC * HC, wlr1l + (size_t)HC * HC, HC, HC);
    conv_wt<<<(HC * ND + 255) / 256, 256, 0, stream>>>(node_W, nwh, nwl, HC, ND);
    conv_wet<<<(EDIM * HC + 255) / 256, 256, 0, stream>>>(We0, we0h, we0l);
    conv_wet<<<(EDIM * HC + 255) / 256, 256, 0, stream>>>(We1, we1h, we1l);
    concat_bias<<<1, 256, 0, stream>>>(bl0, br0, b0cat);
    concat_bias<<<1, 256, 0, stream>>>(bl1, br1, b1cat);

    dim3 gw(4, (NN + 63) / 64);
    // Layer 0
    gemm_wide<<<gw, 256, 0, stream>>>(node_feature, wlr0h, wlr0l, b0cat, xlr, NN, DIN);
    score_kernel<<<2048, 256, 0, stream>>>(efp_h, efp_l, srcf, dstf,
                                           xlr, we0h, we0l, att0, alpha);
    gat_aggr<<<(NN + 3) / 4, 256, 0, stream>>>(xlr, alpha, row_ptr, csr_src, bias0, xb, 1);
    // Layer 1
    gemm_wide<<<gw, 256, 0, stream>>>(xb, wlr1h, wlr1l, b1cat, xlr, NN, HC);
    score_kernel<<<2048, 256, 0, stream>>>(efp_h, efp_l, srcf, dstf,
                                           xlr, we1h, we1l, att1, alpha);
    gat_aggr<<<(NN + 3) / 4, 256, 0, stream>>>(xlr, alpha, row_ptr, csr_src, bias1, xb, 0);

    // Heads
    float* out_local = (float*)d_out;
    float* out_glob  = out_local + (size_t)NN * ND;
    dim3 gh(1, (NN + 63) / 64);
    gemm_head<<<gh, 256, 0, stream>>>(xb, nwh, nwl, node_b, out_local, NN, HC, nn_g, nn_b);
    graph_sum<<<(NN + 255) / 256, 256, 0, stream>>>(xb, batch, gsum, gcnt);
    glob_kernel<<<NGG, 64, 0, stream>>>(gsum, gcnt, graph_W, graph_b, gn_g, gn_b, out_glob);
}

// Round 7
// 745.519 us; speedup vs baseline: 1.4812x; 1.1349x over previous
//
#include <hip/hip_runtime.h>
#include <cstdint>
#include <cstddef>

#define NN   50000
#define NE   500000
#define DIN  64
#define EDIM 32
#define NH   4
#define NC   64
#define HC   256   // NH*NC
#define NGG  64
#define ND   64
#define LN_EPS 1e-5f
#define EESLOTS (NE + NN)   // edges + self-loops, CSR-slot order
#define XLR  512            // row stride of fused xl|xr buffer (fp16)
#define SCAN_B   256
#define SCAN_NB  ((NN + SCAN_B - 1) / SCAN_B)   // 196

typedef __attribute__((ext_vector_type(8))) short bf16x8;
typedef __attribute__((ext_vector_type(4))) float f32x4;
typedef __attribute__((ext_vector_type(4))) unsigned short u16x4;
typedef _Float16 f16;
typedef __attribute__((ext_vector_type(4))) _Float16 f16x4;
typedef __attribute__((ext_vector_type(8))) _Float16 f16x8;

__device__ __forceinline__ unsigned short f2bf(float x) {
    unsigned u = __float_as_uint(x);
    unsigned r = (u + 0x7FFFu + ((u >> 16) & 1u)) >> 16;
    return (unsigned short)r;
}
__device__ __forceinline__ float bf2f(unsigned short h) {
    return __uint_as_float(((unsigned)h) << 16);
}

// ---------------------------------------------------------------------------
// CSR build: degree count -> 3-kernel device-wide scan -> fill
// ---------------------------------------------------------------------------
__global__ void count_deg(const int* __restrict__ dst, int* __restrict__ deg) {
    int e = blockIdx.x * blockDim.x + threadIdx.x;
    if (e < NE) atomicAdd(&deg[dst[e]], 1);
}

// A: per-block sum of 256 degrees (coalesced)
__global__ void scan_bsum(const int* __restrict__ deg, int* __restrict__ bsum) {
    __shared__ int s[SCAN_B];
    int t = threadIdx.x;
    int i = blockIdx.x * SCAN_B + t;
    s[t] = (i < NN) ? deg[i] : 0;
    __syncthreads();
    #pragma unroll
    for (int off = SCAN_B / 2; off > 0; off >>= 1) {
        if (t < off) s[t] += s[t + off];
        __syncthreads();
    }
    if (t == 0) bsum[blockIdx.x] = s[0];
}

// B: exclusive scan of the block sums (single tiny block)
__global__ void scan_boff(const int* __restrict__ bsum, int* __restrict__ boff) {
    __shared__ int s[SCAN_B];
    int t = threadIdx.x;
    int v = (t < SCAN_NB) ? bsum[t] : 0;
    s[t] = v;
    __syncthreads();
    #pragma unroll
    for (int off = 1; off < SCAN_B; off <<= 1) {
        int u = (t >= off) ? s[t - off] : 0;
        __syncthreads();
        s[t] += u;
        __syncthreads();
    }
    boff[t] = s[t] - v;   // exclusive
}

// C: block-local exclusive scan + block offset -> row_ptr, cursor
__global__ void scan_final(const int* __restrict__ deg, const int* __restrict__ boff,
                           int* __restrict__ row_ptr, int* __restrict__ cursor) {
    __shared__ int s[SCAN_B];
    int t = threadIdx.x;
    int i = blockIdx.x * SCAN_B + t;
    int v = (i < NN) ? deg[i] : 0;
    s[t] = v;
    __syncthreads();
    #pragma unroll
    for (int off = 1; off < SCAN_B; off <<= 1) {
        int u = (t >= off) ? s[t - off] : 0;
        __syncthreads();
        s[t] += u;
        __syncthreads();
    }
    int excl = boff[blockIdx.x] + s[t] - v;
    if (i < NN) {
        row_ptr[i] = excl;
        cursor[i] = excl;
    }
    if (i == 0) row_ptr[NN] = NE;
}

__global__ void fill_csr(const int* __restrict__ src, const int* __restrict__ dst,
                         int* __restrict__ cursor, int* __restrict__ csr_src,
                         int* __restrict__ csr_dst, int* __restrict__ csr_eid) {
    int e = blockIdx.x * blockDim.x + threadIdx.x;
    if (e < NE) {
        int d = dst[e];
        int pos = atomicAdd(&cursor[d], 1);
        csr_src[pos] = src[e];
        csr_dst[pos] = d;
        csr_eid[pos] = e;
    }
}

// ---------------------------------------------------------------------------
// perm_ef: materialize ef in CSR-slot order as pre-split bf16 hi/lo, and
// build full src/dst arrays (edge slots).
// ---------------------------------------------------------------------------
__global__ void perm_ef(const float* __restrict__ ef, const int* __restrict__ csr_eid,
                        const int* __restrict__ csr_src, const int* __restrict__ csr_dst,
                        unsigned short* __restrict__ efp_h, unsigned short* __restrict__ efp_l,
                        int* __restrict__ srcf, int* __restrict__ dstf) {
    int idx = blockIdx.x * blockDim.x + threadIdx.x;
    if (idx >= NE * 4) return;
    int j = idx >> 2, ch = idx & 3;
    int eid = csr_eid[j];
    const float* sp = ef + (size_t)eid * EDIM + ch * 8;
    float4 v0 = *(const float4*)sp;
    float4 v1 = *(const float4*)(sp + 4);
    float vv[8] = {v0.x, v0.y, v0.z, v0.w, v1.x, v1.y, v1.z, v1.w};
    unsigned short hh[8], ll[8];
    #pragma unroll
    for (int i = 0; i < 8; i++) {
        hh[i] = f2bf(vv[i]);
        ll[i] = f2bf(vv[i] - bf2f(hh[i]));
    }
    size_t o = (size_t)j * EDIM + ch * 8;
    *(u16x4*)&efp_h[o]     = (u16x4){hh[0], hh[1], hh[2], hh[3]};
    *(u16x4*)&efp_h[o + 4] = (u16x4){hh[4], hh[5], hh[6], hh[7]};
    *(u16x4*)&efp_l[o]     = (u16x4){ll[0], ll[1], ll[2], ll[3]};
    *(u16x4*)&efp_l[o + 4] = (u16x4){ll[4], ll[5], ll[6], ll[7]};
    if (ch == 0) { srcf[j] = csr_src[j]; dstf[j] = csr_dst[j]; }
}

// ---------------------------------------------------------------------------
// self_slots: per-node mean of incident edge attrs (sequential scan of efp),
// written as bf16 hi/lo into the self-loop slots NE..NE+NN of efp.
// ---------------------------------------------------------------------------
__global__ void self_slots(const int* __restrict__ row_ptr,
                           unsigned short* __restrict__ efp_h, unsigned short* __restrict__ efp_l,
                           int* __restrict__ srcf, int* __restrict__ dstf) {
    int idx = blockIdx.x * blockDim.x + threadIdx.x;
    if (idx >= NN * EDIM) return;
    int n = idx >> 5, c = idx & 31;
    int s = row_ptr[n], e = row_ptr[n + 1];
    float acc = 0.f;
    for (int j = s; j < e; j++)
        acc += bf2f(efp_h[(size_t)j * EDIM + c]) + bf2f(efp_l[(size_t)j * EDIM + c]);
    float m = acc / (float)max(e - s, 1);
    unsigned short h = f2bf(m);
    unsigned short l = f2bf(m - bf2f(h));
    size_t o = (size_t)(NE + n) * EDIM + c;
    efp_h[o] = h;
    efp_l[o] = l;
    if (c == 0) { srcf[NE + n] = n; dstf[NE + n] = n; }
}

// ---------------------------------------------------------------------------
// Weight pre-passes
// ---------------------------------------------------------------------------
// W[K][N] fp32 -> transposed bf16 hi/lo [N][K] (for MFMA GEMM)
__global__ void conv_wt(const float* __restrict__ W, unsigned short* __restrict__ hi,
                        unsigned short* __restrict__ lo, int K, int Nn) {
    int idx = blockIdx.x * blockDim.x + threadIdx.x;
    if (idx >= K * Nn) return;
    int k = idx / Nn, n = idx - k * Nn;
    float x = W[idx];
    unsigned short h = f2bf(x);
    unsigned short l = f2bf(x - bf2f(h));
    hi[(size_t)n * K + k] = h;
    lo[(size_t)n * K + k] = l;
}

// We[EDIM][HC] fp32 -> PERMUTED transposed bf16 hi/lo [HC][EDIM].
// Row r of Weth holds We column ((r&15)<<4)|(r>>4): MFMA output channel at
// (tile ct, col m) is m*16+ct -> lane owns 16 consecutive channels.
__global__ void conv_wet(const float* __restrict__ We, unsigned short* __restrict__ hi,
                         unsigned short* __restrict__ lo) {
    int idx = blockIdx.x * blockDim.x + threadIdx.x;
    if (idx >= EDIM * HC) return;
    int k = idx / HC, c = idx - k * HC;
    float x = We[idx];
    unsigned short h = f2bf(x);
    unsigned short l = f2bf(x - bf2f(h));
    int r = ((c & 15) << 4) | (c >> 4);   // inverse of c = (r&15)*16 + (r>>4)
    hi[(size_t)r * EDIM + k] = h;
    lo[(size_t)r * EDIM + k] = l;
}

__global__ void concat_bias(const float* __restrict__ a, const float* __restrict__ b,
                            float* __restrict__ o) {
    int i = threadIdx.x;
    o[i] = a[i];
    o[i + HC] = b[i];
}

#define LDT 40

// ---------------------------------------------------------------------------
// Wide fused GEMM: C[M,512] = A[M,K] @ [Wl|Wr] + [bl|br].  Tile 64x128,
// 256 threads, 8 16x16 col-tiles per wave row-group. 3-term split-bf16.
// Output: FP16 xlr buffer, row stride XLR=512 (xl = 0..255, xr = 256..511).
// ---------------------------------------------------------------------------
__global__ __launch_bounds__(256, 2)
void gemm_wide(const float* __restrict__ A, const unsigned short* __restrict__ Bth,
               const unsigned short* __restrict__ Btl, const float* __restrict__ bias,
               f16* __restrict__ C, int M, int K) {
    __shared__ unsigned short Ah[64][LDT], Al[64][LDT];
    __shared__ unsigned short Bh[128][LDT], Bl[128][LDT];
    int tid = threadIdx.x;
    int lane = tid & 63, w = tid >> 6;
    int m = lane & 15, q = lane >> 4;
    int rowBase = blockIdx.y * 64, colBase = blockIdx.x * 128;
    f32x4 acc[8];
    #pragma unroll
    for (int ct = 0; ct < 8; ct++) acc[ct] = (f32x4){0.f, 0.f, 0.f, 0.f};

    for (int kk = 0; kk < K; kk += 32) {
        // ---- stage A: 64 rows x 32 k fp32 -> hi/lo bf16 (2 float4 / thread)
        #pragma unroll
        for (int u = 0; u < 2; u++) {
            int f = tid + 256 * u;
            int r = f >> 3;
            int k4 = (f & 7) * 4;
            int row = rowBase + r;
            float4 v = make_float4(0.f, 0.f, 0.f, 0.f);
            if (row < M) v = *(const float4*)(A + (size_t)row * K + kk + k4);
            unsigned short h0 = f2bf(v.x), h1 = f2bf(v.y), h2 = f2bf(v.z), h3 = f2bf(v.w);
            unsigned short l0 = f2bf(v.x - bf2f(h0)), l1 = f2bf(v.y - bf2f(h1));
            unsigned short l2 = f2bf(v.z - bf2f(h2)), l3 = f2bf(v.w - bf2f(h3));
            *(u16x4*)&Ah[r][k4] = (u16x4){h0, h1, h2, h3};
            *(u16x4*)&Al[r][k4] = (u16x4){l0, l1, l2, l3};
        }
        // ---- stage B: 128 rows x 32 k bf16 hi/lo (2 chunks / thread)
        #pragma unroll
        for (int u = 0; u < 2; u++) {
            int f = tid + 256 * u;
            int n = f >> 2;
            int ch = f & 3;
            size_t goff = (size_t)(colBase + n) * K + kk + ch * 8;
            *(bf16x8*)&Bh[n][ch * 8] = *(const bf16x8*)(Bth + goff);
            *(bf16x8*)&Bl[n][ch * 8] = *(const bf16x8*)(Btl + goff);
        }
        __syncthreads();
        bf16x8 a_h = *(const bf16x8*)&Ah[w * 16 + m][q * 8];
        bf16x8 a_l = *(const bf16x8*)&Al[w * 16 + m][q * 8];
        #pragma unroll
        for (int ct = 0; ct < 8; ct++) {
            bf16x8 b_h = *(const bf16x8*)&Bh[ct * 16 + m][q * 8];
            bf16x8 b_l = *(const bf16x8*)&Bl[ct * 16 + m][q * 8];
            acc[ct] = __builtin_amdgcn_mfma_f32_16x16x32_bf16(a_h, b_h, acc[ct], 0, 0, 0);
            acc[ct] = __builtin_amdgcn_mfma_f32_16x16x32_bf16(a_l, b_h, acc[ct], 0, 0, 0);
            acc[ct] = __builtin_amdgcn_mfma_f32_16x16x32_bf16(a_h, b_l, acc[ct], 0, 0, 0);
        }
        __syncthreads();
    }
    #pragma unroll
    for (int ct = 0; ct < 8; ct++) {
        int col = colBase + ct * 16 + m;
        float bb = bias[col];
        #pragma unroll
        for (int r = 0; r < 4; r++) {
            int row = rowBase + w * 16 + q * 4 + r;
            if (row < M) C[(size_t)row * XLR + col] = (f16)(acc[ct][r] + bb);
        }
    }
}

// ---------------------------------------------------------------------------
// MFMA split-bf16 GEMM (64x64) with fused LayerNorm epilogue (Nn==64).
// Used for the local head only (fp32 in/out, unchanged).
// ---------------------------------------------------------------------------
__global__ __launch_bounds__(256, 2)
void gemm_head(const float* __restrict__ A, const unsigned short* __restrict__ Bth,
               const unsigned short* __restrict__ Btl, const float* __restrict__ bias,
               float* __restrict__ C, int M, int K,
               const float* __restrict__ ln_g, const float* __restrict__ ln_b) {
    __shared__ unsigned short Ah[64][LDT], Al[64][LDT];
    __shared__ unsigned short Bh[64][LDT], Bl[64][LDT];
    int tid = threadIdx.x;
    int lane = tid & 63, w = tid >> 6;
    int m = lane & 15, q = lane >> 4;
    int rowBase = blockIdx.y * 64;
    f32x4 acc[4];
    #pragma unroll
    for (int ct = 0; ct < 4; ct++) acc[ct] = (f32x4){0.f, 0.f, 0.f, 0.f};

    for (int kk = 0; kk < K; kk += 32) {
        #pragma unroll
        for (int u = 0; u < 2; u++) {
            int f = tid + 256 * u;
            int r = f >> 3;
            int k4 = (f & 7) * 4;
            int row = rowBase + r;
            float4 v = make_float4(0.f, 0.f, 0.f, 0.f);
            if (row < M) v = *(const float4*)(A + (size_t)row * K + kk + k4);
            unsigned short h0 = f2bf(v.x), h1 = f2bf(v.y), h2 = f2bf(v.z), h3 = f2bf(v.w);
            unsigned short l0 = f2bf(v.x - bf2f(h0)), l1 = f2bf(v.y - bf2f(h1));
            unsigned short l2 = f2bf(v.z - bf2f(h2)), l3 = f2bf(v.w - bf2f(h3));
            *(u16x4*)&Ah[r][k4] = (u16x4){h0, h1, h2, h3};
            *(u16x4*)&Al[r][k4] = (u16x4){l0, l1, l2, l3};
        }
        {
            int n = tid >> 2;
            int ch = tid & 3;
            size_t goff = (size_t)n * K + kk + ch * 8;
            *(bf16x8*)&Bh[n][ch * 8] = *(const bf16x8*)(Bth + goff);
            *(bf16x8*)&Bl[n][ch * 8] = *(const bf16x8*)(Btl + goff);
        }
        __syncthreads();
        bf16x8 a_h = *(const bf16x8*)&Ah[w * 16 + m][q * 8];
        bf16x8 a_l = *(const bf16x8*)&Al[w * 16 + m][q * 8];
        #pragma unroll
        for (int ct = 0; ct < 4; ct++) {
            bf16x8 b_h = *(const bf16x8*)&Bh[ct * 16 + m][q * 8];
            bf16x8 b_l = *(const bf16x8*)&Bl[ct * 16 + m][q * 8];
            acc[ct] = __builtin_amdgcn_mfma_f32_16x16x32_bf16(a_h, b_h, acc[ct], 0, 0, 0);
            acc[ct] = __builtin_amdgcn_mfma_f32_16x16x32_bf16(a_l, b_h, acc[ct], 0, 0, 0);
            acc[ct] = __builtin_amdgcn_mfma_f32_16x16x32_bf16(a_h, b_l, acc[ct], 0, 0, 0);
        }
        __syncthreads();
    }
    // LN epilogue: row held by 16 lanes (m) x 4 cols (ct)
    #pragma unroll
    for (int r = 0; r < 4; r++) {
        float v[4];
        float sum = 0.f;
        #pragma unroll
        for (int ct = 0; ct < 4; ct++) {
            v[ct] = acc[ct][r] + bias[ct * 16 + m];
            sum += v[ct];
        }
        sum += __shfl_xor(sum, 1); sum += __shfl_xor(sum, 2);
        sum += __shfl_xor(sum, 4); sum += __shfl_xor(sum, 8);
        float mu = sum * (1.f / 64.f);
        float sq = 0.f;
        #pragma unroll
        for (int ct = 0; ct < 4; ct++) {
            float d = v[ct] - mu;
            sq += d * d;
        }
        sq += __shfl_xor(sq, 1); sq += __shfl_xor(sq, 2);
        sq += __shfl_xor(sq, 4); sq += __shfl_xor(sq, 8);
        float inv = rsqrtf(sq * (1.f / 64.f) + LN_EPS);
        int row = rowBase + w * 16 + q * 4 + r;
        if (row < M) {
            #pragma unroll
            for (int ct = 0; ct < 4; ct++) {
                int col = ct * 16 + m;
                C[(size_t)row * 64 + col] = (v[ct] - mu) * inv * ln_g[col] + ln_b[col];
            }
        }
    }
}

// ---------------------------------------------------------------------------
// score_kernel (persistent): per 64-slot group, ee = ea @ We via split-bf16
// MFMA, fused GATv2 score epilogue -> alpha[slot][h]. Stage A streams the
// pre-permuted efp buffer; xl/xr gathered from the FP16 xlr buffer.
// Lane m owns channels [m*16 .. m*16+15].
// ---------------------------------------------------------------------------
__global__ __launch_bounds__(256, 2)
void score_kernel(const unsigned short* __restrict__ efp_h,
                  const unsigned short* __restrict__ efp_l,
                  const int* __restrict__ srcf, const int* __restrict__ dstf,
                  const f16* __restrict__ xlr,
                  const unsigned short* __restrict__ Weth,
                  const unsigned short* __restrict__ Wetl,
                  const float* __restrict__ att, float* __restrict__ alpha) {
    __shared__ unsigned short Ah[64][LDT], Al[64][LDT];
    __shared__ unsigned short Bh[256][LDT], Bl[256][LDT];
    __shared__ int s_src[64], s_dst[64];
    int tid = threadIdx.x;
    int lane = tid & 63, w = tid >> 6;
    int m = lane & 15, q = lane >> 4;

    // stage B (We^T permuted, [256][32] hi/lo) ONCE
    #pragma unroll
    for (int u = 0; u < 4; u++) {
        *(bf16x8*)&Bh[tid][u * 8] = *(const bf16x8*)(Weth + (size_t)tid * EDIM + u * 8);
        *(bf16x8*)&Bl[tid][u * 8] = *(const bf16x8*)(Wetl + (size_t)tid * EDIM + u * 8);
    }
    // attv[ct] = att coefficient of channel m*16+ct
    float attv[16];
    #pragma unroll
    for (int u = 0; u < 4; u++) {
        float4 a4 = *(const float4*)(att + m * 16 + u * 4);
        attv[u * 4 + 0] = a4.x; attv[u * 4 + 1] = a4.y;
        attv[u * 4 + 2] = a4.z; attv[u * 4 + 3] = a4.w;
    }

    int groups = (EESLOTS + 63) >> 6;
    for (int g = blockIdx.x; g < groups; g += gridDim.x) {
        int base = g << 6;
        __syncthreads();   // protect Ah/Al + s_src reads of previous group
        // stage A: 64 slots x 32 k, sequential bf16 hi/lo stream from efp
        {
            int r = tid >> 2, ch = tid & 3;
            int j = base + r;
            if (j >= EESLOTS) j = EESLOTS - 1;
            size_t o = (size_t)j * EDIM + ch * 8;
            *(bf16x8*)&Ah[r][ch * 8] = *(const bf16x8*)(efp_h + o);
            *(bf16x8*)&Al[r][ch * 8] = *(const bf16x8*)(efp_l + o);
            if (ch == 0) { s_src[r] = srcf[j]; s_dst[r] = dstf[j]; }
        }
        __syncthreads();

        bf16x8 a_h = *(const bf16x8*)&Ah[w * 16 + m][q * 8];
        bf16x8 a_l = *(const bf16x8*)&Al[w * 16 + m][q * 8];
        f32x4 acc[16];
        #pragma unroll
        for (int ct = 0; ct < 16; ct++) {
            bf16x8 b_h = *(const bf16x8*)&Bh[ct * 16 + m][q * 8];
            bf16x8 b_l = *(const bf16x8*)&Bl[ct * 16 + m][q * 8];
            f32x4 c = (f32x4){0.f, 0.f, 0.f, 0.f};
            c = __builtin_amdgcn_mfma_f32_16x16x32_bf16(a_h, b_h, c, 0, 0, 0);
            c = __builtin_amdgcn_mfma_f32_16x16x32_bf16(a_l, b_h, c, 0, 0, 0);
            c = __builtin_amdgcn_mfma_f32_16x16x32_bf16(a_h, b_l, c, 0, 0, 0);
            acc[ct] = c;
        }

        // epilogue: per-slot score (fp16 gathers, 32 B per side per lane)
        #pragma unroll
        for (int r = 0; r < 4; r++) {
            int sl = w * 16 + q * 4 + r;
            int slot = base + sl;
            int ss = s_src[sl], dd = s_dst[sl];
            const f16* xlp = xlr + (size_t)ss * XLR + m * 16;         // xl part
            const f16* xrp = xlr + (size_t)dd * XLR + HC + m * 16;    // xr part
            f16x8 xa0 = *(const f16x8*)(xlp);
            f16x8 xa1 = *(const f16x8*)(xlp + 8);
            f16x8 xb0 = *(const f16x8*)(xrp);
            f16x8 xb1 = *(const f16x8*)(xrp + 8);
            float s = 0.f;
            #pragma unroll
            for (int i = 0; i < 8; i++) {
                float z0 = (float)xa0[i] + (float)xb0[i] + acc[i][r];
                float lz0 = fmaxf(z0, 0.f) + 0.2f * fminf(z0, 0.f);
                s += lz0 * attv[i];
                float z1 = (float)xa1[i] + (float)xb1[i] + acc[8 + i][r];
                float lz1 = fmaxf(z1, 0.f) + 0.2f * fminf(z1, 0.f);
                s += lz1 * attv[8 + i];
            }
            // head h = m>>2: reduce over the 4 lanes m in [4h..4h+3]
            s += __shfl_xor(s, 1);
            s += __shfl_xor(s, 2);
            if ((m & 3) == 0 && slot < EESLOTS) {
                alpha[(size_t)slot * 4 + (m >> 2)] = s;
            }
        }
    }
}

// ---------------------------------------------------------------------------
// Lean aggregation: softmax over precomputed alpha (shift = alpha_self),
// weighted gather of fp16 xl (cols 0..255 of xlr). One wave per node, ILP x4.
// fp32 accumulation; fp32 output xb.
// ---------------------------------------------------------------------------
__global__ __launch_bounds__(256)
void gat_aggr(const f16* __restrict__ xlr, const float* __restrict__ alpha,
              const int* __restrict__ row_ptr, const int* __restrict__ csr_src,
              const float* __restrict__ bias, float* __restrict__ out, int do_relu) {
    int lane = threadIdx.x & 63;
    int wv = threadIdx.x >> 6;
    int n = blockIdx.x * 4 + wv;
    if (n >= NN) return;
    int h = lane >> 4;
    float4 bb = *(const float4*)(bias + 4 * lane);
    int s0 = row_ptr[n], e0 = row_ptr[n + 1];
    float aself = alpha[(size_t)(NE + n) * 4 + h];
    float denom = 1.f;
    f16x4 xs = *(const f16x4*)(xlr + (size_t)n * XLR + 4 * lane);
    float4 acc = make_float4((float)xs[0], (float)xs[1], (float)xs[2], (float)xs[3]);

    for (int j0 = s0; j0 < e0; j0 += 64) {
        int cnt = min(64, e0 - j0);
        int sidx = (j0 + lane < e0) ? csr_src[j0 + lane] : 0;
        int t = 0;
        for (; t + 3 < cnt; t += 4) {
            int sa = __shfl(sidx, t);
            int sb = __shfl(sidx, t + 1);
            int sc = __shfl(sidx, t + 2);
            int sd = __shfl(sidx, t + 3);
            float a0 = __expf(alpha[(size_t)(j0 + t) * 4 + h] - aself);
            float a1 = __expf(alpha[(size_t)(j0 + t + 1) * 4 + h] - aself);
            float a2 = __expf(alpha[(size_t)(j0 + t + 2) * 4 + h] - aself);
            float a3 = __expf(alpha[(size_t)(j0 + t + 3) * 4 + h] - aself);
            f16x4 x0 = *(const f16x4*)(xlr + (size_t)sa * XLR + 4 * lane);
            f16x4 x1 = *(const f16x4*)(xlr + (size_t)sb * XLR + 4 * lane);
            f16x4 x2 = *(const f16x4*)(xlr + (size_t)sc * XLR + 4 * lane);
            f16x4 x3 = *(const f16x4*)(xlr + (size_t)sd * XLR + 4 * lane);
            denom += a0 + a1 + a2 + a3;
            acc.x += a0 * (float)x0[0] + a1 * (float)x1[0] + a2 * (float)x2[0] + a3 * (float)x3[0];
            acc.y += a0 * (float)x0[1] + a1 * (float)x1[1] + a2 * (float)x2[1] + a3 * (float)x3[1];
            acc.z += a0 * (float)x0[2] + a1 * (float)x1[2] + a2 * (float)x2[2] + a3 * (float)x3[2];
            acc.w += a0 * (float)x0[3] + a1 * (float)x1[3] + a2 * (float)x2[3] + a3 * (float)x3[3];
        }
        for (; t < cnt; t++) {
            int sa = __shfl(sidx, t);
            float a0 = __expf(alpha[(size_t)(j0 + t) * 4 + h] - aself);
            f16x4 x0 = *(const f16x4*)(xlr + (size_t)sa * XLR + 4 * lane);
            denom += a0;
            acc.x += a0 * (float)x0[0]; acc.y += a0 * (float)x0[1];
            acc.z += a0 * (float)x0[2]; acc.w += a0 * (float)x0[3];
        }
    }

    float inv = 1.f / denom;
    float4 r = make_float4(acc.x * inv + bb.x, acc.y * inv + bb.y,
                           acc.z * inv + bb.z, acc.w * inv + bb.w);
    if (do_relu) {
        r.x = fmaxf(r.x, 0.f); r.y = fmaxf(r.y, 0.f);
        r.z = fmaxf(r.z, 0.f); r.w = fmaxf(r.w, 0.f);
    }
    *(float4*)(out + (size_t)n * HC + 4 * lane) = r;
}

// ---------------------------------------------------------------------------
// Graph mean pre-reduction exploiting sorted batch
// ---------------------------------------------------------------------------
__global__ void graph_sum(const float* __restrict__ x, const int* __restrict__ batch,
                          float* __restrict__ gsum, float* __restrict__ gcnt) {
    int c = threadIdx.x;
    int r0 = blockIdx.x * 256;
    int r1 = min(r0 + 256, NN);
    float acc = 0.f;
    int gcur = batch[r0];
    for (int n = r0; n < r1; n++) {
        int g = batch[n];
        if (g != gcur) {
            atomicAdd(&gsum[(size_t)gcur * HC + c], acc);
            acc = 0.f; gcur = g;
        }
        acc += x[(size_t)n * HC + c];
    }
    atomicAdd(&gsum[(size_t)gcur * HC + c], acc);
    if (c == 0) {
        int cnt = 0; gcur = batch[r0];
        for (int n = r0; n < r1; n++) {
            int g = batch[n];
            if (g != gcur) {
                atomicAdd(&gcnt[gcur], (float)cnt);
                cnt = 0; gcur = g;
            }
            cnt++;
        }
        atomicAdd(&gcnt[gcur], (float)cnt);
    }
}

__global__ void glob_kernel(const float* __restrict__ gsum, const float* __restrict__ gcnt,
                            const float* __restrict__ W, const float* __restrict__ bias,
                            const float* __restrict__ g, const float* __restrict__ b,
                            float* __restrict__ out) {
    int gi = blockIdx.x;
    int lane = threadIdx.x;
    float inv = 1.f / fmaxf(gcnt[gi], 1.f);
    float acc = 0.f;
    for (int k = 0; k < HC; k++)
        acc += (gsum[(size_t)gi * HC + k] * inv) * W[(size_t)k * ND + lane];
    acc += bias[lane];
    float s = acc;
    #pragma unroll
    for (int o = 32; o >= 1; o >>= 1) s += __shfl_xor(s, o);
    float mu = s * (1.f / 64.f);
    float dv = acc - mu;
    float q = dv * dv;
    #pragma unroll
    for (int o = 32; o >= 1; o >>= 1) q += __shfl_xor(q, o);
    float var = q * (1.f / 64.f);
    out[(size_t)gi * ND + lane] = dv * rsqrtf(var + LN_EPS) * g[lane] + b[lane];
}

// ---------------------------------------------------------------------------
extern "C" void kernel_launch(void* const* d_in, const int* in_sizes, int n_in,
                              void* d_out, int out_size, void* d_ws, size_t ws_size,
                              hipStream_t stream) {
    (void)in_sizes; (void)n_in; (void)out_size; (void)ws_size;
    const float* node_feature = (const float*)d_in[0];
    const int*   edge_index   = (const int*)d_in[1];
    const float* edge_feature = (const float*)d_in[2];
    const int*   batch        = (const int*)d_in[3];
    const float* Wl0   = (const float*)d_in[4];
    const float* bl0   = (const float*)d_in[5];
    const float* Wr0   = (const float*)d_in[6];
    const float* br0   = (const float*)d_in[7];
    const float* We0   = (const float*)d_in[8];
    const float* att0  = (const float*)d_in[9];
    const float* bias0 = (const float*)d_in[10];
    const float* Wl1   = (const float*)d_in[11];
    const float* bl1   = (const float*)d_in[12];
    const float* Wr1   = (const float*)d_in[13];
    const float* br1   = (const float*)d_in[14];
    const float* We1   = (const float*)d_in[15];
    const float* att1  = (const float*)d_in[16];
    const float* bias1 = (const float*)d_in[17];
    const float* node_W  = (const float*)d_in[18];
    const float* node_b  = (const float*)d_in[19];
    const float* graph_W = (const float*)d_in[20];
    const float* graph_b = (const float*)d_in[21];
    const float* nn_g = (const float*)d_in[22];
    const float* nn_b = (const float*)d_in[23];
    const float* gn_g = (const float*)d_in[24];
    const float* gn_b = (const float*)d_in[25];

    const int* src = edge_index;
    const int* dst = edge_index + NE;

    char* p = (char*)d_ws;
    auto carve = [&](size_t bytes) {
        char* r = p;
        p += (bytes + 255) & ~(size_t)255;
        return r;
    };
    int*   row_ptr   = (int*)carve((NN + 1) * sizeof(int));
    int*   cursor    = (int*)carve(NN * sizeof(int));
    int*   deg       = (int*)carve(NN * sizeof(int));
    int*   bsum      = (int*)carve(SCAN_B * sizeof(int));
    int*   boff      = (int*)carve(SCAN_B * sizeof(int));
    int*   csr_src   = (int*)carve((size_t)NE * sizeof(int));
    int*   csr_dst   = (int*)carve((size_t)NE * sizeof(int));
    int*   csr_eid   = (int*)carve((size_t)NE * sizeof(int));
    int*   srcf      = (int*)carve((size_t)EESLOTS * sizeof(int));
    int*   dstf      = (int*)carve((size_t)EESLOTS * sizeof(int));
    unsigned short* efp_h = (unsigned short*)carve((size_t)EESLOTS * EDIM * sizeof(unsigned short));
    unsigned short* efp_l = (unsigned short*)carve((size_t)EESLOTS * EDIM * sizeof(unsigned short));
    f16*   xlr       = (f16*)carve((size_t)NN * XLR * sizeof(f16));   // fp16 xl|xr fused
    float* xb        = (float*)carve((size_t)NN * HC * sizeof(float));
    float* alpha     = (float*)carve((size_t)EESLOTS * NH * sizeof(float));
    float* gsum      = (float*)carve((size_t)(NGG * HC + NGG) * sizeof(float));
    float* gcnt      = gsum + (size_t)NGG * HC;
    // concat bf16 transposed weights [512][K] hi/lo
    unsigned short* wlr0h = (unsigned short*)carve((size_t)XLR * DIN * 2 * 2);
    unsigned short* wlr0l = wlr0h + (size_t)XLR * DIN;
    unsigned short* wlr1h = (unsigned short*)carve((size_t)XLR * HC * 2 * 2);
    unsigned short* wlr1l = wlr1h + (size_t)XLR * HC;
    unsigned short* nwh   = (unsigned short*)carve((size_t)HC * ND * 2 * 2);
    unsigned short* nwl   = nwh + (size_t)HC * ND;
    unsigned short* we0h  = (unsigned short*)carve((size_t)EDIM * HC * 2 * 2);
    unsigned short* we0l  = we0h + (size_t)EDIM * HC;
    unsigned short* we1h  = (unsigned short*)carve((size_t)EDIM * HC * 2 * 2);
    unsigned short* we1l  = we1h + (size_t)EDIM * HC;
    float* b0cat = (float*)carve(XLR * sizeof(float));
    float* b1cat = (float*)carve(XLR * sizeof(float));

    hipMemsetAsync(deg, 0, NN * sizeof(int), stream);
    hipMemsetAsync(gsum, 0, (NGG * HC + NGG) * sizeof(float), stream);

    // CSR (3-kernel scan) + efp pre-permutation + weight conversion
    count_deg<<<(NE + 255) / 256, 256, 0, stream>>>(dst, deg);
    scan_bsum<<<SCAN_NB, SCAN_B, 0, stream>>>(deg, bsum);
    scan_boff<<<1, SCAN_B, 0, stream>>>(bsum, boff);
    scan_final<<<SCAN_NB, SCAN_B, 0, stream>>>(deg, boff, row_ptr, cursor);
    fill_csr<<<(NE + 255) / 256, 256, 0, stream>>>(src, dst, cursor, csr_src, csr_dst, csr_eid);
    perm_ef<<<(NE * 4 + 255) / 256, 256, 0, stream>>>(edge_feature, csr_eid, csr_src, csr_dst,
                                                      efp_h, efp_l, srcf, dstf);
    self_slots<<<(NN * EDIM + 255) / 256, 256, 0, stream>>>(row_ptr, efp_h, efp_l, srcf, dstf);
    conv_wt<<<(DIN * HC + 255) / 256, 256, 0, stream>>>(Wl0, wlr0h, wlr0l, DIN, HC);
    conv_wt<<<(DIN * HC + 255) / 256, 256, 0, stream>>>(Wr0, wlr0h + (size_t)HC * DIN, wlr0l + (size_t)HC * DIN, DIN, HC);
    conv_wt<<<(HC * HC + 255) / 256, 256, 0, stream>>>(Wl1, wlr1h, wlr1l, HC, HC);
    conv_wt<<<(HC * HC + 255) / 256, 256, 0, stream>>>(Wr1, wlr1h + (size_t)HC * HC, wlr1l + (size_t)HC * HC, HC, HC);
    conv_wt<<<(HC * ND + 255) / 256, 256, 0, stream>>>(node_W, nwh, nwl, HC, ND);
    conv_wet<<<(EDIM * HC + 255) / 256, 256, 0, stream>>>(We0, we0h, we0l);
    conv_wet<<<(EDIM * HC + 255) / 256, 256, 0, stream>>>(We1, we1h, we1l);
    concat_bias<<<1, 256, 0, stream>>>(bl0, br0, b0cat);
    concat_bias<<<1, 256, 0, stream>>>(bl1, br1, b1cat);

    dim3 gw(4, (NN + 63) / 64);
    // Layer 0
    gemm_wide<<<gw, 256, 0, stream>>>(node_feature, wlr0h, wlr0l, b0cat, xlr, NN, DIN);
    score_kernel<<<2048, 256, 0, stream>>>(efp_h, efp_l, srcf, dstf,
                                           xlr, we0h, we0l, att0, alpha);
    gat_aggr<<<(NN + 3) / 4, 256, 0, stream>>>(xlr, alpha, row_ptr, csr_src, bias0, xb, 1);
    // Layer 1
    gemm_wide<<<gw, 256, 0, stream>>>(xb, wlr1h, wlr1l, b1cat, xlr, NN, HC);
    score_kernel<<<2048, 256, 0, stream>>>(efp_h, efp_l, srcf, dstf,
                                           xlr, we1h, we1l, att1, alpha);
    gat_aggr<<<(NN + 3) / 4, 256, 0, stream>>>(xlr, alpha, row_ptr, csr_src, bias1, xb, 0);

    // Heads
    float* out_local = (float*)d_out;
    float* out_glob  = out_local + (size_t)NN * ND;
    dim3 gh(1, (NN + 63) / 64);
    gemm_head<<<gh, 256, 0, stream>>>(xb, nwh, nwl, node_b, out_local, NN, HC, nn_g, nn_b);
    graph_sum<<<(NN + 255) / 256, 256, 0, stream>>>(xb, batch, gsum, gcnt);
    glob_kernel<<<NGG, 64, 0, stream>>>(gsum, gcnt, graph_W, graph_b, gn_g, gn_b, out_glob);
}

// Round 8
// 706.657 us; speedup vs baseline: 1.5627x; 1.0550x over previous
//
#include <hip/hip_runtime.h>
#include <cstdint>
#include <cstddef>

#define NN   50000
#define NE   500000
#define DIN  64
#define EDIM 32
#define NH   4
#define NC   64
#define HC   256   // NH*NC
#define NGG  64
#define ND   64
#define LN_EPS 1e-5f
#define EESLOTS (NE + NN)   // edges + self-loops, CSR-slot order
#define XLR  512            // row stride of fused xl|xr buffer (fp16)
#define SCAN_B   256
#define SCAN_NB  ((NN + SCAN_B - 1) / SCAN_B)   // 196

typedef __attribute__((ext_vector_type(8))) short bf16x8;
typedef __attribute__((ext_vector_type(4))) float f32x4;
typedef __attribute__((ext_vector_type(4))) unsigned short u16x4;
typedef _Float16 f16;
typedef __attribute__((ext_vector_type(4))) _Float16 f16x4;
typedef __attribute__((ext_vector_type(8))) _Float16 f16x8;

__device__ __forceinline__ unsigned short f2bf(float x) {
    unsigned u = __float_as_uint(x);
    unsigned r = (u + 0x7FFFu + ((u >> 16) & 1u)) >> 16;
    return (unsigned short)r;
}
__device__ __forceinline__ float bf2f(unsigned short h) {
    return __uint_as_float(((unsigned)h) << 16);
}

// ---------------------------------------------------------------------------
// CSR build: degree count -> 3-kernel device-wide scan -> fill
// ---------------------------------------------------------------------------
__global__ void count_deg(const int* __restrict__ dst, int* __restrict__ deg) {
    int e = blockIdx.x * blockDim.x + threadIdx.x;
    if (e < NE) atomicAdd(&deg[dst[e]], 1);
}

__global__ void scan_bsum(const int* __restrict__ deg, int* __restrict__ bsum) {
    __shared__ int s[SCAN_B];
    int t = threadIdx.x;
    int i = blockIdx.x * SCAN_B + t;
    s[t] = (i < NN) ? deg[i] : 0;
    __syncthreads();
    #pragma unroll
    for (int off = SCAN_B / 2; off > 0; off >>= 1) {
        if (t < off) s[t] += s[t + off];
        __syncthreads();
    }
    if (t == 0) bsum[blockIdx.x] = s[0];
}

__global__ void scan_boff(const int* __restrict__ bsum, int* __restrict__ boff) {
    __shared__ int s[SCAN_B];
    int t = threadIdx.x;
    int v = (t < SCAN_NB) ? bsum[t] : 0;
    s[t] = v;
    __syncthreads();
    #pragma unroll
    for (int off = 1; off < SCAN_B; off <<= 1) {
        int u = (t >= off) ? s[t - off] : 0;
        __syncthreads();
        s[t] += u;
        __syncthreads();
    }
    boff[t] = s[t] - v;   // exclusive
}

__global__ void scan_final(const int* __restrict__ deg, const int* __restrict__ boff,
                           int* __restrict__ row_ptr, int* __restrict__ cursor) {
    __shared__ int s[SCAN_B];
    int t = threadIdx.x;
    int i = blockIdx.x * SCAN_B + t;
    int v = (i < NN) ? deg[i] : 0;
    s[t] = v;
    __syncthreads();
    #pragma unroll
    for (int off = 1; off < SCAN_B; off <<= 1) {
        int u = (t >= off) ? s[t - off] : 0;
        __syncthreads();
        s[t] += u;
        __syncthreads();
    }
    int excl = boff[blockIdx.x] + s[t] - v;
    if (i < NN) {
        row_ptr[i] = excl;
        cursor[i] = excl;
    }
    if (i == 0) row_ptr[NN] = NE;
}

__global__ void fill_csr(const int* __restrict__ src, const int* __restrict__ dst,
                         int* __restrict__ cursor, int* __restrict__ csr_src,
                         int* __restrict__ csr_dst, int* __restrict__ csr_eid) {
    int e = blockIdx.x * blockDim.x + threadIdx.x;
    if (e < NE) {
        int d = dst[e];
        int pos = atomicAdd(&cursor[d], 1);
        csr_src[pos] = src[e];
        csr_dst[pos] = d;
        csr_eid[pos] = e;
    }
}

// ---------------------------------------------------------------------------
// perm_ef: materialize ef in CSR-slot order as f16 (single precision path —
// ee consumers already carry fp16-level error from the xlr buffer), and
// build full src/dst arrays.
// ---------------------------------------------------------------------------
__global__ void perm_ef(const float* __restrict__ ef, const int* __restrict__ csr_eid,
                        const int* __restrict__ csr_src, const int* __restrict__ csr_dst,
                        f16* __restrict__ efp,
                        int* __restrict__ srcf, int* __restrict__ dstf) {
    int idx = blockIdx.x * blockDim.x + threadIdx.x;
    if (idx >= NE * 4) return;
    int j = idx >> 2, ch = idx & 3;
    int eid = csr_eid[j];
    const float* sp = ef + (size_t)eid * EDIM + ch * 8;
    float4 v0 = *(const float4*)sp;
    float4 v1 = *(const float4*)(sp + 4);
    f16x8 o;
    o[0] = (f16)v0.x; o[1] = (f16)v0.y; o[2] = (f16)v0.z; o[3] = (f16)v0.w;
    o[4] = (f16)v1.x; o[5] = (f16)v1.y; o[6] = (f16)v1.z; o[7] = (f16)v1.w;
    *(f16x8*)(efp + (size_t)j * EDIM + ch * 8) = o;
    if (ch == 0) { srcf[j] = csr_src[j]; dstf[j] = csr_dst[j]; }
}

// ---------------------------------------------------------------------------
// self_slots: per-node mean of incident edge attrs (sequential scan of efp),
// written as f16 into the self-loop slots NE..NE+NN of efp.
// ---------------------------------------------------------------------------
__global__ void self_slots(const int* __restrict__ row_ptr,
                           f16* __restrict__ efp,
                           int* __restrict__ srcf, int* __restrict__ dstf) {
    int idx = blockIdx.x * blockDim.x + threadIdx.x;
    if (idx >= NN * EDIM) return;
    int n = idx >> 5, c = idx & 31;
    int s = row_ptr[n], e = row_ptr[n + 1];
    float acc = 0.f;
    for (int j = s; j < e; j++)
        acc += (float)efp[(size_t)j * EDIM + c];
    float m = acc / (float)max(e - s, 1);
    efp[(size_t)(NE + n) * EDIM + c] = (f16)m;
    if (c == 0) { srcf[NE + n] = n; dstf[NE + n] = n; }
}

// ---------------------------------------------------------------------------
// Weight pre-passes
// ---------------------------------------------------------------------------
// W[K][N] fp32 -> transposed bf16 hi/lo [N][K] (for MFMA GEMM, accurate path)
__global__ void conv_wt(const float* __restrict__ W, unsigned short* __restrict__ hi,
                        unsigned short* __restrict__ lo, int K, int Nn) {
    int idx = blockIdx.x * blockDim.x + threadIdx.x;
    if (idx >= K * Nn) return;
    int k = idx / Nn, n = idx - k * Nn;
    float x = W[idx];
    unsigned short h = f2bf(x);
    unsigned short l = f2bf(x - bf2f(h));
    hi[(size_t)n * K + k] = h;
    lo[(size_t)n * K + k] = l;
}

// We[EDIM][HC] fp32 -> PERMUTED transposed f16 [HC][EDIM].
// Row r holds We column ((r&15)<<4)|(r>>4): MFMA output channel at
// (tile ct, col m) is m*16+ct -> lane owns 16 consecutive channels.
__global__ void conv_wet(const float* __restrict__ We, f16* __restrict__ wet) {
    int idx = blockIdx.x * blockDim.x + threadIdx.x;
    if (idx >= EDIM * HC) return;
    int k = idx / HC, c = idx - k * HC;
    int r = ((c & 15) << 4) | (c >> 4);   // inverse of c = (r&15)*16 + (r>>4)
    wet[(size_t)r * EDIM + k] = (f16)We[idx];
}

__global__ void concat_bias(const float* __restrict__ a, const float* __restrict__ b,
                            float* __restrict__ o) {
    int i = threadIdx.x;
    o[i] = a[i];
    o[i + HC] = b[i];
}

#define LDT 40

// ---------------------------------------------------------------------------
// Wide fused GEMM: C[M,512] = A[M,K] @ [Wl|Wr] + [bl|br].  Tile 64x128,
// 256 threads, 8 16x16 col-tiles per wave row-group. 3-term split-bf16.
// Output: FP16 xlr buffer, row stride XLR=512 (xl = 0..255, xr = 256..511).
// ---------------------------------------------------------------------------
__global__ __launch_bounds__(256, 2)
void gemm_wide(const float* __restrict__ A, const unsigned short* __restrict__ Bth,
               const unsigned short* __restrict__ Btl, const float* __restrict__ bias,
               f16* __restrict__ C, int M, int K) {
    __shared__ unsigned short Ah[64][LDT], Al[64][LDT];
    __shared__ unsigned short Bh[128][LDT], Bl[128][LDT];
    int tid = threadIdx.x;
    int lane = tid & 63, w = tid >> 6;
    int m = lane & 15, q = lane >> 4;
    int rowBase = blockIdx.y * 64, colBase = blockIdx.x * 128;
    f32x4 acc[8];
    #pragma unroll
    for (int ct = 0; ct < 8; ct++) acc[ct] = (f32x4){0.f, 0.f, 0.f, 0.f};

    for (int kk = 0; kk < K; kk += 32) {
        // ---- stage A: 64 rows x 32 k fp32 -> hi/lo bf16 (2 float4 / thread)
        #pragma unroll
        for (int u = 0; u < 2; u++) {
            int f = tid + 256 * u;
            int r = f >> 3;
            int k4 = (f & 7) * 4;
            int row = rowBase + r;
            float4 v = make_float4(0.f, 0.f, 0.f, 0.f);
            if (row < M) v = *(const float4*)(A + (size_t)row * K + kk + k4);
            unsigned short h0 = f2bf(v.x), h1 = f2bf(v.y), h2 = f2bf(v.z), h3 = f2bf(v.w);
            unsigned short l0 = f2bf(v.x - bf2f(h0)), l1 = f2bf(v.y - bf2f(h1));
            unsigned short l2 = f2bf(v.z - bf2f(h2)), l3 = f2bf(v.w - bf2f(h3));
            *(u16x4*)&Ah[r][k4] = (u16x4){h0, h1, h2, h3};
            *(u16x4*)&Al[r][k4] = (u16x4){l0, l1, l2, l3};
        }
        // ---- stage B: 128 rows x 32 k bf16 hi/lo (2 chunks / thread)
        #pragma unroll
        for (int u = 0; u < 2; u++) {
            int f = tid + 256 * u;
            int n = f >> 2;
            int ch = f & 3;
            size_t goff = (size_t)(colBase + n) * K + kk + ch * 8;
            *(bf16x8*)&Bh[n][ch * 8] = *(const bf16x8*)(Bth + goff);
            *(bf16x8*)&Bl[n][ch * 8] = *(const bf16x8*)(Btl + goff);
        }
        __syncthreads();
        bf16x8 a_h = *(const bf16x8*)&Ah[w * 16 + m][q * 8];
        bf16x8 a_l = *(const bf16x8*)&Al[w * 16 + m][q * 8];
        #pragma unroll
        for (int ct = 0; ct < 8; ct++) {
            bf16x8 b_h = *(const bf16x8*)&Bh[ct * 16 + m][q * 8];
            bf16x8 b_l = *(const bf16x8*)&Bl[ct * 16 + m][q * 8];
            acc[ct] = __builtin_amdgcn_mfma_f32_16x16x32_bf16(a_h, b_h, acc[ct], 0, 0, 0);
            acc[ct] = __builtin_amdgcn_mfma_f32_16x16x32_bf16(a_l, b_h, acc[ct], 0, 0, 0);
            acc[ct] = __builtin_amdgcn_mfma_f32_16x16x32_bf16(a_h, b_l, acc[ct], 0, 0, 0);
        }
        __syncthreads();
    }
    #pragma unroll
    for (int ct = 0; ct < 8; ct++) {
        int col = colBase + ct * 16 + m;
        float bb = bias[col];
        #pragma unroll
        for (int r = 0; r < 4; r++) {
            int row = rowBase + w * 16 + q * 4 + r;
            if (row < M) C[(size_t)row * XLR + col] = (f16)(acc[ct][r] + bb);
        }
    }
}

// ---------------------------------------------------------------------------
// MFMA split-bf16 GEMM (64x64) with fused LayerNorm epilogue (Nn==64).
// Used for the local head only (fp32 in/out, unchanged).
// ---------------------------------------------------------------------------
__global__ __launch_bounds__(256, 2)
void gemm_head(const float* __restrict__ A, const unsigned short* __restrict__ Bth,
               const unsigned short* __restrict__ Btl, const float* __restrict__ bias,
               float* __restrict__ C, int M, int K,
               const float* __restrict__ ln_g, const float* __restrict__ ln_b) {
    __shared__ unsigned short Ah[64][LDT], Al[64][LDT];
    __shared__ unsigned short Bh[64][LDT], Bl[64][LDT];
    int tid = threadIdx.x;
    int lane = tid & 63, w = tid >> 6;
    int m = lane & 15, q = lane >> 4;
    int rowBase = blockIdx.y * 64;
    f32x4 acc[4];
    #pragma unroll
    for (int ct = 0; ct < 4; ct++) acc[ct] = (f32x4){0.f, 0.f, 0.f, 0.f};

    for (int kk = 0; kk < K; kk += 32) {
        #pragma unroll
        for (int u = 0; u < 2; u++) {
            int f = tid + 256 * u;
            int r = f >> 3;
            int k4 = (f & 7) * 4;
            int row = rowBase + r;
            float4 v = make_float4(0.f, 0.f, 0.f, 0.f);
            if (row < M) v = *(const float4*)(A + (size_t)row * K + kk + k4);
            unsigned short h0 = f2bf(v.x), h1 = f2bf(v.y), h2 = f2bf(v.z), h3 = f2bf(v.w);
            unsigned short l0 = f2bf(v.x - bf2f(h0)), l1 = f2bf(v.y - bf2f(h1));
            unsigned short l2 = f2bf(v.z - bf2f(h2)), l3 = f2bf(v.w - bf2f(h3));
            *(u16x4*)&Ah[r][k4] = (u16x4){h0, h1, h2, h3};
            *(u16x4*)&Al[r][k4] = (u16x4){l0, l1, l2, l3};
        }
        {
            int n = tid >> 2;
            int ch = tid & 3;
            size_t goff = (size_t)n * K + kk + ch * 8;
            *(bf16x8*)&Bh[n][ch * 8] = *(const bf16x8*)(Bth + goff);
            *(bf16x8*)&Bl[n][ch * 8] = *(const bf16x8*)(Btl + goff);
        }
        __syncthreads();
        bf16x8 a_h = *(const bf16x8*)&Ah[w * 16 + m][q * 8];
        bf16x8 a_l = *(const bf16x8*)&Al[w * 16 + m][q * 8];
        #pragma unroll
        for (int ct = 0; ct < 4; ct++) {
            bf16x8 b_h = *(const bf16x8*)&Bh[ct * 16 + m][q * 8];
            bf16x8 b_l = *(const bf16x8*)&Bl[ct * 16 + m][q * 8];
            acc[ct] = __builtin_amdgcn_mfma_f32_16x16x32_bf16(a_h, b_h, acc[ct], 0, 0, 0);
            acc[ct] = __builtin_amdgcn_mfma_f32_16x16x32_bf16(a_l, b_h, acc[ct], 0, 0, 0);
            acc[ct] = __builtin_amdgcn_mfma_f32_16x16x32_bf16(a_h, b_l, acc[ct], 0, 0, 0);
        }
        __syncthreads();
    }
    // LN epilogue: row held by 16 lanes (m) x 4 cols (ct)
    #pragma unroll
    for (int r = 0; r < 4; r++) {
        float v[4];
        float sum = 0.f;
        #pragma unroll
        for (int ct = 0; ct < 4; ct++) {
            v[ct] = acc[ct][r] + bias[ct * 16 + m];
            sum += v[ct];
        }
        sum += __shfl_xor(sum, 1); sum += __shfl_xor(sum, 2);
        sum += __shfl_xor(sum, 4); sum += __shfl_xor(sum, 8);
        float mu = sum * (1.f / 64.f);
        float sq = 0.f;
        #pragma unroll
        for (int ct = 0; ct < 4; ct++) {
            float d = v[ct] - mu;
            sq += d * d;
        }
        sq += __shfl_xor(sq, 1); sq += __shfl_xor(sq, 2);
        sq += __shfl_xor(sq, 4); sq += __shfl_xor(sq, 8);
        float inv = rsqrtf(sq * (1.f / 64.f) + LN_EPS);
        int row = rowBase + w * 16 + q * 4 + r;
        if (row < M) {
            #pragma unroll
            for (int ct = 0; ct < 4; ct++) {
                int col = ct * 16 + m;
                C[(size_t)row * 64 + col] = (v[ct] - mu) * inv * ln_g[col] + ln_b[col];
            }
        }
    }
}

// ---------------------------------------------------------------------------
// score_kernel (persistent): per 64-slot group, ee = ea @ We via SINGLE f16
// MFMA (16 MFMA/group vs 48 in the bf16 3-term path — consumers already
// carry fp16-level error from xlr), fused GATv2 score epilogue.
// LDS 26 KB -> ~6 blocks/CU (75% static occupancy) for gather latency hiding.
// Lane m owns channels [m*16 .. m*16+15].
// ---------------------------------------------------------------------------
__global__ __launch_bounds__(256, 2)
void score_kernel(const f16* __restrict__ efp,
                  const int* __restrict__ srcf, const int* __restrict__ dstf,
                  const f16* __restrict__ xlr,
                  const f16* __restrict__ wet,
                  const float* __restrict__ att, float* __restrict__ alpha) {
    __shared__ _Float16 Af[64][LDT];
    __shared__ _Float16 Bf[256][LDT];
    __shared__ int s_src[64], s_dst[64];
    int tid = threadIdx.x;
    int lane = tid & 63, w = tid >> 6;
    int m = lane & 15, q = lane >> 4;

    // stage B (We^T permuted f16, [256][32]) ONCE
    #pragma unroll
    for (int u = 0; u < 4; u++) {
        *(f16x8*)&Bf[tid][u * 8] = *(const f16x8*)(wet + (size_t)tid * EDIM + u * 8);
    }
    // attv[ct] = att coefficient of channel m*16+ct
    float attv[16];
    #pragma unroll
    for (int u = 0; u < 4; u++) {
        float4 a4 = *(const float4*)(att + m * 16 + u * 4);
        attv[u * 4 + 0] = a4.x; attv[u * 4 + 1] = a4.y;
        attv[u * 4 + 2] = a4.z; attv[u * 4 + 3] = a4.w;
    }

    int groups = (EESLOTS + 63) >> 6;
    for (int g = blockIdx.x; g < groups; g += gridDim.x) {
        int base = g << 6;
        __syncthreads();   // protect Af + s_src reads of previous group
        // stage A: 64 slots x 32 k, sequential f16 stream from efp
        {
            int r = tid >> 2, ch = tid & 3;
            int j = base + r;
            if (j >= EESLOTS) j = EESLOTS - 1;
            *(f16x8*)&Af[r][ch * 8] = *(const f16x8*)(efp + (size_t)j * EDIM + ch * 8);
            if (ch == 0) { s_src[r] = srcf[j]; s_dst[r] = dstf[j]; }
        }
        __syncthreads();

        f16x8 a = *(const f16x8*)&Af[w * 16 + m][q * 8];
        f32x4 acc[16];
        #pragma unroll
        for (int ct = 0; ct < 16; ct++) {
            f16x8 b = *(const f16x8*)&Bf[ct * 16 + m][q * 8];
            acc[ct] = __builtin_amdgcn_mfma_f32_16x16x32_f16(
                a, b, (f32x4){0.f, 0.f, 0.f, 0.f}, 0, 0, 0);
        }

        // epilogue: per-slot score (fp16 gathers, 32 B per side per lane)
        #pragma unroll
        for (int r = 0; r < 4; r++) {
            int sl = w * 16 + q * 4 + r;
            int slot = base + sl;
            int ss = s_src[sl], dd = s_dst[sl];
            const f16* xlp = xlr + (size_t)ss * XLR + m * 16;         // xl part
            const f16* xrp = xlr + (size_t)dd * XLR + HC + m * 16;    // xr part
            f16x8 xa0 = *(const f16x8*)(xlp);
            f16x8 xa1 = *(const f16x8*)(xlp + 8);
            f16x8 xb0 = *(const f16x8*)(xrp);
            f16x8 xb1 = *(const f16x8*)(xrp + 8);
            float s = 0.f;
            #pragma unroll
            for (int i = 0; i < 8; i++) {
                float z0 = (float)xa0[i] + (float)xb0[i] + acc[i][r];
                float lz0 = fmaxf(z0, 0.f) + 0.2f * fminf(z0, 0.f);
                s += lz0 * attv[i];
                float z1 = (float)xa1[i] + (float)xb1[i] + acc[8 + i][r];
                float lz1 = fmaxf(z1, 0.f) + 0.2f * fminf(z1, 0.f);
                s += lz1 * attv[8 + i];
            }
            // head h = m>>2: reduce over the 4 lanes m in [4h..4h+3]
            s += __shfl_xor(s, 1);
            s += __shfl_xor(s, 2);
            if ((m & 3) == 0 && slot < EESLOTS) {
                alpha[(size_t)slot * 4 + (m >> 2)] = s;
            }
        }
    }
}

// ---------------------------------------------------------------------------
// Lean aggregation: softmax over precomputed alpha (shift = alpha_self),
// weighted gather of fp16 xl (cols 0..255 of xlr). One wave per node, ILP x4.
// fp32 accumulation; fp32 output xb.
// ---------------------------------------------------------------------------
__global__ __launch_bounds__(256)
void gat_aggr(const f16* __restrict__ xlr, const float* __restrict__ alpha,
              const int* __restrict__ row_ptr, const int* __restrict__ csr_src,
              const float* __restrict__ bias, float* __restrict__ out, int do_relu) {
    int lane = threadIdx.x & 63;
    int wv = threadIdx.x >> 6;
    int n = blockIdx.x * 4 + wv;
    if (n >= NN) return;
    int h = lane >> 4;
    float4 bb = *(const float4*)(bias + 4 * lane);
    int s0 = row_ptr[n], e0 = row_ptr[n + 1];
    float aself = alpha[(size_t)(NE + n) * 4 + h];
    float denom = 1.f;
    f16x4 xs = *(const f16x4*)(xlr + (size_t)n * XLR + 4 * lane);
    float4 acc = make_float4((float)xs[0], (float)xs[1], (float)xs[2], (float)xs[3]);

    for (int j0 = s0; j0 < e0; j0 += 64) {
        int cnt = min(64, e0 - j0);
        int sidx = (j0 + lane < e0) ? csr_src[j0 + lane] : 0;
        int t = 0;
        for (; t + 3 < cnt; t += 4) {
            int sa = __shfl(sidx, t);
            int sb = __shfl(sidx, t + 1);
            int sc = __shfl(sidx, t + 2);
            int sd = __shfl(sidx, t + 3);
            float a0 = __expf(alpha[(size_t)(j0 + t) * 4 + h] - aself);
            float a1 = __expf(alpha[(size_t)(j0 + t + 1) * 4 + h] - aself);
            float a2 = __expf(alpha[(size_t)(j0 + t + 2) * 4 + h] - aself);
            float a3 = __expf(alpha[(size_t)(j0 + t + 3) * 4 + h] - aself);
            f16x4 x0 = *(const f16x4*)(xlr + (size_t)sa * XLR + 4 * lane);
            f16x4 x1 = *(const f16x4*)(xlr + (size_t)sb * XLR + 4 * lane);
            f16x4 x2 = *(const f16x4*)(xlr + (size_t)sc * XLR + 4 * lane);
            f16x4 x3 = *(const f16x4*)(xlr + (size_t)sd * XLR + 4 * lane);
            denom += a0 + a1 + a2 + a3;
            acc.x += a0 * (float)x0[0] + a1 * (float)x1[0] + a2 * (float)x2[0] + a3 * (float)x3[0];
            acc.y += a0 * (float)x0[1] + a1 * (float)x1[1] + a2 * (float)x2[1] + a3 * (float)x3[1];
            acc.z += a0 * (float)x0[2] + a1 * (float)x1[2] + a2 * (float)x2[2] + a3 * (float)x3[2];
            acc.w += a0 * (float)x0[3] + a1 * (float)x1[3] + a2 * (float)x2[3] + a3 * (float)x3[3];
        }
        for (; t < cnt; t++) {
            int sa = __shfl(sidx, t);
            float a0 = __expf(alpha[(size_t)(j0 + t) * 4 + h] - aself);
            f16x4 x0 = *(const f16x4*)(xlr + (size_t)sa * XLR + 4 * lane);
            denom += a0;
            acc.x += a0 * (float)x0[0]; acc.y += a0 * (float)x0[1];
            acc.z += a0 * (float)x0[2]; acc.w += a0 * (float)x0[3];
        }
    }

    float inv = 1.f / denom;
    float4 r = make_float4(acc.x * inv + bb.x, acc.y * inv + bb.y,
                           acc.z * inv + bb.z, acc.w * inv + bb.w);
    if (do_relu) {
        r.x = fmaxf(r.x, 0.f); r.y = fmaxf(r.y, 0.f);
        r.z = fmaxf(r.z, 0.f); r.w = fmaxf(r.w, 0.f);
    }
    *(float4*)(out + (size_t)n * HC + 4 * lane) = r;
}

// ---------------------------------------------------------------------------
// Graph mean pre-reduction exploiting sorted batch
// ---------------------------------------------------------------------------
__global__ void graph_sum(const float* __restrict__ x, const int* __restrict__ batch,
                          float* __restrict__ gsum, float* __restrict__ gcnt) {
    int c = threadIdx.x;
    int r0 = blockIdx.x * 256;
    int r1 = min(r0 + 256, NN);
    float acc = 0.f;
    int gcur = batch[r0];
    for (int n = r0; n < r1; n++) {
        int g = batch[n];
        if (g != gcur) {
            atomicAdd(&gsum[(size_t)gcur * HC + c], acc);
            acc = 0.f; gcur = g;
        }
        acc += x[(size_t)n * HC + c];
    }
    atomicAdd(&gsum[(size_t)gcur * HC + c], acc);
    if (c == 0) {
        int cnt = 0; gcur = batch[r0];
        for (int n = r0; n < r1; n++) {
            int g = batch[n];
            if (g != gcur) {
                atomicAdd(&gcnt[gcur], (float)cnt);
                cnt = 0; gcur = g;
            }
            cnt++;
        }
        atomicAdd(&gcnt[gcur], (float)cnt);
    }
}

__global__ void glob_kernel(const float* __restrict__ gsum, const float* __restrict__ gcnt,
                            const float* __restrict__ W, const float* __restrict__ bias,
                            const float* __restrict__ g, const float* __restrict__ b,
                            float* __restrict__ out) {
    int gi = blockIdx.x;
    int lane = threadIdx.x;
    float inv = 1.f / fmaxf(gcnt[gi], 1.f);
    float acc = 0.f;
    for (int k = 0; k < HC; k++)
        acc += (gsum[(size_t)gi * HC + k] * inv) * W[(size_t)k * ND + lane];
    acc += bias[lane];
    float s = acc;
    #pragma unroll
    for (int o = 32; o >= 1; o >>= 1) s += __shfl_xor(s, o);
    float mu = s * (1.f / 64.f);
    float dv = acc - mu;
    float q = dv * dv;
    #pragma unroll
    for (int o = 32; o >= 1; o >>= 1) q += __shfl_xor(q, o);
    float var = q * (1.f / 64.f);
    out[(size_t)gi * ND + lane] = dv * rsqrtf(var + LN_EPS) * g[lane] + b[lane];
}

// ---------------------------------------------------------------------------
extern "C" void kernel_launch(void* const* d_in, const int* in_sizes, int n_in,
                              void* d_out, int out_size, void* d_ws, size_t ws_size,
                              hipStream_t stream) {
    (void)in_sizes; (void)n_in; (void)out_size; (void)ws_size;
    const float* node_feature = (const float*)d_in[0];
    const int*   edge_index   = (const int*)d_in[1];
    const float* edge_feature = (const float*)d_in[2];
    const int*   batch        = (const int*)d_in[3];
    const float* Wl0   = (const float*)d_in[4];
    const float* bl0   = (const float*)d_in[5];
    const float* Wr0   = (const float*)d_in[6];
    const float* br0   = (const float*)d_in[7];
    const float* We0   = (const float*)d_in[8];
    const float* att0  = (const float*)d_in[9];
    const float* bias0 = (const float*)d_in[10];
    const float* Wl1   = (const float*)d_in[11];
    const float* bl1   = (const float*)d_in[12];
    const float* Wr1   = (const float*)d_in[13];
    const float* br1   = (const float*)d_in[14];
    const float* We1   = (const float*)d_in[15];
    const float* att1  = (const float*)d_in[16];
    const float* bias1 = (const float*)d_in[17];
    const float* node_W  = (const float*)d_in[18];
    const float* node_b  = (const float*)d_in[19];
    const float* graph_W = (const float*)d_in[20];
    const float* graph_b = (const float*)d_in[21];
    const float* nn_g = (const float*)d_in[22];
    const float* nn_b = (const float*)d_in[23];
    const float* gn_g = (const float*)d_in[24];
    const float* gn_b = (const float*)d_in[25];

    const int* src = edge_index;
    const int* dst = edge_index + NE;

    char* p = (char*)d_ws;
    auto carve = [&](size_t bytes) {
        char* r = p;
        p += (bytes + 255) & ~(size_t)255;
        return r;
    };
    int*   row_ptr   = (int*)carve((NN + 1) * sizeof(int));
    int*   cursor    = (int*)carve(NN * sizeof(int));
    int*   deg       = (int*)carve(NN * sizeof(int));
    int*   bsum      = (int*)carve(SCAN_B * sizeof(int));
    int*   boff      = (int*)carve(SCAN_B * sizeof(int));
    int*   csr_src   = (int*)carve((size_t)NE * sizeof(int));
    int*   csr_dst   = (int*)carve((size_t)NE * sizeof(int));
    int*   csr_eid   = (int*)carve((size_t)NE * sizeof(int));
    int*   srcf      = (int*)carve((size_t)EESLOTS * sizeof(int));
    int*   dstf      = (int*)carve((size_t)EESLOTS * sizeof(int));
    f16*   efp       = (f16*)carve((size_t)EESLOTS * EDIM * sizeof(f16));
    f16*   xlr       = (f16*)carve((size_t)NN * XLR * sizeof(f16));   // fp16 xl|xr fused
    float* xb        = (float*)carve((size_t)NN * HC * sizeof(float));
    float* alpha     = (float*)carve((size_t)EESLOTS * NH * sizeof(float));
    float* gsum      = (float*)carve((size_t)(NGG * HC + NGG) * sizeof(float));
    float* gcnt      = gsum + (size_t)NGG * HC;
    // concat bf16 transposed weights [512][K] hi/lo (accurate GEMM path)
    unsigned short* wlr0h = (unsigned short*)carve((size_t)XLR * DIN * 2 * 2);
    unsigned short* wlr0l = wlr0h + (size_t)XLR * DIN;
    unsigned short* wlr1h = (unsigned short*)carve((size_t)XLR * HC * 2 * 2);
    unsigned short* wlr1l = wlr1h + (size_t)XLR * HC;
    unsigned short* nwh   = (unsigned short*)carve((size_t)HC * ND * 2 * 2);
    unsigned short* nwl   = nwh + (size_t)HC * ND;
    f16* wet0 = (f16*)carve((size_t)EDIM * HC * sizeof(f16));
    f16* wet1 = (f16*)carve((size_t)EDIM * HC * sizeof(f16));
    float* b0cat = (float*)carve(XLR * sizeof(float));
    float* b1cat = (float*)carve(XLR * sizeof(float));

    hipMemsetAsync(deg, 0, NN * sizeof(int), stream);
    hipMemsetAsync(gsum, 0, (NGG * HC + NGG) * sizeof(float), stream);

    // CSR (3-kernel scan) + efp pre-permutation + weight conversion
    count_deg<<<(NE + 255) / 256, 256, 0, stream>>>(dst, deg);
    scan_bsum<<<SCAN_NB, SCAN_B, 0, stream>>>(deg, bsum);
    scan_boff<<<1, SCAN_B, 0, stream>>>(bsum, boff);
    scan_final<<<SCAN_NB, SCAN_B, 0, stream>>>(deg, boff, row_ptr, cursor);
    fill_csr<<<(NE + 255) / 256, 256, 0, stream>>>(src, dst, cursor, csr_src, csr_dst, csr_eid);
    perm_ef<<<(NE * 4 + 255) / 256, 256, 0, stream>>>(edge_feature, csr_eid, csr_src, csr_dst,
                                                      efp, srcf, dstf);
    self_slots<<<(NN * EDIM + 255) / 256, 256, 0, stream>>>(row_ptr, efp, srcf, dstf);
    conv_wt<<<(DIN * HC + 255) / 256, 256, 0, stream>>>(Wl0, wlr0h, wlr0l, DIN, HC);
    conv_wt<<<(DIN * HC + 255) / 256, 256, 0, stream>>>(Wr0, wlr0h + (size_t)HC * DIN, wlr0l + (size_t)HC * DIN, DIN, HC);
    conv_wt<<<(HC * HC + 255) / 256, 256, 0, stream>>>(Wl1, wlr1h, wlr1l, HC, HC);
    conv_wt<<<(HC * HC + 255) / 256, 256, 0, stream>>>(Wr1, wlr1h + (size_t)HC * HC, wlr1l + (size_t)HC * HC, HC, HC);
    conv_wt<<<(HC * ND + 255) / 256, 256, 0, stream>>>(node_W, nwh, nwl, HC, ND);
    conv_wet<<<(EDIM * HC + 255) / 256, 256, 0, stream>>>(We0, wet0);
    conv_wet<<<(EDIM * HC + 255) / 256, 256, 0, stream>>>(We1, wet1);
    concat_bias<<<1, 256, 0, stream>>>(bl0, br0, b0cat);
    concat_bias<<<1, 256, 0, stream>>>(bl1, br1, b1cat);

    dim3 gw(4, (NN + 63) / 64);
    // Layer 0
    gemm_wide<<<gw, 256, 0, stream>>>(node_feature, wlr0h, wlr0l, b0cat, xlr, NN, DIN);
    score_kernel<<<2048, 256, 0, stream>>>(efp, srcf, dstf, xlr, wet0, att0, alpha);
    gat_aggr<<<(NN + 3) / 4, 256, 0, stream>>>(xlr, alpha, row_ptr, csr_src, bias0, xb, 1);
    // Layer 1
    gemm_wide<<<gw, 256, 0, stream>>>(xb, wlr1h, wlr1l, b1cat, xlr, NN, HC);
    score_kernel<<<2048, 256, 0, stream>>>(efp, srcf, dstf, xlr, wet1, att1, alpha);
    gat_aggr<<<(NN + 3) / 4, 256, 0, stream>>>(xlr, alpha, row_ptr, csr_src, bias1, xb, 0);

    // Heads
    float* out_local = (float*)d_out;
    float* out_glob  = out_local + (size_t)NN * ND;
    dim3 gh(1, (NN + 63) / 64);
    gemm_head<<<gh, 256, 0, stream>>>(xb, nwh, nwl, node_b, out_local, NN, HC, nn_g, nn_b);
    graph_sum<<<(NN + 255) / 256, 256, 0, stream>>>(xb, batch, gsum, gcnt);
    glob_kernel<<<NGG, 64, 0, stream>>>(gsum, gcnt, graph_W, graph_b, gn_g, gn_b, out_glob);
}

// Round 9
// 605.327 us; speedup vs baseline: 1.8243x; 1.1674x over previous
//
#include <hip/hip_runtime.h>
#include <cstdint>
#include <cstddef>

#define NN   50000
#define NE   500000
#define DIN  64
#define EDIM 32
#define NH   4
#define NC   64
#define HC   256   // NH*NC
#define NGG  64
#define ND   64
#define LN_EPS 1e-5f
#define EESLOTS (NE + NN)   // edges + self-loops, CSR-slot order
#define XLR  512            // row stride of fused xl|xr buffer (fp16)
#define SCAN_B   256
#define SCAN_NB  ((NN + SCAN_B - 1) / SCAN_B)   // 196

typedef __attribute__((ext_vector_type(8))) short bf16x8;
typedef __attribute__((ext_vector_type(4))) float f32x4;
typedef __attribute__((ext_vector_type(4))) unsigned short u16x4;
typedef _Float16 f16;
typedef __attribute__((ext_vector_type(4))) _Float16 f16x4;
typedef __attribute__((ext_vector_type(8))) _Float16 f16x8;

__device__ __forceinline__ unsigned short f2bf(float x) {
    unsigned u = __float_as_uint(x);
    unsigned r = (u + 0x7FFFu + ((u >> 16) & 1u)) >> 16;
    return (unsigned short)r;
}
__device__ __forceinline__ float bf2f(unsigned short h) {
    return __uint_as_float(((unsigned)h) << 16);
}

// ---------------------------------------------------------------------------
// CSR build: degree count -> 3-kernel device-wide scan -> fill
// ---------------------------------------------------------------------------
__global__ void count_deg(const int* __restrict__ dst, int* __restrict__ deg) {
    int e = blockIdx.x * blockDim.x + threadIdx.x;
    if (e < NE) atomicAdd(&deg[dst[e]], 1);
}

__global__ void scan_bsum(const int* __restrict__ deg, int* __restrict__ bsum) {
    __shared__ int s[SCAN_B];
    int t = threadIdx.x;
    int i = blockIdx.x * SCAN_B + t;
    s[t] = (i < NN) ? deg[i] : 0;
    __syncthreads();
    #pragma unroll
    for (int off = SCAN_B / 2; off > 0; off >>= 1) {
        if (t < off) s[t] += s[t + off];
        __syncthreads();
    }
    if (t == 0) bsum[blockIdx.x] = s[0];
}

__global__ void scan_boff(const int* __restrict__ bsum, int* __restrict__ boff) {
    __shared__ int s[SCAN_B];
    int t = threadIdx.x;
    int v = (t < SCAN_NB) ? bsum[t] : 0;
    s[t] = v;
    __syncthreads();
    #pragma unroll
    for (int off = 1; off < SCAN_B; off <<= 1) {
        int u = (t >= off) ? s[t - off] : 0;
        __syncthreads();
        s[t] += u;
        __syncthreads();
    }
    boff[t] = s[t] - v;   // exclusive
}

__global__ void scan_final(const int* __restrict__ deg, const int* __restrict__ boff,
                           int* __restrict__ row_ptr, int* __restrict__ cursor) {
    __shared__ int s[SCAN_B];
    int t = threadIdx.x;
    int i = blockIdx.x * SCAN_B + t;
    int v = (i < NN) ? deg[i] : 0;
    s[t] = v;
    __syncthreads();
    #pragma unroll
    for (int off = 1; off < SCAN_B; off <<= 1) {
        int u = (t >= off) ? s[t - off] : 0;
        __syncthreads();
        s[t] += u;
        __syncthreads();
    }
    int excl = boff[blockIdx.x] + s[t] - v;
    if (i < NN) {
        row_ptr[i] = excl;
        cursor[i] = excl;
    }
    if (i == 0) row_ptr[NN] = NE;
}

__global__ void fill_csr(const int* __restrict__ src, const int* __restrict__ dst,
                         int* __restrict__ cursor, int* __restrict__ csr_src,
                         int* __restrict__ csr_dst, int* __restrict__ csr_eid) {
    int e = blockIdx.x * blockDim.x + threadIdx.x;
    if (e < NE) {
        int d = dst[e];
        int pos = atomicAdd(&cursor[d], 1);
        csr_src[pos] = src[e];
        csr_dst[pos] = d;
        csr_eid[pos] = e;
    }
}

// ---------------------------------------------------------------------------
// perm_ef: materialize ef in CSR-slot order as f16, build src/dst arrays.
// ---------------------------------------------------------------------------
__global__ void perm_ef(const float* __restrict__ ef, const int* __restrict__ csr_eid,
                        const int* __restrict__ csr_src, const int* __restrict__ csr_dst,
                        f16* __restrict__ efp,
                        int* __restrict__ srcf, int* __restrict__ dstf) {
    int idx = blockIdx.x * blockDim.x + threadIdx.x;
    if (idx >= NE * 4) return;
    int j = idx >> 2, ch = idx & 3;
    int eid = csr_eid[j];
    const float* sp = ef + (size_t)eid * EDIM + ch * 8;
    float4 v0 = *(const float4*)sp;
    float4 v1 = *(const float4*)(sp + 4);
    f16x8 o;
    o[0] = (f16)v0.x; o[1] = (f16)v0.y; o[2] = (f16)v0.z; o[3] = (f16)v0.w;
    o[4] = (f16)v1.x; o[5] = (f16)v1.y; o[6] = (f16)v1.z; o[7] = (f16)v1.w;
    *(f16x8*)(efp + (size_t)j * EDIM + ch * 8) = o;
    if (ch == 0) { srcf[j] = csr_src[j]; dstf[j] = csr_dst[j]; }
}

// ---------------------------------------------------------------------------
// self_slots: per-node mean of incident edge attrs -> self-loop slots of efp.
// ---------------------------------------------------------------------------
__global__ void self_slots(const int* __restrict__ row_ptr,
                           f16* __restrict__ efp,
                           int* __restrict__ srcf, int* __restrict__ dstf) {
    int idx = blockIdx.x * blockDim.x + threadIdx.x;
    if (idx >= NN * EDIM) return;
    int n = idx >> 5, c = idx & 31;
    int s = row_ptr[n], e = row_ptr[n + 1];
    float acc = 0.f;
    for (int j = s; j < e; j++)
        acc += (float)efp[(size_t)j * EDIM + c];
    float m = acc / (float)max(e - s, 1);
    efp[(size_t)(NE + n) * EDIM + c] = (f16)m;
    if (c == 0) { srcf[NE + n] = n; dstf[NE + n] = n; }
}

// ---------------------------------------------------------------------------
// Weight pre-passes
// ---------------------------------------------------------------------------
// W[K][N] fp32 -> transposed bf16 hi/lo [N][K] (accurate path: head GEMM)
__global__ void conv_wt(const float* __restrict__ W, unsigned short* __restrict__ hi,
                        unsigned short* __restrict__ lo, int K, int Nn) {
    int idx = blockIdx.x * blockDim.x + threadIdx.x;
    if (idx >= K * Nn) return;
    int k = idx / Nn, n = idx - k * Nn;
    float x = W[idx];
    unsigned short h = f2bf(x);
    unsigned short l = f2bf(x - bf2f(h));
    hi[(size_t)n * K + k] = h;
    lo[(size_t)n * K + k] = l;
}

// W[K][N] fp32 -> transposed f16 [N][K] (fast path: layer GEMMs; output
// buffer is fp16 anyway so single-f16 MFMA precision suffices)
__global__ void conv_wtf(const float* __restrict__ W, f16* __restrict__ o, int K, int Nn) {
    int idx = blockIdx.x * blockDim.x + threadIdx.x;
    if (idx >= K * Nn) return;
    int k = idx / Nn, n = idx - k * Nn;
    o[(size_t)n * K + k] = (f16)W[idx];
}

// We[EDIM][HC] fp32 -> PERMUTED transposed f16 [HC][EDIM].
__global__ void conv_wet(const float* __restrict__ We, f16* __restrict__ wet) {
    int idx = blockIdx.x * blockDim.x + threadIdx.x;
    if (idx >= EDIM * HC) return;
    int k = idx / HC, c = idx - k * HC;
    int r = ((c & 15) << 4) | (c >> 4);   // inverse of c = (r&15)*16 + (r>>4)
    wet[(size_t)r * EDIM + k] = (f16)We[idx];
}

__global__ void concat_bias(const float* __restrict__ a, const float* __restrict__ b,
                            float* __restrict__ o) {
    int i = threadIdx.x;
    o[i] = a[i];
    o[i + HC] = b[i];
}

#define LDT 40

// ---------------------------------------------------------------------------
// Wide fused GEMM (f16 single-term): C[M,512] = A[M,K] @ [Wl|Wr] + [bl|br].
// Tile 64x128, 256 threads, 8 16x16 col-tiles per wave row-group.
// LDS 15.4 KB, 8 MFMA/kk -> high occupancy, low VALU (1 cvt/elem).
// Output: FP16 xlr buffer, row stride XLR=512.
// ---------------------------------------------------------------------------
__global__ __launch_bounds__(256, 2)
void gemm_wide(const float* __restrict__ A, const f16* __restrict__ Bt,
               const float* __restrict__ bias,
               f16* __restrict__ C, int M, int K) {
    __shared__ _Float16 Af[64][LDT];
    __shared__ _Float16 Bf[128][LDT];
    int tid = threadIdx.x;
    int lane = tid & 63, w = tid >> 6;
    int m = lane & 15, q = lane >> 4;
    int rowBase = blockIdx.y * 64, colBase = blockIdx.x * 128;
    f32x4 acc[8];
    #pragma unroll
    for (int ct = 0; ct < 8; ct++) acc[ct] = (f32x4){0.f, 0.f, 0.f, 0.f};

    for (int kk = 0; kk < K; kk += 32) {
        // ---- stage A: 64 rows x 32 k fp32 -> f16 (2 float4 / thread)
        #pragma unroll
        for (int u = 0; u < 2; u++) {
            int f = tid + 256 * u;
            int r = f >> 3;
            int k4 = (f & 7) * 4;
            int row = rowBase + r;
            float4 v = make_float4(0.f, 0.f, 0.f, 0.f);
            if (row < M) v = *(const float4*)(A + (size_t)row * K + kk + k4);
            f16x4 h;
            h[0] = (f16)v.x; h[1] = (f16)v.y; h[2] = (f16)v.z; h[3] = (f16)v.w;
            *(f16x4*)&Af[r][k4] = h;
        }
        // ---- stage B: 128 rows x 32 k f16 (2 f16x8 / thread)
        {
            int n = tid >> 1, hf = (tid & 1) * 16;
            size_t goff = (size_t)(colBase + n) * K + kk + hf;
            *(f16x8*)&Bf[n][hf]     = *(const f16x8*)(Bt + goff);
            *(f16x8*)&Bf[n][hf + 8] = *(const f16x8*)(Bt + goff + 8);
        }
        __syncthreads();
        f16x8 a = *(const f16x8*)&Af[w * 16 + m][q * 8];
        #pragma unroll
        for (int ct = 0; ct < 8; ct++) {
            f16x8 b = *(const f16x8*)&Bf[ct * 16 + m][q * 8];
            acc[ct] = __builtin_amdgcn_mfma_f32_16x16x32_f16(a, b, acc[ct], 0, 0, 0);
        }
        __syncthreads();
    }
    #pragma unroll
    for (int ct = 0; ct < 8; ct++) {
        int col = colBase + ct * 16 + m;
        float bb = bias[col];
        #pragma unroll
        for (int r = 0; r < 4; r++) {
            int row = rowBase + w * 16 + q * 4 + r;
            if (row < M) C[(size_t)row * XLR + col] = (f16)(acc[ct][r] + bb);
        }
    }
}

// ---------------------------------------------------------------------------
// MFMA split-bf16 GEMM (64x64) with fused LayerNorm epilogue (Nn==64).
// Local head only — keeps the accurate 3-term path (final output).
// ---------------------------------------------------------------------------
__global__ __launch_bounds__(256, 2)
void gemm_head(const float* __restrict__ A, const unsigned short* __restrict__ Bth,
               const unsigned short* __restrict__ Btl, const float* __restrict__ bias,
               float* __restrict__ C, int M, int K,
               const float* __restrict__ ln_g, const float* __restrict__ ln_b) {
    __shared__ unsigned short Ah[64][LDT], Al[64][LDT];
    __shared__ unsigned short Bh[64][LDT], Bl[64][LDT];
    int tid = threadIdx.x;
    int lane = tid & 63, w = tid >> 6;
    int m = lane & 15, q = lane >> 4;
    int rowBase = blockIdx.y * 64;
    f32x4 acc[4];
    #pragma unroll
    for (int ct = 0; ct < 4; ct++) acc[ct] = (f32x4){0.f, 0.f, 0.f, 0.f};

    for (int kk = 0; kk < K; kk += 32) {
        #pragma unroll
        for (int u = 0; u < 2; u++) {
            int f = tid + 256 * u;
            int r = f >> 3;
            int k4 = (f & 7) * 4;
            int row = rowBase + r;
            float4 v = make_float4(0.f, 0.f, 0.f, 0.f);
            if (row < M) v = *(const float4*)(A + (size_t)row * K + kk + k4);
            unsigned short h0 = f2bf(v.x), h1 = f2bf(v.y), h2 = f2bf(v.z), h3 = f2bf(v.w);
            unsigned short l0 = f2bf(v.x - bf2f(h0)), l1 = f2bf(v.y - bf2f(h1));
            unsigned short l2 = f2bf(v.z - bf2f(h2)), l3 = f2bf(v.w - bf2f(h3));
            *(u16x4*)&Ah[r][k4] = (u16x4){h0, h1, h2, h3};
            *(u16x4*)&Al[r][k4] = (u16x4){l0, l1, l2, l3};
        }
        {
            int n = tid >> 2;
            int ch = tid & 3;
            size_t goff = (size_t)n * K + kk + ch * 8;
            *(bf16x8*)&Bh[n][ch * 8] = *(const bf16x8*)(Bth + goff);
            *(bf16x8*)&Bl[n][ch * 8] = *(const bf16x8*)(Btl + goff);
        }
        __syncthreads();
        bf16x8 a_h = *(const bf16x8*)&Ah[w * 16 + m][q * 8];
        bf16x8 a_l = *(const bf16x8*)&Al[w * 16 + m][q * 8];
        #pragma unroll
        for (int ct = 0; ct < 4; ct++) {
            bf16x8 b_h = *(const bf16x8*)&Bh[ct * 16 + m][q * 8];
            bf16x8 b_l = *(const bf16x8*)&Bl[ct * 16 + m][q * 8];
            acc[ct] = __builtin_amdgcn_mfma_f32_16x16x32_bf16(a_h, b_h, acc[ct], 0, 0, 0);
            acc[ct] = __builtin_amdgcn_mfma_f32_16x16x32_bf16(a_l, b_h, acc[ct], 0, 0, 0);
            acc[ct] = __builtin_amdgcn_mfma_f32_16x16x32_bf16(a_h, b_l, acc[ct], 0, 0, 0);
        }
        __syncthreads();
    }
    // LN epilogue: row held by 16 lanes (m) x 4 cols (ct)
    #pragma unroll
    for (int r = 0; r < 4; r++) {
        float v[4];
        float sum = 0.f;
        #pragma unroll
        for (int ct = 0; ct < 4; ct++) {
            v[ct] = acc[ct][r] + bias[ct * 16 + m];
            sum += v[ct];
        }
        sum += __shfl_xor(sum, 1); sum += __shfl_xor(sum, 2);
        sum += __shfl_xor(sum, 4); sum += __shfl_xor(sum, 8);
        float mu = sum * (1.f / 64.f);
        float sq = 0.f;
        #pragma unroll
        for (int ct = 0; ct < 4; ct++) {
            float d = v[ct] - mu;
            sq += d * d;
        }
        sq += __shfl_xor(sq, 1); sq += __shfl_xor(sq, 2);
        sq += __shfl_xor(sq, 4); sq += __shfl_xor(sq, 8);
        float inv = rsqrtf(sq * (1.f / 64.f) + LN_EPS);
        int row = rowBase + w * 16 + q * 4 + r;
        if (row < M) {
            #pragma unroll
            for (int ct = 0; ct < 4; ct++) {
                int col = ct * 16 + m;
                C[(size_t)row * 64 + col] = (v[ct] - mu) * inv * ln_g[col] + ln_b[col];
            }
        }
    }
}

// ---------------------------------------------------------------------------
// score_kernel (persistent): per 64-slot group, ee = ea @ We via single f16
// MFMA, fused GATv2 score epilogue. Lane m owns channels [m*16 .. m*16+15].
// ---------------------------------------------------------------------------
__global__ __launch_bounds__(256, 2)
void score_kernel(const f16* __restrict__ efp,
                  const int* __restrict__ srcf, const int* __restrict__ dstf,
                  const f16* __restrict__ xlr,
                  const f16* __restrict__ wet,
                  const float* __restrict__ att, float* __restrict__ alpha) {
    __shared__ _Float16 Af[64][LDT];
    __shared__ _Float16 Bf[256][LDT];
    __shared__ int s_src[64], s_dst[64];
    int tid = threadIdx.x;
    int lane = tid & 63, w = tid >> 6;
    int m = lane & 15, q = lane >> 4;

    // stage B (We^T permuted f16, [256][32]) ONCE
    #pragma unroll
    for (int u = 0; u < 4; u++) {
        *(f16x8*)&Bf[tid][u * 8] = *(const f16x8*)(wet + (size_t)tid * EDIM + u * 8);
    }
    // attv[ct] = att coefficient of channel m*16+ct
    float attv[16];
    #pragma unroll
    for (int u = 0; u < 4; u++) {
        float4 a4 = *(const float4*)(att + m * 16 + u * 4);
        attv[u * 4 + 0] = a4.x; attv[u * 4 + 1] = a4.y;
        attv[u * 4 + 2] = a4.z; attv[u * 4 + 3] = a4.w;
    }

    int groups = (EESLOTS + 63) >> 6;
    for (int g = blockIdx.x; g < groups; g += gridDim.x) {
        int base = g << 6;
        __syncthreads();   // protect Af + s_src reads of previous group
        // stage A: 64 slots x 32 k, sequential f16 stream from efp
        {
            int r = tid >> 2, ch = tid & 3;
            int j = base + r;
            if (j >= EESLOTS) j = EESLOTS - 1;
            *(f16x8*)&Af[r][ch * 8] = *(const f16x8*)(efp + (size_t)j * EDIM + ch * 8);
            if (ch == 0) { s_src[r] = srcf[j]; s_dst[r] = dstf[j]; }
        }
        __syncthreads();

        f16x8 a = *(const f16x8*)&Af[w * 16 + m][q * 8];
        f32x4 acc[16];
        #pragma unroll
        for (int ct = 0; ct < 16; ct++) {
            f16x8 b = *(const f16x8*)&Bf[ct * 16 + m][q * 8];
            acc[ct] = __builtin_amdgcn_mfma_f32_16x16x32_f16(
                a, b, (f32x4){0.f, 0.f, 0.f, 0.f}, 0, 0, 0);
        }

        // epilogue: per-slot score (fp16 gathers, 32 B per side per lane)
        #pragma unroll
        for (int r = 0; r < 4; r++) {
            int sl = w * 16 + q * 4 + r;
            int slot = base + sl;
            int ss = s_src[sl], dd = s_dst[sl];
            const f16* xlp = xlr + (size_t)ss * XLR + m * 16;         // xl part
            const f16* xrp = xlr + (size_t)dd * XLR + HC + m * 16;    // xr part
            f16x8 xa0 = *(const f16x8*)(xlp);
            f16x8 xa1 = *(const f16x8*)(xlp + 8);
            f16x8 xb0 = *(const f16x8*)(xrp);
            f16x8 xb1 = *(const f16x8*)(xrp + 8);
            float s = 0.f;
            #pragma unroll
            for (int i = 0; i < 8; i++) {
                float z0 = (float)xa0[i] + (float)xb0[i] + acc[i][r];
                float lz0 = fmaxf(z0, 0.f) + 0.2f * fminf(z0, 0.f);
                s += lz0 * attv[i];
                float z1 = (float)xa1[i] + (float)xb1[i] + acc[8 + i][r];
                float lz1 = fmaxf(z1, 0.f) + 0.2f * fminf(z1, 0.f);
                s += lz1 * attv[8 + i];
            }
            // head h = m>>2: reduce over the 4 lanes m in [4h..4h+3]
            s += __shfl_xor(s, 1);
            s += __shfl_xor(s, 2);
            if ((m & 3) == 0 && slot < EESLOTS) {
                alpha[(size_t)slot * 4 + (m >> 2)] = s;
            }
        }
    }
}

// ---------------------------------------------------------------------------
// Lean aggregation: softmax over precomputed alpha (shift = alpha_self),
// weighted gather of fp16 xl (cols 0..255 of xlr). One wave per node, ILP x4.
// ---------------------------------------------------------------------------
__global__ __launch_bounds__(256)
void gat_aggr(const f16* __restrict__ xlr, const float* __restrict__ alpha,
              const int* __restrict__ row_ptr, const int* __restrict__ csr_src,
              const float* __restrict__ bias, float* __restrict__ out, int do_relu) {
    int lane = threadIdx.x & 63;
    int wv = threadIdx.x >> 6;
    int n = blockIdx.x * 4 + wv;
    if (n >= NN) return;
    int h = lane >> 4;
    float4 bb = *(const float4*)(bias + 4 * lane);
    int s0 = row_ptr[n], e0 = row_ptr[n + 1];
    float aself = alpha[(size_t)(NE + n) * 4 + h];
    float denom = 1.f;
    f16x4 xs = *(const f16x4*)(xlr + (size_t)n * XLR + 4 * lane);
    float4 acc = make_float4((float)xs[0], (float)xs[1], (float)xs[2], (float)xs[3]);

    for (int j0 = s0; j0 < e0; j0 += 64) {
        int cnt = min(64, e0 - j0);
        int sidx = (j0 + lane < e0) ? csr_src[j0 + lane] : 0;
        int t = 0;
        for (; t + 3 < cnt; t += 4) {
            int sa = __shfl(sidx, t);
            int sb = __shfl(sidx, t + 1);
            int sc = __shfl(sidx, t + 2);
            int sd = __shfl(sidx, t + 3);
            float a0 = __expf(alpha[(size_t)(j0 + t) * 4 + h] - aself);
            float a1 = __expf(alpha[(size_t)(j0 + t + 1) * 4 + h] - aself);
            float a2 = __expf(alpha[(size_t)(j0 + t + 2) * 4 + h] - aself);
            float a3 = __expf(alpha[(size_t)(j0 + t + 3) * 4 + h] - aself);
            f16x4 x0 = *(const f16x4*)(xlr + (size_t)sa * XLR + 4 * lane);
            f16x4 x1 = *(const f16x4*)(xlr + (size_t)sb * XLR + 4 * lane);
            f16x4 x2 = *(const f16x4*)(xlr + (size_t)sc * XLR + 4 * lane);
            f16x4 x3 = *(const f16x4*)(xlr + (size_t)sd * XLR + 4 * lane);
            denom += a0 + a1 + a2 + a3;
            acc.x += a0 * (float)x0[0] + a1 * (float)x1[0] + a2 * (float)x2[0] + a3 * (float)x3[0];
            acc.y += a0 * (float)x0[1] + a1 * (float)x1[1] + a2 * (float)x2[1] + a3 * (float)x3[1];
            acc.z += a0 * (float)x0[2] + a1 * (float)x1[2] + a2 * (float)x2[2] + a3 * (float)x3[2];
            acc.w += a0 * (float)x0[3] + a1 * (float)x1[3] + a2 * (float)x2[3] + a3 * (float)x3[3];
        }
        for (; t < cnt; t++) {
            int sa = __shfl(sidx, t);
            float a0 = __expf(alpha[(size_t)(j0 + t) * 4 + h] - aself);
            f16x4 x0 = *(const f16x4*)(xlr + (size_t)sa * XLR + 4 * lane);
            denom += a0;
            acc.x += a0 * (float)x0[0]; acc.y += a0 * (float)x0[1];
            acc.z += a0 * (float)x0[2]; acc.w += a0 * (float)x0[3];
        }
    }

    float inv = 1.f / denom;
    float4 r = make_float4(acc.x * inv + bb.x, acc.y * inv + bb.y,
                           acc.z * inv + bb.z, acc.w * inv + bb.w);
    if (do_relu) {
        r.x = fmaxf(r.x, 0.f); r.y = fmaxf(r.y, 0.f);
        r.z = fmaxf(r.z, 0.f); r.w = fmaxf(r.w, 0.f);
    }
    *(float4*)(out + (size_t)n * HC + 4 * lane) = r;
}

// ---------------------------------------------------------------------------
// Graph mean pre-reduction exploiting sorted batch.
// 64 rows/block (782 blocks) for parallelism — was 256 rows/196 blocks at
// 7% occupancy / 0.6 TB/s.
// ---------------------------------------------------------------------------
__global__ void graph_sum(const float* __restrict__ x, const int* __restrict__ batch,
                          float* __restrict__ gsum, float* __restrict__ gcnt) {
    int c = threadIdx.x;
    int r0 = blockIdx.x * 64;
    int r1 = min(r0 + 64, NN);
    if (r0 >= NN) return;
    float acc = 0.f;
    int gcur = batch[r0];
    for (int n = r0; n < r1; n++) {
        int g = batch[n];
        if (g != gcur) {
            atomicAdd(&gsum[(size_t)gcur * HC + c], acc);
            acc = 0.f; gcur = g;
        }
        acc += x[(size_t)n * HC + c];
    }
    atomicAdd(&gsum[(size_t)gcur * HC + c], acc);
    if (c == 0) {
        int cnt = 0; gcur = batch[r0];
        for (int n = r0; n < r1; n++) {
            int g = batch[n];
            if (g != gcur) {
                atomicAdd(&gcnt[gcur], (float)cnt);
                cnt = 0; gcur = g;
            }
            cnt++;
        }
        atomicAdd(&gcnt[gcur], (float)cnt);
    }
}

__global__ void glob_kernel(const float* __restrict__ gsum, const float* __restrict__ gcnt,
                            const float* __restrict__ W, const float* __restrict__ bias,
                            const float* __restrict__ g, const float* __restrict__ b,
                            float* __restrict__ out) {
    int gi = blockIdx.x;
    int lane = threadIdx.x;
    float inv = 1.f / fmaxf(gcnt[gi], 1.f);
    float acc = 0.f;
    for (int k = 0; k < HC; k++)
        acc += (gsum[(size_t)gi * HC + k] * inv) * W[(size_t)k * ND + lane];
    acc += bias[lane];
    float s = acc;
    #pragma unroll
    for (int o = 32; o >= 1; o >>= 1) s += __shfl_xor(s, o);
    float mu = s * (1.f / 64.f);
    float dv = acc - mu;
    float q = dv * dv;
    #pragma unroll
    for (int o = 32; o >= 1; o >>= 1) q += __shfl_xor(q, o);
    float var = q * (1.f / 64.f);
    out[(size_t)gi * ND + lane] = dv * rsqrtf(var + LN_EPS) * g[lane] + b[lane];
}

// ---------------------------------------------------------------------------
extern "C" void kernel_launch(void* const* d_in, const int* in_sizes, int n_in,
                              void* d_out, int out_size, void* d_ws, size_t ws_size,
                              hipStream_t stream) {
    (void)in_sizes; (void)n_in; (void)out_size; (void)ws_size;
    const float* node_feature = (const float*)d_in[0];
    const int*   edge_index   = (const int*)d_in[1];
    const float* edge_feature = (const float*)d_in[2];
    const int*   batch        = (const int*)d_in[3];
    const float* Wl0   = (const float*)d_in[4];
    const float* bl0   = (const float*)d_in[5];
    const float* Wr0   = (const float*)d_in[6];
    const float* br0   = (const float*)d_in[7];
    const float* We0   = (const float*)d_in[8];
    const float* att0  = (const float*)d_in[9];
    const float* bias0 = (const float*)d_in[10];
    const float* Wl1   = (const float*)d_in[11];
    const float* bl1   = (const float*)d_in[12];
    const float* Wr1   = (const float*)d_in[13];
    const float* br1   = (const float*)d_in[14];
    const float* We1   = (const float*)d_in[15];
    const float* att1  = (const float*)d_in[16];
    const float* bias1 = (const float*)d_in[17];
    const float* node_W  = (const float*)d_in[18];
    const float* node_b  = (const float*)d_in[19];
    const float* graph_W = (const float*)d_in[20];
    const float* graph_b = (const float*)d_in[21];
    const float* nn_g = (const float*)d_in[22];
    const float* nn_b = (const float*)d_in[23];
    const float* gn_g = (const float*)d_in[24];
    const float* gn_b = (const float*)d_in[25];

    const int* src = edge_index;
    const int* dst = edge_index + NE;

    char* p = (char*)d_ws;
    auto carve = [&](size_t bytes) {
        char* r = p;
        p += (bytes + 255) & ~(size_t)255;
        return r;
    };
    int*   row_ptr   = (int*)carve((NN + 1) * sizeof(int));
    int*   cursor    = (int*)carve(NN * sizeof(int));
    int*   deg       = (int*)carve(NN * sizeof(int));
    int*   bsum      = (int*)carve(SCAN_B * sizeof(int));
    int*   boff      = (int*)carve(SCAN_B * sizeof(int));
    int*   csr_src   = (int*)carve((size_t)NE * sizeof(int));
    int*   csr_dst   = (int*)carve((size_t)NE * sizeof(int));
    int*   csr_eid   = (int*)carve((size_t)NE * sizeof(int));
    int*   srcf      = (int*)carve((size_t)EESLOTS * sizeof(int));
    int*   dstf      = (int*)carve((size_t)EESLOTS * sizeof(int));
    f16*   efp       = (f16*)carve((size_t)EESLOTS * EDIM * sizeof(f16));
    f16*   xlr       = (f16*)carve((size_t)NN * XLR * sizeof(f16));   // fp16 xl|xr fused
    float* xb        = (float*)carve((size_t)NN * HC * sizeof(float));
    float* alpha     = (float*)carve((size_t)EESLOTS * NH * sizeof(float));
    float* gsum      = (float*)carve((size_t)(NGG * HC + NGG) * sizeof(float));
    float* gcnt      = gsum + (size_t)NGG * HC;
    // layer GEMM weights: f16 transposed [512][K]
    f16* wlr0f = (f16*)carve((size_t)XLR * DIN * sizeof(f16));
    f16* wlr1f = (f16*)carve((size_t)XLR * HC * sizeof(f16));
    // head weights: bf16 hi/lo (accurate)
    unsigned short* nwh   = (unsigned short*)carve((size_t)HC * ND * 2 * 2);
    unsigned short* nwl   = nwh + (size_t)HC * ND;
    f16* wet0 = (f16*)carve((size_t)EDIM * HC * sizeof(f16));
    f16* wet1 = (f16*)carve((size_t)EDIM * HC * sizeof(f16));
    float* b0cat = (float*)carve(XLR * sizeof(float));
    float* b1cat = (float*)carve(XLR * sizeof(float));

    hipMemsetAsync(deg, 0, NN * sizeof(int), stream);
    hipMemsetAsync(gsum, 0, (NGG * HC + NGG) * sizeof(float), stream);

    // CSR (3-kernel scan) + efp pre-permutation + weight conversion
    count_deg<<<(NE + 255) / 256, 256, 0, stream>>>(dst, deg);
    scan_bsum<<<SCAN_NB, SCAN_B, 0, stream>>>(deg, bsum);
    scan_boff<<<1, SCAN_B, 0, stream>>>(bsum, boff);
    scan_final<<<SCAN_NB, SCAN_B, 0, stream>>>(deg, boff, row_ptr, cursor);
    fill_csr<<<(NE + 255) / 256, 256, 0, stream>>>(src, dst, cursor, csr_src, csr_dst, csr_eid);
    perm_ef<<<(NE * 4 + 255) / 256, 256, 0, stream>>>(edge_feature, csr_eid, csr_src, csr_dst,
                                                      efp, srcf, dstf);
    self_slots<<<(NN * EDIM + 255) / 256, 256, 0, stream>>>(row_ptr, efp, srcf, dstf);
    conv_wtf<<<(DIN * HC + 255) / 256, 256, 0, stream>>>(Wl0, wlr0f, DIN, HC);
    conv_wtf<<<(DIN * HC + 255) / 256, 256, 0, stream>>>(Wr0, wlr0f + (size_t)HC * DIN, DIN, HC);
    conv_wtf<<<(HC * HC + 255) / 256, 256, 0, stream>>>(Wl1, wlr1f, HC, HC);
    conv_wtf<<<(HC * HC + 255) / 256, 256, 0, stream>>>(Wr1, wlr1f + (size_t)HC * HC, HC, HC);
    conv_wt<<<(HC * ND + 255) / 256, 256, 0, stream>>>(node_W, nwh, nwl, HC, ND);
    conv_wet<<<(EDIM * HC + 255) / 256, 256, 0, stream>>>(We0, wet0);
    conv_wet<<<(EDIM * HC + 255) / 256, 256, 0, stream>>>(We1, wet1);
    concat_bias<<<1, 256, 0, stream>>>(bl0, br0, b0cat);
    concat_bias<<<1, 256, 0, stream>>>(bl1, br1, b1cat);

    dim3 gw(4, (NN + 63) / 64);
    // Layer 0
    gemm_wide<<<gw, 256, 0, stream>>>(node_feature, wlr0f, b0cat, xlr, NN, DIN);
    score_kernel<<<2048, 256, 0, stream>>>(efp, srcf, dstf, xlr, wet0, att0, alpha);
    gat_aggr<<<(NN + 3) / 4, 256, 0, stream>>>(xlr, alpha, row_ptr, csr_src, bias0, xb, 1);
    // Layer 1
    gemm_wide<<<gw, 256, 0, stream>>>(xb, wlr1f, b1cat, xlr, NN, HC);
    score_kernel<<<2048, 256, 0, stream>>>(efp, srcf, dstf, xlr, wet1, att1, alpha);
    gat_aggr<<<(NN + 3) / 4, 256, 0, stream>>>(xlr, alpha, row_ptr, csr_src, bias1, xb, 0);

    // Heads
    float* out_local = (float*)d_out;
    float* out_glob  = out_local + (size_t)NN * ND;
    dim3 gh(1, (NN + 63) / 64);
    gemm_head<<<gh, 256, 0, stream>>>(xb, nwh, nwl, node_b, out_local, NN, HC, nn_g, nn_b);
    graph_sum<<<(NN + 63) / 64, 256, 0, stream>>>(xb, batch, gsum, gcnt);
    glob_kernel<<<NGG, 64, 0, stream>>>(gsum, gcnt, graph_W, graph_b, gn_g, gn_b, out_glob);
}

// Round 10
// 604.246 us; speedup vs baseline: 1.8276x; 1.0018x over previous
//
#include <hip/hip_runtime.h>
#include <cstdint>
#include <cstddef>

#define NN   50000
#define NE   500000
#define DIN  64
#define EDIM 32
#define NH   4
#define NC   64
#define HC   256   // NH*NC
#define NGG  64
#define ND   64
#define LN_EPS 1e-5f
#define EESLOTS (NE + NN)   // edges + self-loops, CSR-slot order
#define SCAN_B   256
#define SCAN_NB  ((NN + SCAN_B - 1) / SCAN_B)   // 196

typedef __attribute__((ext_vector_type(8))) short bf16x8;
typedef __attribute__((ext_vector_type(4))) float f32x4;
typedef __attribute__((ext_vector_type(4))) unsigned short u16x4;
typedef _Float16 f16;
typedef __attribute__((ext_vector_type(2))) _Float16 f16x2;
typedef __attribute__((ext_vector_type(4))) _Float16 f16x4;
typedef __attribute__((ext_vector_type(8))) _Float16 f16x8;

__device__ __forceinline__ unsigned short f2bf(float x) {
    unsigned u = __float_as_uint(x);
    unsigned r = (u + 0x7FFFu + ((u >> 16) & 1u)) >> 16;
    return (unsigned short)r;
}
__device__ __forceinline__ float bf2f(unsigned short h) {
    return __uint_as_float(((unsigned)h) << 16);
}

// ---------------------------------------------------------------------------
// CSR build: degree count -> 3-kernel device-wide scan -> fill
// ---------------------------------------------------------------------------
__global__ void count_deg(const int* __restrict__ dst, int* __restrict__ deg) {
    int e = blockIdx.x * blockDim.x + threadIdx.x;
    if (e < NE) atomicAdd(&deg[dst[e]], 1);
}

__global__ void scan_bsum(const int* __restrict__ deg, int* __restrict__ bsum) {
    __shared__ int s[SCAN_B];
    int t = threadIdx.x;
    int i = blockIdx.x * SCAN_B + t;
    s[t] = (i < NN) ? deg[i] : 0;
    __syncthreads();
    #pragma unroll
    for (int off = SCAN_B / 2; off > 0; off >>= 1) {
        if (t < off) s[t] += s[t + off];
        __syncthreads();
    }
    if (t == 0) bsum[blockIdx.x] = s[0];
}

__global__ void scan_boff(const int* __restrict__ bsum, int* __restrict__ boff) {
    __shared__ int s[SCAN_B];
    int t = threadIdx.x;
    int v = (t < SCAN_NB) ? bsum[t] : 0;
    s[t] = v;
    __syncthreads();
    #pragma unroll
    for (int off = 1; off < SCAN_B; off <<= 1) {
        int u = (t >= off) ? s[t - off] : 0;
        __syncthreads();
        s[t] += u;
        __syncthreads();
    }
    boff[t] = s[t] - v;   // exclusive
}

__global__ void scan_final(const int* __restrict__ deg, const int* __restrict__ boff,
                           int* __restrict__ row_ptr, int* __restrict__ cursor) {
    __shared__ int s[SCAN_B];
    int t = threadIdx.x;
    int i = blockIdx.x * SCAN_B + t;
    int v = (i < NN) ? deg[i] : 0;
    s[t] = v;
    __syncthreads();
    #pragma unroll
    for (int off = 1; off < SCAN_B; off <<= 1) {
        int u = (t >= off) ? s[t - off] : 0;
        __syncthreads();
        s[t] += u;
        __syncthreads();
    }
    int excl = boff[blockIdx.x] + s[t] - v;
    if (i < NN) {
        row_ptr[i] = excl;
        cursor[i] = excl;
    }
    if (i == 0) row_ptr[NN] = NE;
}

__global__ void fill_csr(const int* __restrict__ src, const int* __restrict__ dst,
                         int* __restrict__ cursor, int* __restrict__ csr_src,
                         int* __restrict__ csr_dst, int* __restrict__ csr_eid) {
    int e = blockIdx.x * blockDim.x + threadIdx.x;
    if (e < NE) {
        int d = dst[e];
        int pos = atomicAdd(&cursor[d], 1);
        csr_src[pos] = src[e];
        csr_dst[pos] = d;
        csr_eid[pos] = e;
    }
}

// ---------------------------------------------------------------------------
// perm_ef: materialize ef in CSR-slot order as f16, build src/dst arrays.
// ---------------------------------------------------------------------------
__global__ void perm_ef(const float* __restrict__ ef, const int* __restrict__ csr_eid,
                        const int* __restrict__ csr_src, const int* __restrict__ csr_dst,
                        f16* __restrict__ efp,
                        int* __restrict__ srcf, int* __restrict__ dstf) {
    int idx = blockIdx.x * blockDim.x + threadIdx.x;
    if (idx >= NE * 4) return;
    int j = idx >> 2, ch = idx & 3;
    int eid = csr_eid[j];
    const float* sp = ef + (size_t)eid * EDIM + ch * 8;
    float4 v0 = *(const float4*)sp;
    float4 v1 = *(const float4*)(sp + 4);
    f16x8 o;
    o[0] = (f16)v0.x; o[1] = (f16)v0.y; o[2] = (f16)v0.z; o[3] = (f16)v0.w;
    o[4] = (f16)v1.x; o[5] = (f16)v1.y; o[6] = (f16)v1.z; o[7] = (f16)v1.w;
    *(f16x8*)(efp + (size_t)j * EDIM + ch * 8) = o;
    if (ch == 0) { srcf[j] = csr_src[j]; dstf[j] = csr_dst[j]; }
}

// ---------------------------------------------------------------------------
// self_slots: per-node mean of incident edge attrs -> self-loop slots of efp.
// ---------------------------------------------------------------------------
__global__ void self_slots(const int* __restrict__ row_ptr,
                           f16* __restrict__ efp,
                           int* __restrict__ srcf, int* __restrict__ dstf) {
    int idx = blockIdx.x * blockDim.x + threadIdx.x;
    if (idx >= NN * EDIM) return;
    int n = idx >> 5, c = idx & 31;
    int s = row_ptr[n], e = row_ptr[n + 1];
    float acc = 0.f;
    for (int j = s; j < e; j++)
        acc += (float)efp[(size_t)j * EDIM + c];
    float m = acc / (float)max(e - s, 1);
    efp[(size_t)(NE + n) * EDIM + c] = (f16)m;
    if (c == 0) { srcf[NE + n] = n; dstf[NE + n] = n; }
}

// ---------------------------------------------------------------------------
// Weight pre-passes
// ---------------------------------------------------------------------------
// W[K][N] fp32 -> transposed bf16 hi/lo [N][K] (accurate path: head GEMM)
__global__ void conv_wt(const float* __restrict__ W, unsigned short* __restrict__ hi,
                        unsigned short* __restrict__ lo, int K, int Nn) {
    int idx = blockIdx.x * blockDim.x + threadIdx.x;
    if (idx >= K * Nn) return;
    int k = idx / Nn, n = idx - k * Nn;
    float x = W[idx];
    unsigned short h = f2bf(x);
    unsigned short l = f2bf(x - bf2f(h));
    hi[(size_t)n * K + k] = h;
    lo[(size_t)n * K + k] = l;
}

// W[K][N] fp32 -> transposed f16 [N][K] (fast path: layer GEMMs)
__global__ void conv_wtf(const float* __restrict__ W, f16* __restrict__ o, int K, int Nn) {
    int idx = blockIdx.x * blockDim.x + threadIdx.x;
    if (idx >= K * Nn) return;
    int k = idx / Nn, n = idx - k * Nn;
    o[(size_t)n * K + k] = (f16)W[idx];
}

// We[EDIM][HC] fp32 -> PERMUTED transposed f16 [HC][EDIM].
__global__ void conv_wet(const float* __restrict__ We, f16* __restrict__ wet) {
    int idx = blockIdx.x * blockDim.x + threadIdx.x;
    if (idx >= EDIM * HC) return;
    int k = idx / HC, c = idx - k * HC;
    int r = ((c & 15) << 4) | (c >> 4);   // inverse of c = (r&15)*16 + (r>>4)
    wet[(size_t)r * EDIM + k] = (f16)We[idx];
}

__global__ void concat_bias(const float* __restrict__ a, const float* __restrict__ b,
                            float* __restrict__ o) {
    int i = threadIdx.x;
    o[i] = a[i];
    o[i + HC] = b[i];
}

#define LDT 40

// ---------------------------------------------------------------------------
// Wide fused GEMM (f16 single-term): [xl|xr] = A[M,K] @ [Wl|Wr] + [bl|br].
// Tile 64x128; outputs SPLIT fp16 buffers xlb[NN][HC], xrb[NN][HC] so the
// aggregation gather (xl only, 25.6 MB) is ~L2-resident instead of thrashing
// through a 51 MB interleaved buffer.
// ---------------------------------------------------------------------------
__global__ __launch_bounds__(256, 2)
void gemm_wide(const float* __restrict__ A, const f16* __restrict__ Bt,
               const float* __restrict__ bias,
               f16* __restrict__ xlb, f16* __restrict__ xrb, int M, int K) {
    __shared__ _Float16 Af[64][LDT];
    __shared__ _Float16 Bf[128][LDT];
    int tid = threadIdx.x;
    int lane = tid & 63, w = tid >> 6;
    int m = lane & 15, q = lane >> 4;
    int rowBase = blockIdx.y * 64, colBase = blockIdx.x * 128;
    f32x4 acc[8];
    #pragma unroll
    for (int ct = 0; ct < 8; ct++) acc[ct] = (f32x4){0.f, 0.f, 0.f, 0.f};

    for (int kk = 0; kk < K; kk += 32) {
        // ---- stage A: 64 rows x 32 k fp32 -> f16 (2 float4 / thread)
        #pragma unroll
        for (int u = 0; u < 2; u++) {
            int f = tid + 256 * u;
            int r = f >> 3;
            int k4 = (f & 7) * 4;
            int row = rowBase + r;
            float4 v = make_float4(0.f, 0.f, 0.f, 0.f);
            if (row < M) v = *(const float4*)(A + (size_t)row * K + kk + k4);
            f16x4 h;
            h[0] = (f16)v.x; h[1] = (f16)v.y; h[2] = (f16)v.z; h[3] = (f16)v.w;
            *(f16x4*)&Af[r][k4] = h;
        }
        // ---- stage B: 128 rows x 32 k f16 (2 f16x8 / thread)
        {
            int n = tid >> 1, hf = (tid & 1) * 16;
            size_t goff = (size_t)(colBase + n) * K + kk + hf;
            *(f16x8*)&Bf[n][hf]     = *(const f16x8*)(Bt + goff);
            *(f16x8*)&Bf[n][hf + 8] = *(const f16x8*)(Bt + goff + 8);
        }
        __syncthreads();
        f16x8 a = *(const f16x8*)&Af[w * 16 + m][q * 8];
        #pragma unroll
        for (int ct = 0; ct < 8; ct++) {
            f16x8 b = *(const f16x8*)&Bf[ct * 16 + m][q * 8];
            acc[ct] = __builtin_amdgcn_mfma_f32_16x16x32_f16(a, b, acc[ct], 0, 0, 0);
        }
        __syncthreads();
    }
    f16* ob = (colBase < HC) ? xlb : xrb;
    int obase = (colBase < HC) ? colBase : colBase - HC;
    #pragma unroll
    for (int ct = 0; ct < 8; ct++) {
        int col = colBase + ct * 16 + m;
        int ocol = obase + ct * 16 + m;
        float bb = bias[col];
        #pragma unroll
        for (int r = 0; r < 4; r++) {
            int row = rowBase + w * 16 + q * 4 + r;
            if (row < M) ob[(size_t)row * HC + ocol] = (f16)(acc[ct][r] + bb);
        }
    }
}

// ---------------------------------------------------------------------------
// MFMA split-bf16 GEMM (64x64) with fused LayerNorm epilogue (Nn==64).
// Local head only — accurate 3-term path (final output).
// ---------------------------------------------------------------------------
__global__ __launch_bounds__(256, 2)
void gemm_head(const float* __restrict__ A, const unsigned short* __restrict__ Bth,
               const unsigned short* __restrict__ Btl, const float* __restrict__ bias,
               float* __restrict__ C, int M, int K,
               const float* __restrict__ ln_g, const float* __restrict__ ln_b) {
    __shared__ unsigned short Ah[64][LDT], Al[64][LDT];
    __shared__ unsigned short Bh[64][LDT], Bl[64][LDT];
    int tid = threadIdx.x;
    int lane = tid & 63, w = tid >> 6;
    int m = lane & 15, q = lane >> 4;
    int rowBase = blockIdx.y * 64;
    f32x4 acc[4];
    #pragma unroll
    for (int ct = 0; ct < 4; ct++) acc[ct] = (f32x4){0.f, 0.f, 0.f, 0.f};

    for (int kk = 0; kk < K; kk += 32) {
        #pragma unroll
        for (int u = 0; u < 2; u++) {
            int f = tid + 256 * u;
            int r = f >> 3;
            int k4 = (f & 7) * 4;
            int row = rowBase + r;
            float4 v = make_float4(0.f, 0.f, 0.f, 0.f);
            if (row < M) v = *(const float4*)(A + (size_t)row * K + kk + k4);
            unsigned short h0 = f2bf(v.x), h1 = f2bf(v.y), h2 = f2bf(v.z), h3 = f2bf(v.w);
            unsigned short l0 = f2bf(v.x - bf2f(h0)), l1 = f2bf(v.y - bf2f(h1));
            unsigned short l2 = f2bf(v.z - bf2f(h2)), l3 = f2bf(v.w - bf2f(h3));
            *(u16x4*)&Ah[r][k4] = (u16x4){h0, h1, h2, h3};
            *(u16x4*)&Al[r][k4] = (u16x4){l0, l1, l2, l3};
        }
        {
            int n = tid >> 2;
            int ch = tid & 3;
            size_t goff = (size_t)n * K + kk + ch * 8;
            *(bf16x8*)&Bh[n][ch * 8] = *(const bf16x8*)(Bth + goff);
            *(bf16x8*)&Bl[n][ch * 8] = *(const bf16x8*)(Btl + goff);
        }
        __syncthreads();
        bf16x8 a_h = *(const bf16x8*)&Ah[w * 16 + m][q * 8];
        bf16x8 a_l = *(const bf16x8*)&Al[w * 16 + m][q * 8];
        #pragma unroll
        for (int ct = 0; ct < 4; ct++) {
            bf16x8 b_h = *(const bf16x8*)&Bh[ct * 16 + m][q * 8];
            bf16x8 b_l = *(const bf16x8*)&Bl[ct * 16 + m][q * 8];
            acc[ct] = __builtin_amdgcn_mfma_f32_16x16x32_bf16(a_h, b_h, acc[ct], 0, 0, 0);
            acc[ct] = __builtin_amdgcn_mfma_f32_16x16x32_bf16(a_l, b_h, acc[ct], 0, 0, 0);
            acc[ct] = __builtin_amdgcn_mfma_f32_16x16x32_bf16(a_h, b_l, acc[ct], 0, 0, 0);
        }
        __syncthreads();
    }
    // LN epilogue: row held by 16 lanes (m) x 4 cols (ct)
    #pragma unroll
    for (int r = 0; r < 4; r++) {
        float v[4];
        float sum = 0.f;
        #pragma unroll
        for (int ct = 0; ct < 4; ct++) {
            v[ct] = acc[ct][r] + bias[ct * 16 + m];
            sum += v[ct];
        }
        sum += __shfl_xor(sum, 1); sum += __shfl_xor(sum, 2);
        sum += __shfl_xor(sum, 4); sum += __shfl_xor(sum, 8);
        float mu = sum * (1.f / 64.f);
        float sq = 0.f;
        #pragma unroll
        for (int ct = 0; ct < 4; ct++) {
            float d = v[ct] - mu;
            sq += d * d;
        }
        sq += __shfl_xor(sq, 1); sq += __shfl_xor(sq, 2);
        sq += __shfl_xor(sq, 4); sq += __shfl_xor(sq, 8);
        float inv = rsqrtf(sq * (1.f / 64.f) + LN_EPS);
        int row = rowBase + w * 16 + q * 4 + r;
        if (row < M) {
            #pragma unroll
            for (int ct = 0; ct < 4; ct++) {
                int col = ct * 16 + m;
                C[(size_t)row * 64 + col] = (v[ct] - mu) * inv * ln_g[col] + ln_b[col];
            }
        }
    }
}

// ---------------------------------------------------------------------------
// score_kernel (persistent): per 64-slot group, ee = ea @ We via single f16
// MFMA, fused GATv2 score epilogue in PACKED f16 (pk_add/pk_fma + dot2),
// halving the epilogue VALU ops that dominate (VALUBusy 55%).
// Lane m owns channels [m*16 .. m*16+15].
// ---------------------------------------------------------------------------
__global__ __launch_bounds__(256, 2)
void score_kernel(const f16* __restrict__ efp,
                  const int* __restrict__ srcf, const int* __restrict__ dstf,
                  const f16* __restrict__ xlb, const f16* __restrict__ xrb,
                  const f16* __restrict__ wet,
                  const float* __restrict__ att, float* __restrict__ alpha) {
    __shared__ _Float16 Af[64][LDT];
    __shared__ _Float16 Bf[256][LDT];
    __shared__ int s_src[64], s_dst[64];
    int tid = threadIdx.x;
    int lane = tid & 63, w = tid >> 6;
    int m = lane & 15, q = lane >> 4;

    // stage B (We^T permuted f16, [256][32]) ONCE
    #pragma unroll
    for (int u = 0; u < 4; u++) {
        *(f16x8*)&Bf[tid][u * 8] = *(const f16x8*)(wet + (size_t)tid * EDIM + u * 8);
    }
    // att coefficients of channels m*16..m*16+15 as packed f16
    f16x8 attp0, attp1;
    #pragma unroll
    for (int i = 0; i < 8; i++) {
        attp0[i] = (f16)att[m * 16 + i];
        attp1[i] = (f16)att[m * 16 + 8 + i];
    }

    const f16x8 zero8 = {(f16)0, (f16)0, (f16)0, (f16)0, (f16)0, (f16)0, (f16)0, (f16)0};

    int groups = (EESLOTS + 63) >> 6;
    for (int g = blockIdx.x; g < groups; g += gridDim.x) {
        int base = g << 6;
        __syncthreads();   // protect Af + s_src reads of previous group
        // stage A: 64 slots x 32 k, sequential f16 stream from efp
        {
            int r = tid >> 2, ch = tid & 3;
            int j = base + r;
            if (j >= EESLOTS) j = EESLOTS - 1;
            *(f16x8*)&Af[r][ch * 8] = *(const f16x8*)(efp + (size_t)j * EDIM + ch * 8);
            if (ch == 0) { s_src[r] = srcf[j]; s_dst[r] = dstf[j]; }
        }
        __syncthreads();

        f16x8 a = *(const f16x8*)&Af[w * 16 + m][q * 8];
        f32x4 acc[16];
        #pragma unroll
        for (int ct = 0; ct < 16; ct++) {
            f16x8 b = *(const f16x8*)&Bf[ct * 16 + m][q * 8];
            acc[ct] = __builtin_amdgcn_mfma_f32_16x16x32_f16(
                a, b, (f32x4){0.f, 0.f, 0.f, 0.f}, 0, 0, 0);
        }

        // epilogue: per-slot score (packed f16 math)
        #pragma unroll
        for (int r = 0; r < 4; r++) {
            int sl = w * 16 + q * 4 + r;
            int slot = base + sl;
            int ss = s_src[sl], dd = s_dst[sl];
            const f16* xlp = xlb + (size_t)ss * HC + m * 16;
            const f16* xrp = xrb + (size_t)dd * HC + m * 16;
            f16x8 xa0 = *(const f16x8*)(xlp);
            f16x8 xa1 = *(const f16x8*)(xlp + 8);
            f16x8 xb0 = *(const f16x8*)(xrp);
            f16x8 xb1 = *(const f16x8*)(xrp + 8);
            f16x8 z0 = xa0 + xb0;
            f16x8 z1 = xa1 + xb1;
            f16x8 e0, e1;
            #pragma unroll
            for (int i = 0; i < 8; i++) {
                e0[i] = (f16)acc[i][r];
                e1[i] = (f16)acc[8 + i][r];
            }
            z0 += e0;
            z1 += e1;
            f16x8 lz0 = __builtin_elementwise_min(z0, zero8) * (f16)0.2f
                      + __builtin_elementwise_max(z0, zero8);
            f16x8 lz1 = __builtin_elementwise_min(z1, zero8) * (f16)0.2f
                      + __builtin_elementwise_max(z1, zero8);
            float s0 = 0.f, s1 = 0.f;
#if __has_builtin(__builtin_amdgcn_fdot2)
            #pragma unroll
            for (int i = 0; i < 4; i++) {
                f16x2 a2 = {lz0[2 * i], lz0[2 * i + 1]};
                f16x2 b2 = {attp0[2 * i], attp0[2 * i + 1]};
                s0 = __builtin_amdgcn_fdot2(a2, b2, s0, false);
                f16x2 c2 = {lz1[2 * i], lz1[2 * i + 1]};
                f16x2 d2 = {attp1[2 * i], attp1[2 * i + 1]};
                s1 = __builtin_amdgcn_fdot2(c2, d2, s1, false);
            }
#else
            #pragma unroll
            for (int i = 0; i < 8; i++) {
                s0 += (float)lz0[i] * (float)attp0[i];
                s1 += (float)lz1[i] * (float)attp1[i];
            }
#endif
            float s = s0 + s1;
            // head h = m>>2: reduce over the 4 lanes m in [4h..4h+3]
            s += __shfl_xor(s, 1);
            s += __shfl_xor(s, 2);
            if ((m & 3) == 0 && slot < EESLOTS) {
                alpha[(size_t)slot * 4 + (m >> 2)] = s;
            }
        }
    }
}

// ---------------------------------------------------------------------------
// Lean aggregation: softmax over precomputed alpha (shift = alpha_self),
// weighted gather of fp16 xl from the COMPACT xlb buffer (25.6 MB, ~L2
// resident). One wave per node, ILP x4. fp32 accumulation; fp32 output xb.
// ---------------------------------------------------------------------------
__global__ __launch_bounds__(256)
void gat_aggr(const f16* __restrict__ xlb, const float* __restrict__ alpha,
              const int* __restrict__ row_ptr, const int* __restrict__ csr_src,
              const float* __restrict__ bias, float* __restrict__ out, int do_relu) {
    int lane = threadIdx.x & 63;
    int wv = threadIdx.x >> 6;
    int n = blockIdx.x * 4 + wv;
    if (n >= NN) return;
    int h = lane >> 4;
    float4 bb = *(const float4*)(bias + 4 * lane);
    int s0 = row_ptr[n], e0 = row_ptr[n + 1];
    float aself = alpha[(size_t)(NE + n) * 4 + h];
    float denom = 1.f;
    f16x4 xs = *(const f16x4*)(xlb + (size_t)n * HC + 4 * lane);
    float4 acc = make_float4((float)xs[0], (float)xs[1], (float)xs[2], (float)xs[3]);

    for (int j0 = s0; j0 < e0; j0 += 64) {
        int cnt = min(64, e0 - j0);
        int sidx = (j0 + lane < e0) ? csr_src[j0 + lane] : 0;
        int t = 0;
        for (; t + 3 < cnt; t += 4) {
            int sa = __shfl(sidx, t);
            int sb = __shfl(sidx, t + 1);
            int sc = __shfl(sidx, t + 2);
            int sd = __shfl(sidx, t + 3);
            float a0 = __expf(alpha[(size_t)(j0 + t) * 4 + h] - aself);
            float a1 = __expf(alpha[(size_t)(j0 + t + 1) * 4 + h] - aself);
            float a2 = __expf(alpha[(size_t)(j0 + t + 2) * 4 + h] - aself);
            float a3 = __expf(alpha[(size_t)(j0 + t + 3) * 4 + h] - aself);
            f16x4 x0 = *(const f16x4*)(xlb + (size_t)sa * HC + 4 * lane);
            f16x4 x1 = *(const f16x4*)(xlb + (size_t)sb * HC + 4 * lane);
            f16x4 x2 = *(const f16x4*)(xlb + (size_t)sc * HC + 4 * lane);
            f16x4 x3 = *(const f16x4*)(xlb + (size_t)sd * HC + 4 * lane);
            denom += a0 + a1 + a2 + a3;
            acc.x += a0 * (float)x0[0] + a1 * (float)x1[0] + a2 * (float)x2[0] + a3 * (float)x3[0];
            acc.y += a0 * (float)x0[1] + a1 * (float)x1[1] + a2 * (float)x2[1] + a3 * (float)x3[1];
            acc.z += a0 * (float)x0[2] + a1 * (float)x1[2] + a2 * (float)x2[2] + a3 * (float)x3[2];
            acc.w += a0 * (float)x0[3] + a1 * (float)x1[3] + a2 * (float)x2[3] + a3 * (float)x3[3];
        }
        for (; t < cnt; t++) {
            int sa = __shfl(sidx, t);
            float a0 = __expf(alpha[(size_t)(j0 + t) * 4 + h] - aself);
            f16x4 x0 = *(const f16x4*)(xlb + (size_t)sa * HC + 4 * lane);
            denom += a0;
            acc.x += a0 * (float)x0[0]; acc.y += a0 * (float)x0[1];
            acc.z += a0 * (float)x0[2]; acc.w += a0 * (float)x0[3];
        }
    }

    float inv = 1.f / denom;
    float4 r = make_float4(acc.x * inv + bb.x, acc.y * inv + bb.y,
                           acc.z * inv + bb.z, acc.w * inv + bb.w);
    if (do_relu) {
        r.x = fmaxf(r.x, 0.f); r.y = fmaxf(r.y, 0.f);
        r.z = fmaxf(r.z, 0.f); r.w = fmaxf(r.w, 0.f);
    }
    *(float4*)(out + (size_t)n * HC + 4 * lane) = r;
}

// ---------------------------------------------------------------------------
// Graph mean pre-reduction exploiting sorted batch. 64 rows/block.
// ---------------------------------------------------------------------------
__global__ void graph_sum(const float* __restrict__ x, const int* __restrict__ batch,
                          float* __restrict__ gsum, float* __restrict__ gcnt) {
    int c = threadIdx.x;
    int r0 = blockIdx.x * 64;
    int r1 = min(r0 + 64, NN);
    if (r0 >= NN) return;
    float acc = 0.f;
    int gcur = batch[r0];
    for (int n = r0; n < r1; n++) {
        int g = batch[n];
        if (g != gcur) {
            atomicAdd(&gsum[(size_t)gcur * HC + c], acc);
            acc = 0.f; gcur = g;
        }
        acc += x[(size_t)n * HC + c];
    }
    atomicAdd(&gsum[(size_t)gcur * HC + c], acc);
    if (c == 0) {
        int cnt = 0; gcur = batch[r0];
        for (int n = r0; n < r1; n++) {
            int g = batch[n];
            if (g != gcur) {
                atomicAdd(&gcnt[gcur], (float)cnt);
                cnt = 0; gcur = g;
            }
            cnt++;
        }
        atomicAdd(&gcnt[gcur], (float)cnt);
    }
}

__global__ void glob_kernel(const float* __restrict__ gsum, const float* __restrict__ gcnt,
                            const float* __restrict__ W, const float* __restrict__ bias,
                            const float* __restrict__ g, const float* __restrict__ b,
                            float* __restrict__ out) {
    int gi = blockIdx.x;
    int lane = threadIdx.x;
    float inv = 1.f / fmaxf(gcnt[gi], 1.f);
    float acc = 0.f;
    for (int k = 0; k < HC; k++)
        acc += (gsum[(size_t)gi * HC + k] * inv) * W[(size_t)k * ND + lane];
    acc += bias[lane];
    float s = acc;
    #pragma unroll
    for (int o = 32; o >= 1; o >>= 1) s += __shfl_xor(s, o);
    float mu = s * (1.f / 64.f);
    float dv = acc - mu;
    float q = dv * dv;
    #pragma unroll
    for (int o = 32; o >= 1; o >>= 1) q += __shfl_xor(q, o);
    float var = q * (1.f / 64.f);
    out[(size_t)gi * ND + lane] = dv * rsqrtf(var + LN_EPS) * g[lane] + b[lane];
}

// ---------------------------------------------------------------------------
extern "C" void kernel_launch(void* const* d_in, const int* in_sizes, int n_in,
                              void* d_out, int out_size, void* d_ws, size_t ws_size,
                              hipStream_t stream) {
    (void)in_sizes; (void)n_in; (void)out_size; (void)ws_size;
    const float* node_feature = (const float*)d_in[0];
    const int*   edge_index   = (const int*)d_in[1];
    const float* edge_feature = (const float*)d_in[2];
    const int*   batch        = (const int*)d_in[3];
    const float* Wl0   = (const float*)d_in[4];
    const float* bl0   = (const float*)d_in[5];
    const float* Wr0   = (const float*)d_in[6];
    const float* br0   = (const float*)d_in[7];
    const float* We0   = (const float*)d_in[8];
    const float* att0  = (const float*)d_in[9];
    const float* bias0 = (const float*)d_in[10];
    const float* Wl1   = (const float*)d_in[11];
    const float* bl1   = (const float*)d_in[12];
    const float* Wr1   = (const float*)d_in[13];
    const float* br1   = (const float*)d_in[14];
    const float* We1   = (const float*)d_in[15];
    const float* att1  = (const float*)d_in[16];
    const float* bias1 = (const float*)d_in[17];
    const float* node_W  = (const float*)d_in[18];
    const float* node_b  = (const float*)d_in[19];
    const float* graph_W = (const float*)d_in[20];
    const float* graph_b = (const float*)d_in[21];
    const float* nn_g = (const float*)d_in[22];
    const float* nn_b = (const float*)d_in[23];
    const float* gn_g = (const float*)d_in[24];
    const float* gn_b = (const float*)d_in[25];

    const int* src = edge_index;
    const int* dst = edge_index + NE;

    char* p = (char*)d_ws;
    auto carve = [&](size_t bytes) {
        char* r = p;
        p += (bytes + 255) & ~(size_t)255;
        return r;
    };
    int*   row_ptr   = (int*)carve((NN + 1) * sizeof(int));
    int*   cursor    = (int*)carve(NN * sizeof(int));
    int*   deg       = (int*)carve(NN * sizeof(int));
    int*   bsum      = (int*)carve(SCAN_B * sizeof(int));
    int*   boff      = (int*)carve(SCAN_B * sizeof(int));
    int*   csr_src   = (int*)carve((size_t)NE * sizeof(int));
    int*   csr_dst   = (int*)carve((size_t)NE * sizeof(int));
    int*   csr_eid   = (int*)carve((size_t)NE * sizeof(int));
    int*   srcf      = (int*)carve((size_t)EESLOTS * sizeof(int));
    int*   dstf      = (int*)carve((size_t)EESLOTS * sizeof(int));
    f16*   efp       = (f16*)carve((size_t)EESLOTS * EDIM * sizeof(f16));
    f16*   xlb       = (f16*)carve((size_t)NN * HC * sizeof(f16));   // xl fp16
    f16*   xrb       = (f16*)carve((size_t)NN * HC * sizeof(f16));   // xr fp16
    float* xb        = (float*)carve((size_t)NN * HC * sizeof(float));
    float* alpha     = (float*)carve((size_t)EESLOTS * NH * sizeof(float));
    float* gsum      = (float*)carve((size_t)(NGG * HC + NGG) * sizeof(float));
    float* gcnt      = gsum + (size_t)NGG * HC;
    // layer GEMM weights: f16 transposed [512][K]
    f16* wlr0f = (f16*)carve((size_t)(2 * HC) * DIN * sizeof(f16));
    f16* wlr1f = (f16*)carve((size_t)(2 * HC) * HC * sizeof(f16));
    // head weights: bf16 hi/lo (accurate)
    unsigned short* nwh   = (unsigned short*)carve((size_t)HC * ND * 2 * 2);
    unsigned short* nwl   = nwh + (size_t)HC * ND;
    f16* wet0 = (f16*)carve((size_t)EDIM * HC * sizeof(f16));
    f16* wet1 = (f16*)carve((size_t)EDIM * HC * sizeof(f16));
    float* b0cat = (float*)carve(2 * HC * sizeof(float));
    float* b1cat = (float*)carve(2 * HC * sizeof(float));

    hipMemsetAsync(deg, 0, NN * sizeof(int), stream);
    hipMemsetAsync(gsum, 0, (NGG * HC + NGG) * sizeof(float), stream);

    // CSR (3-kernel scan) + efp pre-permutation + weight conversion
    count_deg<<<(NE + 255) / 256, 256, 0, stream>>>(dst, deg);
    scan_bsum<<<SCAN_NB, SCAN_B, 0, stream>>>(deg, bsum);
    scan_boff<<<1, SCAN_B, 0, stream>>>(bsum, boff);
    scan_final<<<SCAN_NB, SCAN_B, 0, stream>>>(deg, boff, row_ptr, cursor);
    fill_csr<<<(NE + 255) / 256, 256, 0, stream>>>(src, dst, cursor, csr_src, csr_dst, csr_eid);
    perm_ef<<<(NE * 4 + 255) / 256, 256, 0, stream>>>(edge_feature, csr_eid, csr_src, csr_dst,
                                                      efp, srcf, dstf);
    self_slots<<<(NN * EDIM + 255) / 256, 256, 0, stream>>>(row_ptr, efp, srcf, dstf);
    conv_wtf<<<(DIN * HC + 255) / 256, 256, 0, stream>>>(Wl0, wlr0f, DIN, HC);
    conv_wtf<<<(DIN * HC + 255) / 256, 256, 0, stream>>>(Wr0, wlr0f + (size_t)HC * DIN, DIN, HC);
    conv_wtf<<<(HC * HC + 255) / 256, 256, 0, stream>>>(Wl1, wlr1f, HC, HC);
    conv_wtf<<<(HC * HC + 255) / 256, 256, 0, stream>>>(Wr1, wlr1f + (size_t)HC * HC, HC, HC);
    conv_wt<<<(HC * ND + 255) / 256, 256, 0, stream>>>(node_W, nwh, nwl, HC, ND);
    conv_wet<<<(EDIM * HC + 255) / 256, 256, 0, stream>>>(We0, wet0);
    conv_wet<<<(EDIM * HC + 255) / 256, 256, 0, stream>>>(We1, wet1);
    concat_bias<<<1, 256, 0, stream>>>(bl0, br0, b0cat);
    concat_bias<<<1, 256, 0, stream>>>(bl1, br1, b1cat);

    dim3 gw(4, (NN + 63) / 64);
    // Layer 0
    gemm_wide<<<gw, 256, 0, stream>>>(node_feature, wlr0f, b0cat, xlb, xrb, NN, DIN);
    score_kernel<<<2048, 256, 0, stream>>>(efp, srcf, dstf, xlb, xrb, wet0, att0, alpha);
    gat_aggr<<<(NN + 3) / 4, 256, 0, stream>>>(xlb, alpha, row_ptr, csr_src, bias0, xb, 1);
    // Layer 1
    gemm_wide<<<gw, 256, 0, stream>>>(xb, wlr1f, b1cat, xlb, xrb, NN, HC);
    score_kernel<<<2048, 256, 0, stream>>>(efp, srcf, dstf, xlb, xrb, wet1, att1, alpha);
    gat_aggr<<<(NN + 3) / 4, 256, 0, stream>>>(xlb, alpha, row_ptr, csr_src, bias1, xb, 0);

    // Heads
    float* out_local = (float*)d_out;
    float* out_glob  = out_local + (size_t)NN * ND;
    dim3 gh(1, (NN + 63) / 64);
    gemm_head<<<gh, 256, 0, stream>>>(xb, nwh, nwl, node_b, out_local, NN, HC, nn_g, nn_b);
    graph_sum<<<(NN + 63) / 64, 256, 0, stream>>>(xb, batch, gsum, gcnt);
    glob_kernel<<<NGG, 64, 0, stream>>>(gsum, gcnt, graph_W, graph_b, gn_g, gn_b, out_glob);
}